// Round 8
// baseline (513.578 us; speedup 1.0000x reference)
//
#include <hip/hip_runtime.h>

#define HID 128

// ---------------- degree histogram (int) ----------------
__global__ __launch_bounds__(256) void deg_kernel(const int* __restrict__ ei,
                                                  int* __restrict__ deg, int E) {
    int e = blockIdx.x * 256 + threadIdx.x;
    if (e >= E) return;
    atomicAdd(&deg[ei[E + e]], 1);
}

// ---------------- scan stage 1: per-block (256 elems) sums ----------------
__global__ __launch_bounds__(256) void part_kernel(const int* __restrict__ deg,
                                                   int* __restrict__ part, int n) {
    int i = blockIdx.x * 256 + threadIdx.x;
    int v = (i < n) ? deg[i] : 0;
    #pragma unroll
    for (int m = 1; m < 64; m <<= 1) v += __shfl_xor(v, m);
    __shared__ int w[4];
    int lane = threadIdx.x & 63, wv = threadIdx.x >> 6;
    if (lane == 0) w[wv] = v;
    __syncthreads();
    if (threadIdx.x == 0) part[blockIdx.x] = w[0] + w[1] + w[2] + w[3];
}

// ---------------- scan stage 2: exclusive scan of block sums ----------------
__global__ __launch_bounds__(1024) void scanpart_kernel(int* __restrict__ part, int nb) {
    __shared__ int s[1024];
    int t = threadIdx.x;
    int v = (t < nb) ? part[t] : 0;
    int orig = v;
    s[t] = v;
    __syncthreads();
    for (int off = 1; off < 1024; off <<= 1) {
        int u = (t >= off) ? s[t - off] : 0;
        __syncthreads();
        s[t] += u;
        __syncthreads();
    }
    if (t < nb) part[t] = s[t] - orig;   // exclusive
}

// ---------------- scan stage 3: per-block exclusive scan -> rp, cursor ----------------
__global__ __launch_bounds__(256) void rp_kernel(const int* __restrict__ deg,
                                                 const int* __restrict__ part,
                                                 int* __restrict__ rp,
                                                 int* __restrict__ cursor, int n) {
    int tid = threadIdx.x, lane = tid & 63, wv = tid >> 6;
    int i = blockIdx.x * 256 + tid;
    int v = (i < n) ? deg[i] : 0;
    int orig = v;
    #pragma unroll
    for (int off = 1; off < 64; off <<= 1) {
        int t = __shfl_up(v, off);
        if (lane >= off) v += t;
    }
    __shared__ int wsum[4];
    if (lane == 63) wsum[wv] = v;
    __syncthreads();
    int wbase = 0;
    #pragma unroll
    for (int w = 0; w < 4; ++w) if (w < wv) wbase += wsum[w];
    int excl = part[blockIdx.x] + wbase + v - orig;
    if (i < n) { rp[i] = excl; cursor[i] = excl; }
    if (i == n - 1) rp[n] = excl + orig;
}

// ---------------- CSR fill ----------------
__global__ __launch_bounds__(256) void fill_kernel(const int* __restrict__ ei,
                                                   int* __restrict__ cursor,
                                                   int* __restrict__ csr_src, int E) {
    int e = blockIdx.x * 256 + threadIdx.x;
    if (e >= E) return;
    int dst = ei[E + e];
    int pos = atomicAdd(&cursor[dst], 1);
    csr_src[pos] = ei[e];
}

// ---------------- 128-dim pull aggregation: one wave per node, writes MEAN ----------------
__global__ __launch_bounds__(256) void aggp_kernel(const int* __restrict__ rp,
                                                   const int* __restrict__ ci,
                                                   const float* __restrict__ h,
                                                   float* __restrict__ agg, int n) {
    int node = (blockIdx.x * 256 + threadIdx.x) >> 6;
    if (node >= n) return;
    int lane = threadIdx.x & 63;
    float2 a0 = make_float2(0.f, 0.f), a1 = make_float2(0.f, 0.f);
    float2 a2 = make_float2(0.f, 0.f), a3 = make_float2(0.f, 0.f);
    float2 a4 = make_float2(0.f, 0.f), a5 = make_float2(0.f, 0.f);
    float2 a6 = make_float2(0.f, 0.f), a7 = make_float2(0.f, 0.f);
    int beg = rp[node], end = rp[node + 1];
    int j = beg;
    for (; j + 7 < end; j += 8) {
        int s0 = ci[j],     s1 = ci[j + 1], s2 = ci[j + 2], s3 = ci[j + 3];
        int s4 = ci[j + 4], s5 = ci[j + 5], s6 = ci[j + 6], s7 = ci[j + 7];
        float2 v0 = *(const float2*)(h + (size_t)s0 * HID + lane * 2);
        float2 v1 = *(const float2*)(h + (size_t)s1 * HID + lane * 2);
        float2 v2 = *(const float2*)(h + (size_t)s2 * HID + lane * 2);
        float2 v3 = *(const float2*)(h + (size_t)s3 * HID + lane * 2);
        float2 v4 = *(const float2*)(h + (size_t)s4 * HID + lane * 2);
        float2 v5 = *(const float2*)(h + (size_t)s5 * HID + lane * 2);
        float2 v6 = *(const float2*)(h + (size_t)s6 * HID + lane * 2);
        float2 v7 = *(const float2*)(h + (size_t)s7 * HID + lane * 2);
        a0.x += v0.x; a0.y += v0.y;  a1.x += v1.x; a1.y += v1.y;
        a2.x += v2.x; a2.y += v2.y;  a3.x += v3.x; a3.y += v3.y;
        a4.x += v4.x; a4.y += v4.y;  a5.x += v5.x; a5.y += v5.y;
        a6.x += v6.x; a6.y += v6.y;  a7.x += v7.x; a7.y += v7.y;
    }
    for (; j + 3 < end; j += 4) {
        int s0 = ci[j], s1 = ci[j + 1], s2 = ci[j + 2], s3 = ci[j + 3];
        float2 v0 = *(const float2*)(h + (size_t)s0 * HID + lane * 2);
        float2 v1 = *(const float2*)(h + (size_t)s1 * HID + lane * 2);
        float2 v2 = *(const float2*)(h + (size_t)s2 * HID + lane * 2);
        float2 v3 = *(const float2*)(h + (size_t)s3 * HID + lane * 2);
        a0.x += v0.x; a0.y += v0.y;  a1.x += v1.x; a1.y += v1.y;
        a2.x += v2.x; a2.y += v2.y;  a3.x += v3.x; a3.y += v3.y;
    }
    for (; j < end; ++j) {
        int s0 = ci[j];
        float2 v0 = *(const float2*)(h + (size_t)s0 * HID + lane * 2);
        a0.x += v0.x; a0.y += v0.y;
    }
    float inv = 1.0f / fmaxf((float)(end - beg), 1.0f);
    float2 o = make_float2((a0.x + a1.x + a2.x + a3.x + a4.x + a5.x + a6.x + a7.x) * inv,
                           (a0.y + a1.y + a2.y + a3.y + a4.y + a5.y + a6.y + a7.y) * inv);
    *(float2*)(agg + (size_t)node * HID + lane * 2) = o;
}

// ---------------- layer 0: fused 11-dim pull-agg + dual matmul + LN + ReLU ----------------
__global__ __launch_bounds__(256) void layer0_kernel(
    const float* __restrict__ x, const int* __restrict__ rp, const int* __restrict__ ci,
    const float* __restrict__ w_l, const float* __restrict__ b_l, const float* __restrict__ w_r,
    const float* __restrict__ ln_w, const float* __restrict__ ln_b,
    float* __restrict__ h_out, int n)
{
    int node = (blockIdx.x * 256 + threadIdx.x) >> 6;
    int lane = threadIdx.x & 63;
    if (node >= n) return;
    int beg = rp[node], end = rp[node + 1];
    int g = lane / 11;
    int d = lane - g * 11;
    float acc0 = 0.f, acc1 = 0.f;
    int j = beg + g;
    if (g < 5) {
        for (; j + 5 < end; j += 10) {
            int s0 = ci[j], s1 = ci[j + 5];
            acc0 += x[(size_t)s0 * 11 + d];
            acc1 += x[(size_t)s1 * 11 + d];
        }
        for (; j < end; j += 5) {
            int s0 = ci[j];
            acc0 += x[(size_t)s0 * 11 + d];
        }
    }
    float acc = acc0 + acc1;
    float aggk = 0.f;
    #pragma unroll
    for (int gg = 0; gg < 5; ++gg) {
        aggk += __shfl(acc, (lane < 11) ? (lane + 11 * gg) : lane);
    }
    float inv = 1.0f / fmaxf((float)(end - beg), 1.0f);
    float v0 = b_l[lane], v1 = b_l[lane + 64];
    #pragma unroll
    for (int k = 0; k < 11; ++k) {
        float a  = __shfl(aggk, k) * inv;
        float xi = x[(size_t)node * 11 + k];
        v0 += a * w_l[k * HID + lane]      + xi * w_r[k * HID + lane];
        v1 += a * w_l[k * HID + lane + 64] + xi * w_r[k * HID + lane + 64];
    }
    float s = v0 + v1, s2 = v0 * v0 + v1 * v1;
    #pragma unroll
    for (int m = 1; m < 64; m <<= 1) { s += __shfl_xor(s, m); s2 += __shfl_xor(s2, m); }
    float mu  = s * (1.0f / HID);
    float var = s2 * (1.0f / HID) - mu * mu;
    float rstd = rsqrtf(var + 1e-5f);
    float o0 = fmaxf((v0 - mu) * rstd * ln_w[lane]      + ln_b[lane],      0.0f);
    float o1 = fmaxf((v1 - mu) * rstd * ln_w[lane + 64] + ln_b[lane + 64], 0.0f);
    h_out[(size_t)node * HID + lane]      = o0;
    h_out[(size_t)node * HID + lane + 64] = o1;
}

// ---------------- layers 1/2: no-LDS GEMM, 8 rows x 4 cols per thread ----------------
// 256 threads: tx = tid&31 (4 output cols), ty = tid>>5 (8 rows) -> 64 nodes/block.
// Tail: non-owner half-waves clamp their row window (in-bounds reads) but NEVER write —
// this is what fixes R7's aliased write/read race on the tail rows.
template<int RES, int CLS>
__global__ __launch_bounds__(256, 4) void layer_kernel(
    const float* __restrict__ agg, const float* __restrict__ h_in,
    const float* __restrict__ w_l, const float* __restrict__ b_l, const float* __restrict__ w_r,
    const float* __restrict__ ln_w, const float* __restrict__ ln_b,
    float* __restrict__ h_out,
    const float* __restrict__ c_w0, const float* __restrict__ c_b0,
    const float* __restrict__ c_w1, const float* __restrict__ c_b1,
    float* __restrict__ cls_out, int n)
{
    __shared__ float lds_h[CLS ? 64 * 132 : 64];
    int tid = threadIdx.x;
    int tx = tid & 31, ty = tid >> 5;
    int base = blockIdx.x * 64;
    int row0u = base + ty * 8;
    int row0 = (row0u > n - 8) ? (n - 8) : row0u;    // clamp for in-bounds addressing
    bool owner = (row0u == row0);                    // only owners write
    const float* ra = agg  + (size_t)row0 * HID;
    const float* rh = h_in + (size_t)row0 * HID;

    float acc[8][4];
    #pragma unroll
    for (int r = 0; r < 8; ++r) { acc[r][0] = acc[r][1] = acc[r][2] = acc[r][3] = 0.f; }

    // weight prefetch pipeline: cw holds chunk k, nw loads chunk k+4
    float4 cw0 = *(const float4*)(w_l + 0 * HID + tx * 4);
    float4 cw1 = *(const float4*)(w_l + 1 * HID + tx * 4);
    float4 cw2 = *(const float4*)(w_l + 2 * HID + tx * 4);
    float4 cw3 = *(const float4*)(w_l + 3 * HID + tx * 4);

    #pragma unroll 1
    for (int k = 0; k < 2 * HID; k += 4) {
        int kn = (k + 4 < 2 * HID) ? (k + 4) : (2 * HID - 4);
        const float* Wn = (kn < HID) ? (w_l + (size_t)kn * HID) : (w_r + (size_t)(kn - HID) * HID);
        float4 nw0 = *(const float4*)(Wn + 0 * HID + tx * 4);
        float4 nw1 = *(const float4*)(Wn + 1 * HID + tx * 4);
        float4 nw2 = *(const float4*)(Wn + 2 * HID + tx * 4);
        float4 nw3 = *(const float4*)(Wn + 3 * HID + tx * 4);

        const float* rb = (k < HID) ? ra : rh;
        int kk = k & (HID - 1);
        float4 a[8];
        #pragma unroll
        for (int r = 0; r < 8; ++r) a[r] = *(const float4*)(rb + r * HID + kk);

        #pragma unroll
        for (int r = 0; r < 8; ++r) {
            acc[r][0] = fmaf(a[r].x, cw0.x, fmaf(a[r].y, cw1.x, fmaf(a[r].z, cw2.x, fmaf(a[r].w, cw3.x, acc[r][0]))));
            acc[r][1] = fmaf(a[r].x, cw0.y, fmaf(a[r].y, cw1.y, fmaf(a[r].z, cw2.y, fmaf(a[r].w, cw3.y, acc[r][1]))));
            acc[r][2] = fmaf(a[r].x, cw0.z, fmaf(a[r].y, cw1.z, fmaf(a[r].z, cw2.z, fmaf(a[r].w, cw3.z, acc[r][2]))));
            acc[r][3] = fmaf(a[r].x, cw0.w, fmaf(a[r].y, cw1.w, fmaf(a[r].z, cw2.w, fmaf(a[r].w, cw3.w, acc[r][3]))));
        }
        cw0 = nw0; cw1 = nw1; cw2 = nw2; cw3 = nw3;
    }

    float4 bl = *(const float4*)(b_l  + tx * 4);
    float4 gw = *(const float4*)(ln_w + tx * 4);
    float4 gb = *(const float4*)(ln_b + tx * 4);
    #pragma unroll
    for (int r = 0; r < 8; ++r) {
        float v0 = acc[r][0] + bl.x, v1 = acc[r][1] + bl.y;
        float v2 = acc[r][2] + bl.z, v3 = acc[r][3] + bl.w;
        float s  = v0 + v1 + v2 + v3;
        float s2 = v0*v0 + v1*v1 + v2*v2 + v3*v3;
        #pragma unroll
        for (int m = 16; m >= 1; m >>= 1) { s += __shfl_xor(s, m); s2 += __shfl_xor(s2, m); }
        float mu  = s * (1.0f / HID);
        float var = s2 * (1.0f / HID) - mu * mu;
        float rstd = rsqrtf(var + 1e-5f);
        float o0 = fmaxf((v0 - mu) * rstd * gw.x + gb.x, 0.f);
        float o1 = fmaxf((v1 - mu) * rstd * gw.y + gb.y, 0.f);
        float o2 = fmaxf((v2 - mu) * rstd * gw.z + gb.z, 0.f);
        float o3 = fmaxf((v3 - mu) * rstd * gw.w + gb.w, 0.f);
        if (RES) {
            float4 res = *(const float4*)(rh + r * HID + tx * 4);
            o0 += res.x; o1 += res.y; o2 += res.z; o3 += res.w;
        }
        if (CLS) {
            if (owner)
                *(float4*)&lds_h[(ty * 8 + r) * 132 + tx * 4] = make_float4(o0, o1, o2, o3);
        } else {
            if (owner)
                *(float4*)(h_out + (size_t)(row0 + r) * HID + tx * 4) = make_float4(o0, o1, o2, o3);
        }
    }

    if (CLS) {
        __syncthreads();
        int lane = tid & 63, wv = tid >> 6;   // 4 waves x 16 rows
        float bb0 = c_b0[lane], ww1 = c_w1[lane], bb1 = c_b1[0];
        #pragma unroll 1
        for (int q = 0; q < 16; ++q) {
            int row = wv * 16 + q;
            int node = base + row;
            if (node >= n) break;
            float s = bb0;
            #pragma unroll 4
            for (int k = 0; k < HID; k += 4) {
                float4 hv = *(const float4*)&lds_h[row * 132 + k];
                s = fmaf(hv.x, c_w0[(k + 0) * 64 + lane], s);
                s = fmaf(hv.y, c_w0[(k + 1) * 64 + lane], s);
                s = fmaf(hv.z, c_w0[(k + 2) * 64 + lane], s);
                s = fmaf(hv.w, c_w0[(k + 3) * 64 + lane], s);
            }
            s = fmaxf(s, 0.f);
            float t = s * ww1;
            #pragma unroll
            for (int m = 1; m < 64; m <<= 1) t += __shfl_xor(t, m);
            if (lane == 0) cls_out[node] = t + bb1;
        }
    }
}

extern "C" void kernel_launch(void* const* d_in, const int* in_sizes, int n_in,
                              void* d_out, int out_size, void* d_ws, size_t ws_size,
                              hipStream_t stream) {
    const float* x  = (const float*)d_in[0];
    const int*   ei = (const int*)d_in[1];     // integer inputs arrive as int32
    const float* w_l0 = (const float*)d_in[2];
    const float* b_l0 = (const float*)d_in[3];
    const float* w_r0 = (const float*)d_in[4];
    const float* lnw0 = (const float*)d_in[5];
    const float* lnb0 = (const float*)d_in[6];
    const float* w_l1 = (const float*)d_in[7];
    const float* b_l1 = (const float*)d_in[8];
    const float* w_r1 = (const float*)d_in[9];
    const float* lnw1 = (const float*)d_in[10];
    const float* lnb1 = (const float*)d_in[11];
    const float* w_l2 = (const float*)d_in[12];
    const float* b_l2 = (const float*)d_in[13];
    const float* w_r2 = (const float*)d_in[14];
    const float* lnw2 = (const float*)d_in[15];
    const float* lnb2 = (const float*)d_in[16];
    const float* c_w0 = (const float*)d_in[17];
    const float* c_b0 = (const float*)d_in[18];
    const float* c_w1 = (const float*)d_in[19];
    const float* c_b1 = (const float*)d_in[20];
    float* out = (float*)d_out;

    int N = in_sizes[0] / 11;
    int E = in_sizes[1] / 2;
    int nb = (N + 255) / 256;

    // workspace: [deg: N][rp: N+1][cursor: N][csr: E][part: nb] [bufA: N*HID][bufB: N*HID]
    int*   deg    = (int*)d_ws;
    int*   rp     = deg + N;
    int*   cursor = rp + (N + 1);
    int*   csr    = cursor + N;
    int*   part   = csr + E;
    float* bufA   = (float*)(part + ((nb + 63) & ~63));
    float* bufB   = bufA + (size_t)N * HID;

    // ---- CSR build ----
    hipMemsetAsync(deg, 0, (size_t)N * sizeof(int), stream);
    deg_kernel<<<(E + 255) / 256, 256, 0, stream>>>(ei, deg, E);
    part_kernel<<<nb, 256, 0, stream>>>(deg, part, N);
    scanpart_kernel<<<1, 1024, 0, stream>>>(part, nb);
    rp_kernel<<<nb, 256, 0, stream>>>(deg, part, rp, cursor, N);
    fill_kernel<<<(E + 255) / 256, 256, 0, stream>>>(ei, cursor, csr, E);

    int nodeBlocks = (N + 3) / 4;

    // ---- layer 0 ----
    layer0_kernel<<<nodeBlocks, 256, 0, stream>>>(x, rp, csr, w_l0, b_l0, w_r0, lnw0, lnb0, bufA, N);

    // ---- layer 1 ----
    aggp_kernel<<<nodeBlocks, 256, 0, stream>>>(rp, csr, bufA, bufB, N);
    layer_kernel<1, 0><<<(N + 63) / 64, 256, 0, stream>>>(bufB, bufA, w_l1, b_l1, w_r1, lnw1, lnb1,
                                                          bufA, nullptr, nullptr, nullptr, nullptr, nullptr, N);

    // ---- layer 2 + fused classifier ----
    aggp_kernel<<<nodeBlocks, 256, 0, stream>>>(rp, csr, bufA, bufB, N);
    layer_kernel<1, 1><<<(N + 63) / 64, 256, 0, stream>>>(bufB, bufA, w_l2, b_l2, w_r2, lnw2, lnb2,
                                                          nullptr, c_w0, c_b0, c_w1, c_b1, out, N);
}

// Round 9
// 459.040 us; speedup vs baseline: 1.1188x; 1.1188x over previous
//
#include <hip/hip_runtime.h>

#define HID 128

// ---------------- degree histogram (int) ----------------
__global__ __launch_bounds__(256) void deg_kernel(const int* __restrict__ ei,
                                                  int* __restrict__ deg, int E) {
    int e = blockIdx.x * 256 + threadIdx.x;
    if (e >= E) return;
    atomicAdd(&deg[ei[E + e]], 1);
}

// ---------------- scan stage 1: per-block (256 elems) sums ----------------
__global__ __launch_bounds__(256) void part_kernel(const int* __restrict__ deg,
                                                   int* __restrict__ part, int n) {
    int i = blockIdx.x * 256 + threadIdx.x;
    int v = (i < n) ? deg[i] : 0;
    #pragma unroll
    for (int m = 1; m < 64; m <<= 1) v += __shfl_xor(v, m);
    __shared__ int w[4];
    int lane = threadIdx.x & 63, wv = threadIdx.x >> 6;
    if (lane == 0) w[wv] = v;
    __syncthreads();
    if (threadIdx.x == 0) part[blockIdx.x] = w[0] + w[1] + w[2] + w[3];
}

// ---------------- scan stage 2: exclusive scan of block sums ----------------
__global__ __launch_bounds__(1024) void scanpart_kernel(int* __restrict__ part, int nb) {
    __shared__ int s[1024];
    int t = threadIdx.x;
    int v = (t < nb) ? part[t] : 0;
    int orig = v;
    s[t] = v;
    __syncthreads();
    for (int off = 1; off < 1024; off <<= 1) {
        int u = (t >= off) ? s[t - off] : 0;
        __syncthreads();
        s[t] += u;
        __syncthreads();
    }
    if (t < nb) part[t] = s[t] - orig;   // exclusive
}

// ---------------- scan stage 3: per-block exclusive scan -> rp, cursor ----------------
__global__ __launch_bounds__(256) void rp_kernel(const int* __restrict__ deg,
                                                 const int* __restrict__ part,
                                                 int* __restrict__ rp,
                                                 int* __restrict__ cursor, int n) {
    int tid = threadIdx.x, lane = tid & 63, wv = tid >> 6;
    int i = blockIdx.x * 256 + tid;
    int v = (i < n) ? deg[i] : 0;
    int orig = v;
    #pragma unroll
    for (int off = 1; off < 64; off <<= 1) {
        int t = __shfl_up(v, off);
        if (lane >= off) v += t;
    }
    __shared__ int wsum[4];
    if (lane == 63) wsum[wv] = v;
    __syncthreads();
    int wbase = 0;
    #pragma unroll
    for (int w = 0; w < 4; ++w) if (w < wv) wbase += wsum[w];
    int excl = part[blockIdx.x] + wbase + v - orig;
    if (i < n) { rp[i] = excl; cursor[i] = excl; }
    if (i == n - 1) rp[n] = excl + orig;
}

// ---------------- CSR fill ----------------
__global__ __launch_bounds__(256) void fill_kernel(const int* __restrict__ ei,
                                                   int* __restrict__ cursor,
                                                   int* __restrict__ csr_src, int E) {
    int e = blockIdx.x * 256 + threadIdx.x;
    if (e >= E) return;
    int dst = ei[E + e];
    int pos = atomicAdd(&cursor[dst], 1);
    csr_src[pos] = ei[e];
}

// ---------------- 128-dim pull aggregation: one wave per node, writes MEAN ----------------
__global__ __launch_bounds__(256) void aggp_kernel(const int* __restrict__ rp,
                                                   const int* __restrict__ ci,
                                                   const float* __restrict__ h,
                                                   float* __restrict__ agg, int n) {
    int node = (blockIdx.x * 256 + threadIdx.x) >> 6;
    if (node >= n) return;
    int lane = threadIdx.x & 63;
    float2 a0 = make_float2(0.f, 0.f), a1 = make_float2(0.f, 0.f);
    float2 a2 = make_float2(0.f, 0.f), a3 = make_float2(0.f, 0.f);
    float2 a4 = make_float2(0.f, 0.f), a5 = make_float2(0.f, 0.f);
    float2 a6 = make_float2(0.f, 0.f), a7 = make_float2(0.f, 0.f);
    int beg = rp[node], end = rp[node + 1];
    int j = beg;
    for (; j + 7 < end; j += 8) {
        int s0 = ci[j],     s1 = ci[j + 1], s2 = ci[j + 2], s3 = ci[j + 3];
        int s4 = ci[j + 4], s5 = ci[j + 5], s6 = ci[j + 6], s7 = ci[j + 7];
        float2 v0 = *(const float2*)(h + (size_t)s0 * HID + lane * 2);
        float2 v1 = *(const float2*)(h + (size_t)s1 * HID + lane * 2);
        float2 v2 = *(const float2*)(h + (size_t)s2 * HID + lane * 2);
        float2 v3 = *(const float2*)(h + (size_t)s3 * HID + lane * 2);
        float2 v4 = *(const float2*)(h + (size_t)s4 * HID + lane * 2);
        float2 v5 = *(const float2*)(h + (size_t)s5 * HID + lane * 2);
        float2 v6 = *(const float2*)(h + (size_t)s6 * HID + lane * 2);
        float2 v7 = *(const float2*)(h + (size_t)s7 * HID + lane * 2);
        a0.x += v0.x; a0.y += v0.y;  a1.x += v1.x; a1.y += v1.y;
        a2.x += v2.x; a2.y += v2.y;  a3.x += v3.x; a3.y += v3.y;
        a4.x += v4.x; a4.y += v4.y;  a5.x += v5.x; a5.y += v5.y;
        a6.x += v6.x; a6.y += v6.y;  a7.x += v7.x; a7.y += v7.y;
    }
    for (; j + 3 < end; j += 4) {
        int s0 = ci[j], s1 = ci[j + 1], s2 = ci[j + 2], s3 = ci[j + 3];
        float2 v0 = *(const float2*)(h + (size_t)s0 * HID + lane * 2);
        float2 v1 = *(const float2*)(h + (size_t)s1 * HID + lane * 2);
        float2 v2 = *(const float2*)(h + (size_t)s2 * HID + lane * 2);
        float2 v3 = *(const float2*)(h + (size_t)s3 * HID + lane * 2);
        a0.x += v0.x; a0.y += v0.y;  a1.x += v1.x; a1.y += v1.y;
        a2.x += v2.x; a2.y += v2.y;  a3.x += v3.x; a3.y += v3.y;
    }
    for (; j < end; ++j) {
        int s0 = ci[j];
        float2 v0 = *(const float2*)(h + (size_t)s0 * HID + lane * 2);
        a0.x += v0.x; a0.y += v0.y;
    }
    float inv = 1.0f / fmaxf((float)(end - beg), 1.0f);
    float2 o = make_float2((a0.x + a1.x + a2.x + a3.x + a4.x + a5.x + a6.x + a7.x) * inv,
                           (a0.y + a1.y + a2.y + a3.y + a4.y + a5.y + a6.y + a7.y) * inv);
    *(float2*)(agg + (size_t)node * HID + lane * 2) = o;
}

// ---------------- layer 0: fused 11-dim pull-agg + dual matmul + LN + ReLU ----------------
__global__ __launch_bounds__(256) void layer0_kernel(
    const float* __restrict__ x, const int* __restrict__ rp, const int* __restrict__ ci,
    const float* __restrict__ w_l, const float* __restrict__ b_l, const float* __restrict__ w_r,
    const float* __restrict__ ln_w, const float* __restrict__ ln_b,
    float* __restrict__ h_out, int n)
{
    int node = (blockIdx.x * 256 + threadIdx.x) >> 6;
    int lane = threadIdx.x & 63;
    if (node >= n) return;
    int beg = rp[node], end = rp[node + 1];
    int g = lane / 11;
    int d = lane - g * 11;
    float acc0 = 0.f, acc1 = 0.f;
    int j = beg + g;
    if (g < 5) {
        for (; j + 5 < end; j += 10) {
            int s0 = ci[j], s1 = ci[j + 5];
            acc0 += x[(size_t)s0 * 11 + d];
            acc1 += x[(size_t)s1 * 11 + d];
        }
        for (; j < end; j += 5) {
            int s0 = ci[j];
            acc0 += x[(size_t)s0 * 11 + d];
        }
    }
    float acc = acc0 + acc1;
    float aggk = 0.f;
    #pragma unroll
    for (int gg = 0; gg < 5; ++gg) {
        aggk += __shfl(acc, (lane < 11) ? (lane + 11 * gg) : lane);
    }
    float inv = 1.0f / fmaxf((float)(end - beg), 1.0f);
    float v0 = b_l[lane], v1 = b_l[lane + 64];
    #pragma unroll
    for (int k = 0; k < 11; ++k) {
        float a  = __shfl(aggk, k) * inv;
        float xi = x[(size_t)node * 11 + k];
        v0 += a * w_l[k * HID + lane]      + xi * w_r[k * HID + lane];
        v1 += a * w_l[k * HID + lane + 64] + xi * w_r[k * HID + lane + 64];
    }
    float s = v0 + v1, s2 = v0 * v0 + v1 * v1;
    #pragma unroll
    for (int m = 1; m < 64; m <<= 1) { s += __shfl_xor(s, m); s2 += __shfl_xor(s2, m); }
    float mu  = s * (1.0f / HID);
    float var = s2 * (1.0f / HID) - mu * mu;
    float rstd = rsqrtf(var + 1e-5f);
    float o0 = fmaxf((v0 - mu) * rstd * ln_w[lane]      + ln_b[lane],      0.0f);
    float o1 = fmaxf((v1 - mu) * rstd * ln_w[lane + 64] + ln_b[lane + 64], 0.0f);
    h_out[(size_t)node * HID + lane]      = o0;
    h_out[(size_t)node * HID + lane + 64] = o1;
}

// ---------------- layers 1/2: R4 shape (LDS tile, 8r x 4c/thread) + weight prefetch ----------------
// 256 threads: tx = tid&31 (4 cols), ty = tid>>5 (8 rows) -> 64 nodes/block.
// Node rows staged to LDS (alias-safe: all global reads of this block's rows happen
// before any global write). Weights register-prefetched distance-1 over flattened K=256.
// CLS=1: epilogue keeps h in LDS and computes classifier; skips h_out entirely.
template<int RES, int CLS>
__global__ __launch_bounds__(256) void layer_kernel(
    const float* __restrict__ agg, const float* __restrict__ h_in,
    const float* __restrict__ w_l, const float* __restrict__ b_l, const float* __restrict__ w_r,
    const float* __restrict__ ln_w, const float* __restrict__ ln_b,
    float* __restrict__ h_out,
    const float* __restrict__ c_w0, const float* __restrict__ c_b0,
    const float* __restrict__ c_w1, const float* __restrict__ c_b1,
    float* __restrict__ cls_out, int n)
{
    __shared__ float lds[64][260];   // [node][agg(0..127) | h_in(128..255)], pad 4
    int base = blockIdx.x * 64;
    int tid = threadIdx.x;
    #pragma unroll
    for (int i = 0; i < 8; ++i) {
        int idx = tid + i * 256;        // float4 index over 64*128/4 = 2048
        int row = idx >> 5;
        int c4  = (idx & 31) * 4;
        int node = base + row;
        float4 a = make_float4(0.f, 0.f, 0.f, 0.f);
        float4 h = make_float4(0.f, 0.f, 0.f, 0.f);
        if (node < n) {
            a = *(const float4*)(agg  + (size_t)node * HID + c4);
            h = *(const float4*)(h_in + (size_t)node * HID + c4);
        }
        *(float4*)&lds[row][c4]       = a;
        *(float4*)&lds[row][HID + c4] = h;
    }
    __syncthreads();

    int tx = tid & 31, ty = tid >> 5;
    float acc[8][4];
    #pragma unroll
    for (int r = 0; r < 8; ++r) { acc[r][0] = acc[r][1] = acc[r][2] = acc[r][3] = 0.f; }

    // weight prefetch pipeline over flattened K=256 (w_l rows 0..127, then w_r rows 0..127)
    float4 cw0 = *(const float4*)(w_l + 0 * HID + tx * 4);
    float4 cw1 = *(const float4*)(w_l + 1 * HID + tx * 4);
    float4 cw2 = *(const float4*)(w_l + 2 * HID + tx * 4);
    float4 cw3 = *(const float4*)(w_l + 3 * HID + tx * 4);

    #pragma unroll 1
    for (int k = 0; k < 2 * HID; k += 4) {
        int kn = (k + 4 < 2 * HID) ? (k + 4) : (2 * HID - 4);
        const float* Wn = (kn < HID) ? (w_l + (size_t)kn * HID) : (w_r + (size_t)(kn - HID) * HID);
        float4 nw0 = *(const float4*)(Wn + 0 * HID + tx * 4);
        float4 nw1 = *(const float4*)(Wn + 1 * HID + tx * 4);
        float4 nw2 = *(const float4*)(Wn + 2 * HID + tx * 4);
        float4 nw3 = *(const float4*)(Wn + 3 * HID + tx * 4);

        float4 a[8];
        #pragma unroll
        for (int r = 0; r < 8; ++r) a[r] = *(const float4*)&lds[ty * 8 + r][k];

        #pragma unroll
        for (int r = 0; r < 8; ++r) {
            acc[r][0] = fmaf(a[r].x, cw0.x, fmaf(a[r].y, cw1.x, fmaf(a[r].z, cw2.x, fmaf(a[r].w, cw3.x, acc[r][0]))));
            acc[r][1] = fmaf(a[r].x, cw0.y, fmaf(a[r].y, cw1.y, fmaf(a[r].z, cw2.y, fmaf(a[r].w, cw3.y, acc[r][1]))));
            acc[r][2] = fmaf(a[r].x, cw0.z, fmaf(a[r].y, cw1.z, fmaf(a[r].z, cw2.z, fmaf(a[r].w, cw3.z, acc[r][2]))));
            acc[r][3] = fmaf(a[r].x, cw0.w, fmaf(a[r].y, cw1.w, fmaf(a[r].z, cw2.w, fmaf(a[r].w, cw3.w, acc[r][3]))));
        }
        cw0 = nw0; cw1 = nw1; cw2 = nw2; cw3 = nw3;
    }

    if (CLS) __syncthreads();   // all agg-half reads done before epilogue overwrites it

    float4 bl = *(const float4*)(b_l  + tx * 4);
    float4 gw = *(const float4*)(ln_w + tx * 4);
    float4 gb = *(const float4*)(ln_b + tx * 4);
    #pragma unroll
    for (int r = 0; r < 8; ++r) {
        float v0 = acc[r][0] + bl.x, v1 = acc[r][1] + bl.y;
        float v2 = acc[r][2] + bl.z, v3 = acc[r][3] + bl.w;
        float s  = v0 + v1 + v2 + v3;
        float s2 = v0*v0 + v1*v1 + v2*v2 + v3*v3;
        #pragma unroll
        for (int m = 16; m >= 1; m >>= 1) { s += __shfl_xor(s, m); s2 += __shfl_xor(s2, m); }
        float mu  = s * (1.0f / HID);
        float var = s2 * (1.0f / HID) - mu * mu;
        float rstd = rsqrtf(var + 1e-5f);
        int row = ty * 8 + r;
        float o0 = fmaxf((v0 - mu) * rstd * gw.x + gb.x, 0.f);
        float o1 = fmaxf((v1 - mu) * rstd * gw.y + gb.y, 0.f);
        float o2 = fmaxf((v2 - mu) * rstd * gw.z + gb.z, 0.f);
        float o3 = fmaxf((v3 - mu) * rstd * gw.w + gb.w, 0.f);
        if (RES) {
            o0 += lds[row][HID + tx * 4 + 0];
            o1 += lds[row][HID + tx * 4 + 1];
            o2 += lds[row][HID + tx * 4 + 2];
            o3 += lds[row][HID + tx * 4 + 3];
        }
        int node = base + row;
        if (CLS) {
            *(float4*)&lds[row][tx * 4] = make_float4(o0, o1, o2, o3);
        } else if (node < n) {
            *(float4*)(h_out + (size_t)node * HID + tx * 4) = make_float4(o0, o1, o2, o3);
        }
    }

    if (CLS) {
        __syncthreads();
        int lane = tid & 63, wv = tid >> 6;   // 4 waves x 16 rows
        float bb0 = c_b0[lane], ww1 = c_w1[lane], bb1 = c_b1[0];
        #pragma unroll 1
        for (int q = 0; q < 16; ++q) {
            int row = wv * 16 + q;
            int node = base + row;
            if (node >= n) break;
            float s = bb0;
            #pragma unroll 4
            for (int k = 0; k < HID; k += 4) {
                float4 hv = *(const float4*)&lds[row][k];
                s = fmaf(hv.x, c_w0[(k + 0) * 64 + lane], s);
                s = fmaf(hv.y, c_w0[(k + 1) * 64 + lane], s);
                s = fmaf(hv.z, c_w0[(k + 2) * 64 + lane], s);
                s = fmaf(hv.w, c_w0[(k + 3) * 64 + lane], s);
            }
            s = fmaxf(s, 0.f);
            float t = s * ww1;
            #pragma unroll
            for (int m = 1; m < 64; m <<= 1) t += __shfl_xor(t, m);
            if (lane == 0) cls_out[node] = t + bb1;
        }
    }
}

extern "C" void kernel_launch(void* const* d_in, const int* in_sizes, int n_in,
                              void* d_out, int out_size, void* d_ws, size_t ws_size,
                              hipStream_t stream) {
    const float* x  = (const float*)d_in[0];
    const int*   ei = (const int*)d_in[1];     // integer inputs arrive as int32
    const float* w_l0 = (const float*)d_in[2];
    const float* b_l0 = (const float*)d_in[3];
    const float* w_r0 = (const float*)d_in[4];
    const float* lnw0 = (const float*)d_in[5];
    const float* lnb0 = (const float*)d_in[6];
    const float* w_l1 = (const float*)d_in[7];
    const float* b_l1 = (const float*)d_in[8];
    const float* w_r1 = (const float*)d_in[9];
    const float* lnw1 = (const float*)d_in[10];
    const float* lnb1 = (const float*)d_in[11];
    const float* w_l2 = (const float*)d_in[12];
    const float* b_l2 = (const float*)d_in[13];
    const float* w_r2 = (const float*)d_in[14];
    const float* lnw2 = (const float*)d_in[15];
    const float* lnb2 = (const float*)d_in[16];
    const float* c_w0 = (const float*)d_in[17];
    const float* c_b0 = (const float*)d_in[18];
    const float* c_w1 = (const float*)d_in[19];
    const float* c_b1 = (const float*)d_in[20];
    float* out = (float*)d_out;

    int N = in_sizes[0] / 11;
    int E = in_sizes[1] / 2;
    int nb = (N + 255) / 256;

    // workspace: [deg: N][rp: N+1][cursor: N][csr: E][part: nb] [bufA: N*HID][bufB: N*HID]
    int*   deg    = (int*)d_ws;
    int*   rp     = deg + N;
    int*   cursor = rp + (N + 1);
    int*   csr    = cursor + N;
    int*   part   = csr + E;
    float* bufA   = (float*)(part + ((nb + 63) & ~63));
    float* bufB   = bufA + (size_t)N * HID;

    // ---- CSR build ----
    hipMemsetAsync(deg, 0, (size_t)N * sizeof(int), stream);
    deg_kernel<<<(E + 255) / 256, 256, 0, stream>>>(ei, deg, E);
    part_kernel<<<nb, 256, 0, stream>>>(deg, part, N);
    scanpart_kernel<<<1, 1024, 0, stream>>>(part, nb);
    rp_kernel<<<nb, 256, 0, stream>>>(deg, part, rp, cursor, N);
    fill_kernel<<<(E + 255) / 256, 256, 0, stream>>>(ei, cursor, csr, E);

    int nodeBlocks = (N + 3) / 4;

    // ---- layer 0 ----
    layer0_kernel<<<nodeBlocks, 256, 0, stream>>>(x, rp, csr, w_l0, b_l0, w_r0, lnw0, lnb0, bufA, N);

    // ---- layer 1 ----
    aggp_kernel<<<nodeBlocks, 256, 0, stream>>>(rp, csr, bufA, bufB, N);
    layer_kernel<1, 0><<<(N + 63) / 64, 256, 0, stream>>>(bufB, bufA, w_l1, b_l1, w_r1, lnw1, lnb1,
                                                          bufA, nullptr, nullptr, nullptr, nullptr, nullptr, N);

    // ---- layer 2 + fused classifier ----
    aggp_kernel<<<nodeBlocks, 256, 0, stream>>>(rp, csr, bufA, bufB, N);
    layer_kernel<1, 1><<<(N + 63) / 64, 256, 0, stream>>>(bufB, bufA, w_l2, b_l2, w_r2, lnw2, lnb2,
                                                          nullptr, c_w0, c_b0, c_w1, c_b1, out, N);
}

// Round 10
// 452.516 us; speedup vs baseline: 1.1349x; 1.0144x over previous
//
#include <hip/hip_runtime.h>

#define HID 128

// ---------------- degree histogram (int) ----------------
__global__ __launch_bounds__(256) void deg_kernel(const int* __restrict__ ei,
                                                  int* __restrict__ deg, int E) {
    int e = blockIdx.x * 256 + threadIdx.x;
    if (e >= E) return;
    atomicAdd(&deg[ei[E + e]], 1);
}

// ---------------- scan stage 1: per-block (256 elems) sums ----------------
__global__ __launch_bounds__(256) void part_kernel(const int* __restrict__ deg,
                                                   int* __restrict__ part, int n) {
    int i = blockIdx.x * 256 + threadIdx.x;
    int v = (i < n) ? deg[i] : 0;
    #pragma unroll
    for (int m = 1; m < 64; m <<= 1) v += __shfl_xor(v, m);
    __shared__ int w[4];
    int lane = threadIdx.x & 63, wv = threadIdx.x >> 6;
    if (lane == 0) w[wv] = v;
    __syncthreads();
    if (threadIdx.x == 0) part[blockIdx.x] = w[0] + w[1] + w[2] + w[3];
}

// ---------------- scan stage 2: exclusive scan of block sums ----------------
__global__ __launch_bounds__(1024) void scanpart_kernel(int* __restrict__ part, int nb) {
    __shared__ int s[1024];
    int t = threadIdx.x;
    int v = (t < nb) ? part[t] : 0;
    int orig = v;
    s[t] = v;
    __syncthreads();
    for (int off = 1; off < 1024; off <<= 1) {
        int u = (t >= off) ? s[t - off] : 0;
        __syncthreads();
        s[t] += u;
        __syncthreads();
    }
    if (t < nb) part[t] = s[t] - orig;   // exclusive
}

// ---------------- scan stage 3: per-block exclusive scan -> rp, cursor ----------------
__global__ __launch_bounds__(256) void rp_kernel(const int* __restrict__ deg,
                                                 const int* __restrict__ part,
                                                 int* __restrict__ rp,
                                                 int* __restrict__ cursor, int n) {
    int tid = threadIdx.x, lane = tid & 63, wv = tid >> 6;
    int i = blockIdx.x * 256 + tid;
    int v = (i < n) ? deg[i] : 0;
    int orig = v;
    #pragma unroll
    for (int off = 1; off < 64; off <<= 1) {
        int t = __shfl_up(v, off);
        if (lane >= off) v += t;
    }
    __shared__ int wsum[4];
    if (lane == 63) wsum[wv] = v;
    __syncthreads();
    int wbase = 0;
    #pragma unroll
    for (int w = 0; w < 4; ++w) if (w < wv) wbase += wsum[w];
    int excl = part[blockIdx.x] + wbase + v - orig;
    if (i < n) { rp[i] = excl; cursor[i] = excl; }
    if (i == n - 1) rp[n] = excl + orig;
}

// ---------------- CSR fill ----------------
__global__ __launch_bounds__(256) void fill_kernel(const int* __restrict__ ei,
                                                   int* __restrict__ cursor,
                                                   int* __restrict__ csr_src, int E) {
    int e = blockIdx.x * 256 + threadIdx.x;
    if (e >= E) return;
    int dst = ei[E + e];
    int pos = atomicAdd(&cursor[dst], 1);
    csr_src[pos] = ei[e];
}

// ---------------- 128-dim pull aggregation: one wave per node, writes MEAN ----------------
__global__ __launch_bounds__(256) void aggp_kernel(const int* __restrict__ rp,
                                                   const int* __restrict__ ci,
                                                   const float* __restrict__ h,
                                                   float* __restrict__ agg, int n) {
    int node = (blockIdx.x * 256 + threadIdx.x) >> 6;
    if (node >= n) return;
    int lane = threadIdx.x & 63;
    float2 a0 = make_float2(0.f, 0.f), a1 = make_float2(0.f, 0.f);
    float2 a2 = make_float2(0.f, 0.f), a3 = make_float2(0.f, 0.f);
    float2 a4 = make_float2(0.f, 0.f), a5 = make_float2(0.f, 0.f);
    float2 a6 = make_float2(0.f, 0.f), a7 = make_float2(0.f, 0.f);
    int beg = rp[node], end = rp[node + 1];
    int j = beg;
    for (; j + 7 < end; j += 8) {
        int s0 = ci[j],     s1 = ci[j + 1], s2 = ci[j + 2], s3 = ci[j + 3];
        int s4 = ci[j + 4], s5 = ci[j + 5], s6 = ci[j + 6], s7 = ci[j + 7];
        float2 v0 = *(const float2*)(h + (size_t)s0 * HID + lane * 2);
        float2 v1 = *(const float2*)(h + (size_t)s1 * HID + lane * 2);
        float2 v2 = *(const float2*)(h + (size_t)s2 * HID + lane * 2);
        float2 v3 = *(const float2*)(h + (size_t)s3 * HID + lane * 2);
        float2 v4 = *(const float2*)(h + (size_t)s4 * HID + lane * 2);
        float2 v5 = *(const float2*)(h + (size_t)s5 * HID + lane * 2);
        float2 v6 = *(const float2*)(h + (size_t)s6 * HID + lane * 2);
        float2 v7 = *(const float2*)(h + (size_t)s7 * HID + lane * 2);
        a0.x += v0.x; a0.y += v0.y;  a1.x += v1.x; a1.y += v1.y;
        a2.x += v2.x; a2.y += v2.y;  a3.x += v3.x; a3.y += v3.y;
        a4.x += v4.x; a4.y += v4.y;  a5.x += v5.x; a5.y += v5.y;
        a6.x += v6.x; a6.y += v6.y;  a7.x += v7.x; a7.y += v7.y;
    }
    for (; j + 3 < end; j += 4) {
        int s0 = ci[j], s1 = ci[j + 1], s2 = ci[j + 2], s3 = ci[j + 3];
        float2 v0 = *(const float2*)(h + (size_t)s0 * HID + lane * 2);
        float2 v1 = *(const float2*)(h + (size_t)s1 * HID + lane * 2);
        float2 v2 = *(const float2*)(h + (size_t)s2 * HID + lane * 2);
        float2 v3 = *(const float2*)(h + (size_t)s3 * HID + lane * 2);
        a0.x += v0.x; a0.y += v0.y;  a1.x += v1.x; a1.y += v1.y;
        a2.x += v2.x; a2.y += v2.y;  a3.x += v3.x; a3.y += v3.y;
    }
    for (; j < end; ++j) {
        int s0 = ci[j];
        float2 v0 = *(const float2*)(h + (size_t)s0 * HID + lane * 2);
        a0.x += v0.x; a0.y += v0.y;
    }
    float inv = 1.0f / fmaxf((float)(end - beg), 1.0f);
    float2 o = make_float2((a0.x + a1.x + a2.x + a3.x + a4.x + a5.x + a6.x + a7.x) * inv,
                           (a0.y + a1.y + a2.y + a3.y + a4.y + a5.y + a6.y + a7.y) * inv);
    *(float2*)(agg + (size_t)node * HID + lane * 2) = o;
}

// ---------------- layer 0: fused 11-dim pull-agg + dual matmul + LN + ReLU ----------------
__global__ __launch_bounds__(256) void layer0_kernel(
    const float* __restrict__ x, const int* __restrict__ rp, const int* __restrict__ ci,
    const float* __restrict__ w_l, const float* __restrict__ b_l, const float* __restrict__ w_r,
    const float* __restrict__ ln_w, const float* __restrict__ ln_b,
    float* __restrict__ h_out, int n)
{
    int node = (blockIdx.x * 256 + threadIdx.x) >> 6;
    int lane = threadIdx.x & 63;
    if (node >= n) return;
    int beg = rp[node], end = rp[node + 1];
    int g = lane / 11;
    int d = lane - g * 11;
    float acc0 = 0.f, acc1 = 0.f;
    int j = beg + g;
    if (g < 5) {
        for (; j + 5 < end; j += 10) {
            int s0 = ci[j], s1 = ci[j + 5];
            acc0 += x[(size_t)s0 * 11 + d];
            acc1 += x[(size_t)s1 * 11 + d];
        }
        for (; j < end; j += 5) {
            int s0 = ci[j];
            acc0 += x[(size_t)s0 * 11 + d];
        }
    }
    float acc = acc0 + acc1;
    float aggk = 0.f;
    #pragma unroll
    for (int gg = 0; gg < 5; ++gg) {
        aggk += __shfl(acc, (lane < 11) ? (lane + 11 * gg) : lane);
    }
    float inv = 1.0f / fmaxf((float)(end - beg), 1.0f);
    float v0 = b_l[lane], v1 = b_l[lane + 64];
    #pragma unroll
    for (int k = 0; k < 11; ++k) {
        float a  = __shfl(aggk, k) * inv;
        float xi = x[(size_t)node * 11 + k];
        v0 += a * w_l[k * HID + lane]      + xi * w_r[k * HID + lane];
        v1 += a * w_l[k * HID + lane + 64] + xi * w_r[k * HID + lane + 64];
    }
    float s = v0 + v1, s2 = v0 * v0 + v1 * v1;
    #pragma unroll
    for (int m = 1; m < 64; m <<= 1) { s += __shfl_xor(s, m); s2 += __shfl_xor(s2, m); }
    float mu  = s * (1.0f / HID);
    float var = s2 * (1.0f / HID) - mu * mu;
    float rstd = rsqrtf(var + 1e-5f);
    float o0 = fmaxf((v0 - mu) * rstd * ln_w[lane]      + ln_b[lane],      0.0f);
    float o1 = fmaxf((v1 - mu) * rstd * ln_w[lane + 64] + ln_b[lane + 64], 0.0f);
    h_out[(size_t)node * HID + lane]      = o0;
    h_out[(size_t)node * HID + lane + 64] = o1;
}

// ---------------- layers 1/2: R4-exact GEMM (LDS tile, 8r x 4c, compiler-unrolled) ----------------
// 256 threads: tx = tid&31 (4 cols), ty = tid>>5 (8 rows) -> 64 nodes/block.
// Node rows staged to LDS (alias-safe). The nested half/k loops are left to the compiler
// to unroll & pipeline — R9 proved forcing unroll-1 + manual prefetch is 1.9x slower.
// CLS=1: epilogue keeps h in LDS and computes classifier; skips h_out entirely.
template<int RES, int CLS>
__global__ __launch_bounds__(256) void layer_kernel(
    const float* __restrict__ agg, const float* __restrict__ h_in,
    const float* __restrict__ w_l, const float* __restrict__ b_l, const float* __restrict__ w_r,
    const float* __restrict__ ln_w, const float* __restrict__ ln_b,
    float* __restrict__ h_out,
    const float* __restrict__ c_w0, const float* __restrict__ c_b0,
    const float* __restrict__ c_w1, const float* __restrict__ c_b1,
    float* __restrict__ cls_out, int n)
{
    __shared__ float lds[64][260];   // [node][agg(0..127) | h_in(128..255)], pad 4
    int base = blockIdx.x * 64;
    int tid = threadIdx.x;
    #pragma unroll
    for (int i = 0; i < 8; ++i) {
        int idx = tid + i * 256;        // float4 index over 64*128/4 = 2048
        int row = idx >> 5;
        int c4  = (idx & 31) * 4;
        int node = base + row;
        float4 a = make_float4(0.f, 0.f, 0.f, 0.f);
        float4 h = make_float4(0.f, 0.f, 0.f, 0.f);
        if (node < n) {
            a = *(const float4*)(agg  + (size_t)node * HID + c4);
            h = *(const float4*)(h_in + (size_t)node * HID + c4);
        }
        *(float4*)&lds[row][c4]       = a;
        *(float4*)&lds[row][HID + c4] = h;
    }
    __syncthreads();

    int tx = tid & 31, ty = tid >> 5;
    float acc[8][4];
    #pragma unroll
    for (int r = 0; r < 8; ++r) { acc[r][0] = acc[r][1] = acc[r][2] = acc[r][3] = 0.f; }

    const float* W = w_l;
    #pragma unroll
    for (int half = 0; half < 2; ++half) {
        int koff = half * HID;
        for (int k = 0; k < HID; k += 4) {
            float4 w0 = *(const float4*)(W + (size_t)(k + 0) * HID + tx * 4);
            float4 w1 = *(const float4*)(W + (size_t)(k + 1) * HID + tx * 4);
            float4 w2 = *(const float4*)(W + (size_t)(k + 2) * HID + tx * 4);
            float4 w3 = *(const float4*)(W + (size_t)(k + 3) * HID + tx * 4);
            #pragma unroll
            for (int r = 0; r < 8; ++r) {
                float4 a = *(const float4*)&lds[ty * 8 + r][koff + k];
                acc[r][0] = fmaf(a.x, w0.x, fmaf(a.y, w1.x, fmaf(a.z, w2.x, fmaf(a.w, w3.x, acc[r][0]))));
                acc[r][1] = fmaf(a.x, w0.y, fmaf(a.y, w1.y, fmaf(a.z, w2.y, fmaf(a.w, w3.y, acc[r][1]))));
                acc[r][2] = fmaf(a.x, w0.z, fmaf(a.y, w1.z, fmaf(a.z, w2.z, fmaf(a.w, w3.z, acc[r][2]))));
                acc[r][3] = fmaf(a.x, w0.w, fmaf(a.y, w1.w, fmaf(a.z, w2.w, fmaf(a.w, w3.w, acc[r][3]))));
            }
        }
        W = w_r;
    }

    if (CLS) __syncthreads();   // all agg-half reads done before epilogue overwrites it

    float4 bl = *(const float4*)(b_l  + tx * 4);
    float4 gw = *(const float4*)(ln_w + tx * 4);
    float4 gb = *(const float4*)(ln_b + tx * 4);
    #pragma unroll
    for (int r = 0; r < 8; ++r) {
        float v0 = acc[r][0] + bl.x, v1 = acc[r][1] + bl.y;
        float v2 = acc[r][2] + bl.z, v3 = acc[r][3] + bl.w;
        float s  = v0 + v1 + v2 + v3;
        float s2 = v0*v0 + v1*v1 + v2*v2 + v3*v3;
        #pragma unroll
        for (int m = 16; m >= 1; m >>= 1) { s += __shfl_xor(s, m); s2 += __shfl_xor(s2, m); }
        float mu  = s * (1.0f / HID);
        float var = s2 * (1.0f / HID) - mu * mu;
        float rstd = rsqrtf(var + 1e-5f);
        int row = ty * 8 + r;
        float o0 = fmaxf((v0 - mu) * rstd * gw.x + gb.x, 0.f);
        float o1 = fmaxf((v1 - mu) * rstd * gw.y + gb.y, 0.f);
        float o2 = fmaxf((v2 - mu) * rstd * gw.z + gb.z, 0.f);
        float o3 = fmaxf((v3 - mu) * rstd * gw.w + gb.w, 0.f);
        if (RES) {
            o0 += lds[row][HID + tx * 4 + 0];
            o1 += lds[row][HID + tx * 4 + 1];
            o2 += lds[row][HID + tx * 4 + 2];
            o3 += lds[row][HID + tx * 4 + 3];
        }
        int node = base + row;
        if (CLS) {
            *(float4*)&lds[row][tx * 4] = make_float4(o0, o1, o2, o3);
        } else if (node < n) {
            *(float4*)(h_out + (size_t)node * HID + tx * 4) = make_float4(o0, o1, o2, o3);
        }
    }

    if (CLS) {
        __syncthreads();
        int lane = tid & 63, wv = tid >> 6;   // 4 waves x 16 rows
        float bb0 = c_b0[lane], ww1 = c_w1[lane], bb1 = c_b1[0];
        #pragma unroll 1
        for (int q = 0; q < 16; ++q) {
            int row = wv * 16 + q;
            int node = base + row;
            if (node >= n) break;
            float s = bb0;
            #pragma unroll 4
            for (int k = 0; k < HID; k += 4) {
                float4 hv = *(const float4*)&lds[row][k];
                s = fmaf(hv.x, c_w0[(k + 0) * 64 + lane], s);
                s = fmaf(hv.y, c_w0[(k + 1) * 64 + lane], s);
                s = fmaf(hv.z, c_w0[(k + 2) * 64 + lane], s);
                s = fmaf(hv.w, c_w0[(k + 3) * 64 + lane], s);
            }
            s = fmaxf(s, 0.f);
            float t = s * ww1;
            #pragma unroll
            for (int m = 1; m < 64; m <<= 1) t += __shfl_xor(t, m);
            if (lane == 0) cls_out[node] = t + bb1;
        }
    }
}

extern "C" void kernel_launch(void* const* d_in, const int* in_sizes, int n_in,
                              void* d_out, int out_size, void* d_ws, size_t ws_size,
                              hipStream_t stream) {
    const float* x  = (const float*)d_in[0];
    const int*   ei = (const int*)d_in[1];     // integer inputs arrive as int32
    const float* w_l0 = (const float*)d_in[2];
    const float* b_l0 = (const float*)d_in[3];
    const float* w_r0 = (const float*)d_in[4];
    const float* lnw0 = (const float*)d_in[5];
    const float* lnb0 = (const float*)d_in[6];
    const float* w_l1 = (const float*)d_in[7];
    const float* b_l1 = (const float*)d_in[8];
    const float* w_r1 = (const float*)d_in[9];
    const float* lnw1 = (const float*)d_in[10];
    const float* lnb1 = (const float*)d_in[11];
    const float* w_l2 = (const float*)d_in[12];
    const float* b_l2 = (const float*)d_in[13];
    const float* w_r2 = (const float*)d_in[14];
    const float* lnw2 = (const float*)d_in[15];
    const float* lnb2 = (const float*)d_in[16];
    const float* c_w0 = (const float*)d_in[17];
    const float* c_b0 = (const float*)d_in[18];
    const float* c_w1 = (const float*)d_in[19];
    const float* c_b1 = (const float*)d_in[20];
    float* out = (float*)d_out;

    int N = in_sizes[0] / 11;
    int E = in_sizes[1] / 2;
    int nb = (N + 255) / 256;

    // workspace: [deg: N][rp: N+1][cursor: N][csr: E][part: nb] [bufA: N*HID][bufB: N*HID]
    int*   deg    = (int*)d_ws;
    int*   rp     = deg + N;
    int*   cursor = rp + (N + 1);
    int*   csr    = cursor + N;
    int*   part   = csr + E;
    float* bufA   = (float*)(part + ((nb + 63) & ~63));
    float* bufB   = bufA + (size_t)N * HID;

    // ---- CSR build ----
    hipMemsetAsync(deg, 0, (size_t)N * sizeof(int), stream);
    deg_kernel<<<(E + 255) / 256, 256, 0, stream>>>(ei, deg, E);
    part_kernel<<<nb, 256, 0, stream>>>(deg, part, N);
    scanpart_kernel<<<1, 1024, 0, stream>>>(part, nb);
    rp_kernel<<<nb, 256, 0, stream>>>(deg, part, rp, cursor, N);
    fill_kernel<<<(E + 255) / 256, 256, 0, stream>>>(ei, cursor, csr, E);

    int nodeBlocks = (N + 3) / 4;

    // ---- layer 0 ----
    layer0_kernel<<<nodeBlocks, 256, 0, stream>>>(x, rp, csr, w_l0, b_l0, w_r0, lnw0, lnb0, bufA, N);

    // ---- layer 1 ----
    aggp_kernel<<<nodeBlocks, 256, 0, stream>>>(rp, csr, bufA, bufB, N);
    layer_kernel<1, 0><<<(N + 63) / 64, 256, 0, stream>>>(bufB, bufA, w_l1, b_l1, w_r1, lnw1, lnb1,
                                                          bufA, nullptr, nullptr, nullptr, nullptr, nullptr, N);

    // ---- layer 2 + fused classifier ----
    aggp_kernel<<<nodeBlocks, 256, 0, stream>>>(rp, csr, bufA, bufB, N);
    layer_kernel<1, 1><<<(N + 63) / 64, 256, 0, stream>>>(bufB, bufA, w_l2, b_l2, w_r2, lnw2, lnb2,
                                                          nullptr, c_w0, c_b0, c_w1, c_b1, out, N);
}

// Round 11
// 411.344 us; speedup vs baseline: 1.2485x; 1.1001x over previous
//
#include <hip/hip_runtime.h>
#include <hip/hip_fp16.h>

#define HID 128

// ---------------- degree histogram (int) ----------------
__global__ __launch_bounds__(256) void deg_kernel(const int* __restrict__ ei,
                                                  int* __restrict__ deg, int E) {
    int e = blockIdx.x * 256 + threadIdx.x;
    if (e >= E) return;
    atomicAdd(&deg[ei[E + e]], 1);
}

// ---------------- scan stage 1: per-block (256 elems) sums ----------------
__global__ __launch_bounds__(256) void part_kernel(const int* __restrict__ deg,
                                                   int* __restrict__ part, int n) {
    int i = blockIdx.x * 256 + threadIdx.x;
    int v = (i < n) ? deg[i] : 0;
    #pragma unroll
    for (int m = 1; m < 64; m <<= 1) v += __shfl_xor(v, m);
    __shared__ int w[4];
    int lane = threadIdx.x & 63, wv = threadIdx.x >> 6;
    if (lane == 0) w[wv] = v;
    __syncthreads();
    if (threadIdx.x == 0) part[blockIdx.x] = w[0] + w[1] + w[2] + w[3];
}

// ---------------- scan stage 2: exclusive scan of block sums ----------------
__global__ __launch_bounds__(1024) void scanpart_kernel(int* __restrict__ part, int nb) {
    __shared__ int s[1024];
    int t = threadIdx.x;
    int v = (t < nb) ? part[t] : 0;
    int orig = v;
    s[t] = v;
    __syncthreads();
    for (int off = 1; off < 1024; off <<= 1) {
        int u = (t >= off) ? s[t - off] : 0;
        __syncthreads();
        s[t] += u;
        __syncthreads();
    }
    if (t < nb) part[t] = s[t] - orig;   // exclusive
}

// ---------------- scan stage 3: per-block exclusive scan -> rp, cursor ----------------
__global__ __launch_bounds__(256) void rp_kernel(const int* __restrict__ deg,
                                                 const int* __restrict__ part,
                                                 int* __restrict__ rp,
                                                 int* __restrict__ cursor, int n) {
    int tid = threadIdx.x, lane = tid & 63, wv = tid >> 6;
    int i = blockIdx.x * 256 + tid;
    int v = (i < n) ? deg[i] : 0;
    int orig = v;
    #pragma unroll
    for (int off = 1; off < 64; off <<= 1) {
        int t = __shfl_up(v, off);
        if (lane >= off) v += t;
    }
    __shared__ int wsum[4];
    if (lane == 63) wsum[wv] = v;
    __syncthreads();
    int wbase = 0;
    #pragma unroll
    for (int w = 0; w < 4; ++w) if (w < wv) wbase += wsum[w];
    int excl = part[blockIdx.x] + wbase + v - orig;
    if (i < n) { rp[i] = excl; cursor[i] = excl; }
    if (i == n - 1) rp[n] = excl + orig;
}

// ---------------- CSR fill ----------------
__global__ __launch_bounds__(256) void fill_kernel(const int* __restrict__ ei,
                                                   int* __restrict__ cursor,
                                                   int* __restrict__ csr_src, int E) {
    int e = blockIdx.x * 256 + threadIdx.x;
    if (e >= E) return;
    int dst = ei[E + e];
    int pos = atomicAdd(&cursor[dst], 1);
    csr_src[pos] = ei[e];
}

// ---------------- 128-dim pull aggregation from fp16 shadow: one wave per node, MEAN ----------------
__global__ __launch_bounds__(256) void aggp_kernel(const int* __restrict__ rp,
                                                   const int* __restrict__ ci,
                                                   const __half* __restrict__ h16,
                                                   float* __restrict__ agg, int n) {
    int node = (blockIdx.x * 256 + threadIdx.x) >> 6;
    if (node >= n) return;
    int lane = threadIdx.x & 63;
    float2 a0 = make_float2(0.f, 0.f), a1 = make_float2(0.f, 0.f);
    float2 a2 = make_float2(0.f, 0.f), a3 = make_float2(0.f, 0.f);
    float2 a4 = make_float2(0.f, 0.f), a5 = make_float2(0.f, 0.f);
    float2 a6 = make_float2(0.f, 0.f), a7 = make_float2(0.f, 0.f);
    int beg = rp[node], end = rp[node + 1];
    int j = beg;
    for (; j + 7 < end; j += 8) {
        int s0 = ci[j],     s1 = ci[j + 1], s2 = ci[j + 2], s3 = ci[j + 3];
        int s4 = ci[j + 4], s5 = ci[j + 5], s6 = ci[j + 6], s7 = ci[j + 7];
        __half2 v0 = *(const __half2*)(h16 + (size_t)s0 * HID + lane * 2);
        __half2 v1 = *(const __half2*)(h16 + (size_t)s1 * HID + lane * 2);
        __half2 v2 = *(const __half2*)(h16 + (size_t)s2 * HID + lane * 2);
        __half2 v3 = *(const __half2*)(h16 + (size_t)s3 * HID + lane * 2);
        __half2 v4 = *(const __half2*)(h16 + (size_t)s4 * HID + lane * 2);
        __half2 v5 = *(const __half2*)(h16 + (size_t)s5 * HID + lane * 2);
        __half2 v6 = *(const __half2*)(h16 + (size_t)s6 * HID + lane * 2);
        __half2 v7 = *(const __half2*)(h16 + (size_t)s7 * HID + lane * 2);
        float2 f0 = __half22float2(v0), f1 = __half22float2(v1);
        float2 f2 = __half22float2(v2), f3 = __half22float2(v3);
        float2 f4 = __half22float2(v4), f5 = __half22float2(v5);
        float2 f6 = __half22float2(v6), f7 = __half22float2(v7);
        a0.x += f0.x; a0.y += f0.y;  a1.x += f1.x; a1.y += f1.y;
        a2.x += f2.x; a2.y += f2.y;  a3.x += f3.x; a3.y += f3.y;
        a4.x += f4.x; a4.y += f4.y;  a5.x += f5.x; a5.y += f5.y;
        a6.x += f6.x; a6.y += f6.y;  a7.x += f7.x; a7.y += f7.y;
    }
    for (; j + 3 < end; j += 4) {
        int s0 = ci[j], s1 = ci[j + 1], s2 = ci[j + 2], s3 = ci[j + 3];
        float2 f0 = __half22float2(*(const __half2*)(h16 + (size_t)s0 * HID + lane * 2));
        float2 f1 = __half22float2(*(const __half2*)(h16 + (size_t)s1 * HID + lane * 2));
        float2 f2 = __half22float2(*(const __half2*)(h16 + (size_t)s2 * HID + lane * 2));
        float2 f3 = __half22float2(*(const __half2*)(h16 + (size_t)s3 * HID + lane * 2));
        a0.x += f0.x; a0.y += f0.y;  a1.x += f1.x; a1.y += f1.y;
        a2.x += f2.x; a2.y += f2.y;  a3.x += f3.x; a3.y += f3.y;
    }
    for (; j < end; ++j) {
        int s0 = ci[j];
        float2 f0 = __half22float2(*(const __half2*)(h16 + (size_t)s0 * HID + lane * 2));
        a0.x += f0.x; a0.y += f0.y;
    }
    float inv = 1.0f / fmaxf((float)(end - beg), 1.0f);
    float2 o = make_float2((a0.x + a1.x + a2.x + a3.x + a4.x + a5.x + a6.x + a7.x) * inv,
                           (a0.y + a1.y + a2.y + a3.y + a4.y + a5.y + a6.y + a7.y) * inv);
    *(float2*)(agg + (size_t)node * HID + lane * 2) = o;
}

// ---------------- layer 0: fused 11-dim pull-agg + dual matmul + LN + ReLU ----------------
// Writes fp32 h (bufA) + fp16 shadow h16 (for next layer's gather).
__global__ __launch_bounds__(256) void layer0_kernel(
    const float* __restrict__ x, const int* __restrict__ rp, const int* __restrict__ ci,
    const float* __restrict__ w_l, const float* __restrict__ b_l, const float* __restrict__ w_r,
    const float* __restrict__ ln_w, const float* __restrict__ ln_b,
    float* __restrict__ h_out, __half* __restrict__ h16, int n)
{
    int node = (blockIdx.x * 256 + threadIdx.x) >> 6;
    int lane = threadIdx.x & 63;
    if (node >= n) return;
    int beg = rp[node], end = rp[node + 1];
    int g = lane / 11;
    int d = lane - g * 11;
    float acc0 = 0.f, acc1 = 0.f;
    int j = beg + g;
    if (g < 5) {
        for (; j + 5 < end; j += 10) {
            int s0 = ci[j], s1 = ci[j + 5];
            acc0 += x[(size_t)s0 * 11 + d];
            acc1 += x[(size_t)s1 * 11 + d];
        }
        for (; j < end; j += 5) {
            int s0 = ci[j];
            acc0 += x[(size_t)s0 * 11 + d];
        }
    }
    float acc = acc0 + acc1;
    float aggk = 0.f;
    #pragma unroll
    for (int gg = 0; gg < 5; ++gg) {
        aggk += __shfl(acc, (lane < 11) ? (lane + 11 * gg) : lane);
    }
    float inv = 1.0f / fmaxf((float)(end - beg), 1.0f);
    float v0 = b_l[lane], v1 = b_l[lane + 64];
    #pragma unroll
    for (int k = 0; k < 11; ++k) {
        float a  = __shfl(aggk, k) * inv;
        float xi = x[(size_t)node * 11 + k];
        v0 += a * w_l[k * HID + lane]      + xi * w_r[k * HID + lane];
        v1 += a * w_l[k * HID + lane + 64] + xi * w_r[k * HID + lane + 64];
    }
    float s = v0 + v1, s2 = v0 * v0 + v1 * v1;
    #pragma unroll
    for (int m = 1; m < 64; m <<= 1) { s += __shfl_xor(s, m); s2 += __shfl_xor(s2, m); }
    float mu  = s * (1.0f / HID);
    float var = s2 * (1.0f / HID) - mu * mu;
    float rstd = rsqrtf(var + 1e-5f);
    float o0 = fmaxf((v0 - mu) * rstd * ln_w[lane]      + ln_b[lane],      0.0f);
    float o1 = fmaxf((v1 - mu) * rstd * ln_w[lane + 64] + ln_b[lane + 64], 0.0f);
    h_out[(size_t)node * HID + lane]      = o0;
    h_out[(size_t)node * HID + lane + 64] = o1;
    h16[(size_t)node * HID + lane]        = __float2half_rn(o0);
    h16[(size_t)node * HID + lane + 64]   = __float2half_rn(o1);
}

// ---------------- layers 1/2: R4-exact GEMM (LDS tile, 8r x 4c, compiler-unrolled) ----------------
// 256 threads: tx = tid&31 (4 cols), ty = tid>>5 (8 rows) -> 64 nodes/block.
// Node rows staged to LDS (alias-safe: block reads only its own 64 rows, all before writes).
// W16=1: also writes the fp16 shadow for the next layer's aggregation gather.
template<int RES, int W16>
__global__ __launch_bounds__(256) void layer_kernel(
    const float* __restrict__ agg, const float* __restrict__ h_in,
    const float* __restrict__ w_l, const float* __restrict__ b_l, const float* __restrict__ w_r,
    const float* __restrict__ ln_w, const float* __restrict__ ln_b,
    float* __restrict__ h_out, __half* __restrict__ h16, int n)
{
    __shared__ float lds[64][260];   // [node][agg(0..127) | h_in(128..255)], pad 4
    int base = blockIdx.x * 64;
    int tid = threadIdx.x;
    #pragma unroll
    for (int i = 0; i < 8; ++i) {
        int idx = tid + i * 256;        // float4 index over 64*128/4 = 2048
        int row = idx >> 5;
        int c4  = (idx & 31) * 4;
        int node = base + row;
        float4 a = make_float4(0.f, 0.f, 0.f, 0.f);
        float4 h = make_float4(0.f, 0.f, 0.f, 0.f);
        if (node < n) {
            a = *(const float4*)(agg  + (size_t)node * HID + c4);
            h = *(const float4*)(h_in + (size_t)node * HID + c4);
        }
        *(float4*)&lds[row][c4]       = a;
        *(float4*)&lds[row][HID + c4] = h;
    }
    __syncthreads();

    int tx = tid & 31, ty = tid >> 5;
    float acc[8][4];
    #pragma unroll
    for (int r = 0; r < 8; ++r) { acc[r][0] = acc[r][1] = acc[r][2] = acc[r][3] = 0.f; }

    const float* W = w_l;
    #pragma unroll
    for (int half = 0; half < 2; ++half) {
        int koff = half * HID;
        for (int k = 0; k < HID; k += 4) {
            float4 w0 = *(const float4*)(W + (size_t)(k + 0) * HID + tx * 4);
            float4 w1 = *(const float4*)(W + (size_t)(k + 1) * HID + tx * 4);
            float4 w2 = *(const float4*)(W + (size_t)(k + 2) * HID + tx * 4);
            float4 w3 = *(const float4*)(W + (size_t)(k + 3) * HID + tx * 4);
            #pragma unroll
            for (int r = 0; r < 8; ++r) {
                float4 a = *(const float4*)&lds[ty * 8 + r][koff + k];
                acc[r][0] = fmaf(a.x, w0.x, fmaf(a.y, w1.x, fmaf(a.z, w2.x, fmaf(a.w, w3.x, acc[r][0]))));
                acc[r][1] = fmaf(a.x, w0.y, fmaf(a.y, w1.y, fmaf(a.z, w2.y, fmaf(a.w, w3.y, acc[r][1]))));
                acc[r][2] = fmaf(a.x, w0.z, fmaf(a.y, w1.z, fmaf(a.z, w2.z, fmaf(a.w, w3.z, acc[r][2]))));
                acc[r][3] = fmaf(a.x, w0.w, fmaf(a.y, w1.w, fmaf(a.z, w2.w, fmaf(a.w, w3.w, acc[r][3]))));
            }
        }
        W = w_r;
    }

    float4 bl = *(const float4*)(b_l  + tx * 4);
    float4 gw = *(const float4*)(ln_w + tx * 4);
    float4 gb = *(const float4*)(ln_b + tx * 4);
    #pragma unroll
    for (int r = 0; r < 8; ++r) {
        float v0 = acc[r][0] + bl.x, v1 = acc[r][1] + bl.y;
        float v2 = acc[r][2] + bl.z, v3 = acc[r][3] + bl.w;
        float s  = v0 + v1 + v2 + v3;
        float s2 = v0*v0 + v1*v1 + v2*v2 + v3*v3;
        #pragma unroll
        for (int m = 16; m >= 1; m >>= 1) { s += __shfl_xor(s, m); s2 += __shfl_xor(s2, m); }
        float mu  = s * (1.0f / HID);
        float var = s2 * (1.0f / HID) - mu * mu;
        float rstd = rsqrtf(var + 1e-5f);
        int row = ty * 8 + r;
        float o0 = fmaxf((v0 - mu) * rstd * gw.x + gb.x, 0.f);
        float o1 = fmaxf((v1 - mu) * rstd * gw.y + gb.y, 0.f);
        float o2 = fmaxf((v2 - mu) * rstd * gw.z + gb.z, 0.f);
        float o3 = fmaxf((v3 - mu) * rstd * gw.w + gb.w, 0.f);
        if (RES) {
            o0 += lds[row][HID + tx * 4 + 0];
            o1 += lds[row][HID + tx * 4 + 1];
            o2 += lds[row][HID + tx * 4 + 2];
            o3 += lds[row][HID + tx * 4 + 3];
        }
        int node = base + row;
        if (node < n) {
            *(float4*)(h_out + (size_t)node * HID + tx * 4) = make_float4(o0, o1, o2, o3);
            if (W16) {
                __half2* d16 = (__half2*)(h16 + (size_t)node * HID + tx * 4);
                d16[0] = __floats2half2_rn(o0, o1);
                d16[1] = __floats2half2_rn(o2, o3);
            }
        }
    }
}

// ---------------- classifier: relu(h@c_w0+b0)@c_w1+b1, separate kernel (R4-proven) ----------------
__global__ __launch_bounds__(256) void cls_kernel(
    const float* __restrict__ h, const float* __restrict__ w0, const float* __restrict__ b0,
    const float* __restrict__ w1, const float* __restrict__ b1, float* __restrict__ out, int n)
{
    __shared__ float w0s[HID * 64];
    __shared__ float w1s[64];
    int tid = threadIdx.x;
    #pragma unroll
    for (int i = 0; i < 32; ++i) w0s[tid + i * 256] = w0[tid + i * 256];
    if (tid < 64) w1s[tid] = w1[tid];
    __syncthreads();
    int lane = tid & 63, wv = tid >> 6;
    float bb0 = b0[lane], bb1 = b1[0];
    for (int i = 0; i < 16; ++i) {
        int node = blockIdx.x * 64 + wv * 16 + i;
        if (node >= n) break;
        const float* hr = h + (size_t)node * HID;
        float s = bb0;
        #pragma unroll 4
        for (int k = 0; k < HID; k += 4) {
            float4 hv = *(const float4*)(hr + k);
            s = fmaf(hv.x, w0s[(k + 0) * 64 + lane], s);
            s = fmaf(hv.y, w0s[(k + 1) * 64 + lane], s);
            s = fmaf(hv.z, w0s[(k + 2) * 64 + lane], s);
            s = fmaf(hv.w, w0s[(k + 3) * 64 + lane], s);
        }
        s = fmaxf(s, 0.f);
        float t = s * w1s[lane];
        #pragma unroll
        for (int m = 1; m < 64; m <<= 1) t += __shfl_xor(t, m);
        if (lane == 0) out[node] = t + bb1;
    }
}

extern "C" void kernel_launch(void* const* d_in, const int* in_sizes, int n_in,
                              void* d_out, int out_size, void* d_ws, size_t ws_size,
                              hipStream_t stream) {
    const float* x  = (const float*)d_in[0];
    const int*   ei = (const int*)d_in[1];     // integer inputs arrive as int32
    const float* w_l0 = (const float*)d_in[2];
    const float* b_l0 = (const float*)d_in[3];
    const float* w_r0 = (const float*)d_in[4];
    const float* lnw0 = (const float*)d_in[5];
    const float* lnb0 = (const float*)d_in[6];
    const float* w_l1 = (const float*)d_in[7];
    const float* b_l1 = (const float*)d_in[8];
    const float* w_r1 = (const float*)d_in[9];
    const float* lnw1 = (const float*)d_in[10];
    const float* lnb1 = (const float*)d_in[11];
    const float* w_l2 = (const float*)d_in[12];
    const float* b_l2 = (const float*)d_in[13];
    const float* w_r2 = (const float*)d_in[14];
    const float* lnw2 = (const float*)d_in[15];
    const float* lnb2 = (const float*)d_in[16];
    const float* c_w0 = (const float*)d_in[17];
    const float* c_b0 = (const float*)d_in[18];
    const float* c_w1 = (const float*)d_in[19];
    const float* c_b1 = (const float*)d_in[20];
    float* out = (float*)d_out;

    int N = in_sizes[0] / 11;
    int E = in_sizes[1] / 2;
    int nb = (N + 255) / 256;

    // workspace: [deg: N][rp: N+1][cursor: N][csr: E][part: nb] [bufA: N*HID][bufB: N*HID][h16: N*HID halves]
    int*    deg    = (int*)d_ws;
    int*    rp     = deg + N;
    int*    cursor = rp + (N + 1);
    int*    csr    = cursor + N;
    int*    part   = csr + E;
    float*  bufA   = (float*)(part + ((nb + 63) & ~63));
    float*  bufB   = bufA + (size_t)N * HID;
    __half* h16    = (__half*)(bufB + (size_t)N * HID);

    // ---- CSR build ----
    hipMemsetAsync(deg, 0, (size_t)N * sizeof(int), stream);
    deg_kernel<<<(E + 255) / 256, 256, 0, stream>>>(ei, deg, E);
    part_kernel<<<nb, 256, 0, stream>>>(deg, part, N);
    scanpart_kernel<<<1, 1024, 0, stream>>>(part, nb);
    rp_kernel<<<nb, 256, 0, stream>>>(deg, part, rp, cursor, N);
    fill_kernel<<<(E + 255) / 256, 256, 0, stream>>>(ei, cursor, csr, E);

    int nodeBlocks = (N + 3) / 4;

    // ---- layer 0 ----  h0 -> bufA (fp32) + h16
    layer0_kernel<<<nodeBlocks, 256, 0, stream>>>(x, rp, csr, w_l0, b_l0, w_r0, lnw0, lnb0,
                                                  bufA, h16, N);

    // ---- layer 1 ----  gather(h16)->bufB ; layer(bufB, bufA) -> bufA + h16
    aggp_kernel<<<nodeBlocks, 256, 0, stream>>>(rp, csr, h16, bufB, N);
    layer_kernel<1, 1><<<(N + 63) / 64, 256, 0, stream>>>(bufB, bufA, w_l1, b_l1, w_r1, lnw1, lnb1,
                                                          bufA, h16, N);

    // ---- layer 2 ----  gather(h16)->bufB ; layer(bufB, bufA) -> bufA (no h16 needed)
    aggp_kernel<<<nodeBlocks, 256, 0, stream>>>(rp, csr, h16, bufB, N);
    layer_kernel<1, 0><<<(N + 63) / 64, 256, 0, stream>>>(bufB, bufA, w_l2, b_l2, w_r2, lnw2, lnb2,
                                                          bufA, nullptr, N);

    // ---- classifier ----
    cls_kernel<<<(N + 63) / 64, 256, 0, stream>>>(bufA, c_w0, c_b0, c_w1, c_b1, out, N);
}

// Round 12
// 378.935 us; speedup vs baseline: 1.3553x; 1.0855x over previous
//
#include <hip/hip_runtime.h>
#include <hip/hip_fp16.h>

#define HID 128

// ---------------- degree histogram (int) ----------------
__global__ __launch_bounds__(256) void deg_kernel(const int* __restrict__ ei,
                                                  int* __restrict__ deg, int E) {
    int e = blockIdx.x * 256 + threadIdx.x;
    if (e >= E) return;
    atomicAdd(&deg[ei[E + e]], 1);
}

// ---------------- scan stage 1: per-block (256 elems) sums ----------------
__global__ __launch_bounds__(256) void part_kernel(const int* __restrict__ deg,
                                                   int* __restrict__ part, int n) {
    int i = blockIdx.x * 256 + threadIdx.x;
    int v = (i < n) ? deg[i] : 0;
    #pragma unroll
    for (int m = 1; m < 64; m <<= 1) v += __shfl_xor(v, m);
    __shared__ int w[4];
    int lane = threadIdx.x & 63, wv = threadIdx.x >> 6;
    if (lane == 0) w[wv] = v;
    __syncthreads();
    if (threadIdx.x == 0) part[blockIdx.x] = w[0] + w[1] + w[2] + w[3];
}

// ---------------- scan stage 2: exclusive scan of block sums ----------------
__global__ __launch_bounds__(1024) void scanpart_kernel(int* __restrict__ part, int nb) {
    __shared__ int s[1024];
    int t = threadIdx.x;
    int v = (t < nb) ? part[t] : 0;
    int orig = v;
    s[t] = v;
    __syncthreads();
    for (int off = 1; off < 1024; off <<= 1) {
        int u = (t >= off) ? s[t - off] : 0;
        __syncthreads();
        s[t] += u;
        __syncthreads();
    }
    if (t < nb) part[t] = s[t] - orig;   // exclusive
}

// ---------------- scan stage 3: per-block exclusive scan -> rp, cursor ----------------
__global__ __launch_bounds__(256) void rp_kernel(const int* __restrict__ deg,
                                                 const int* __restrict__ part,
                                                 int* __restrict__ rp,
                                                 int* __restrict__ cursor, int n) {
    int tid = threadIdx.x, lane = tid & 63, wv = tid >> 6;
    int i = blockIdx.x * 256 + tid;
    int v = (i < n) ? deg[i] : 0;
    int orig = v;
    #pragma unroll
    for (int off = 1; off < 64; off <<= 1) {
        int t = __shfl_up(v, off);
        if (lane >= off) v += t;
    }
    __shared__ int wsum[4];
    if (lane == 63) wsum[wv] = v;
    __syncthreads();
    int wbase = 0;
    #pragma unroll
    for (int w = 0; w < 4; ++w) if (w < wv) wbase += wsum[w];
    int excl = part[blockIdx.x] + wbase + v - orig;
    if (i < n) { rp[i] = excl; cursor[i] = excl; }
    if (i == n - 1) rp[n] = excl + orig;
}

// ---------------- CSR fill ----------------
__global__ __launch_bounds__(256) void fill_kernel(const int* __restrict__ ei,
                                                   int* __restrict__ cursor,
                                                   int* __restrict__ csr_src, int E) {
    int e = blockIdx.x * 256 + threadIdx.x;
    if (e >= E) return;
    int dst = ei[E + e];
    int pos = atomicAdd(&cursor[dst], 1);
    csr_src[pos] = ei[e];
}

// ---------------- 128-dim pull aggregation (fp16 in, fp32 sum, fp16 MEAN out) ----------------
__global__ __launch_bounds__(256) void aggp_kernel(const int* __restrict__ rp,
                                                   const int* __restrict__ ci,
                                                   const __half* __restrict__ h16,
                                                   __half* __restrict__ agg16, int n) {
    int node = (blockIdx.x * 256 + threadIdx.x) >> 6;
    if (node >= n) return;
    int lane = threadIdx.x & 63;
    float2 a0 = make_float2(0.f, 0.f), a1 = make_float2(0.f, 0.f);
    float2 a2 = make_float2(0.f, 0.f), a3 = make_float2(0.f, 0.f);
    float2 a4 = make_float2(0.f, 0.f), a5 = make_float2(0.f, 0.f);
    float2 a6 = make_float2(0.f, 0.f), a7 = make_float2(0.f, 0.f);
    int beg = rp[node], end = rp[node + 1];
    int j = beg;
    for (; j + 7 < end; j += 8) {
        int s0 = ci[j],     s1 = ci[j + 1], s2 = ci[j + 2], s3 = ci[j + 3];
        int s4 = ci[j + 4], s5 = ci[j + 5], s6 = ci[j + 6], s7 = ci[j + 7];
        float2 f0 = __half22float2(*(const __half2*)(h16 + (size_t)s0 * HID + lane * 2));
        float2 f1 = __half22float2(*(const __half2*)(h16 + (size_t)s1 * HID + lane * 2));
        float2 f2 = __half22float2(*(const __half2*)(h16 + (size_t)s2 * HID + lane * 2));
        float2 f3 = __half22float2(*(const __half2*)(h16 + (size_t)s3 * HID + lane * 2));
        float2 f4 = __half22float2(*(const __half2*)(h16 + (size_t)s4 * HID + lane * 2));
        float2 f5 = __half22float2(*(const __half2*)(h16 + (size_t)s5 * HID + lane * 2));
        float2 f6 = __half22float2(*(const __half2*)(h16 + (size_t)s6 * HID + lane * 2));
        float2 f7 = __half22float2(*(const __half2*)(h16 + (size_t)s7 * HID + lane * 2));
        a0.x += f0.x; a0.y += f0.y;  a1.x += f1.x; a1.y += f1.y;
        a2.x += f2.x; a2.y += f2.y;  a3.x += f3.x; a3.y += f3.y;
        a4.x += f4.x; a4.y += f4.y;  a5.x += f5.x; a5.y += f5.y;
        a6.x += f6.x; a6.y += f6.y;  a7.x += f7.x; a7.y += f7.y;
    }
    for (; j + 3 < end; j += 4) {
        int s0 = ci[j], s1 = ci[j + 1], s2 = ci[j + 2], s3 = ci[j + 3];
        float2 f0 = __half22float2(*(const __half2*)(h16 + (size_t)s0 * HID + lane * 2));
        float2 f1 = __half22float2(*(const __half2*)(h16 + (size_t)s1 * HID + lane * 2));
        float2 f2 = __half22float2(*(const __half2*)(h16 + (size_t)s2 * HID + lane * 2));
        float2 f3 = __half22float2(*(const __half2*)(h16 + (size_t)s3 * HID + lane * 2));
        a0.x += f0.x; a0.y += f0.y;  a1.x += f1.x; a1.y += f1.y;
        a2.x += f2.x; a2.y += f2.y;  a3.x += f3.x; a3.y += f3.y;
    }
    for (; j < end; ++j) {
        int s0 = ci[j];
        float2 f0 = __half22float2(*(const __half2*)(h16 + (size_t)s0 * HID + lane * 2));
        a0.x += f0.x; a0.y += f0.y;
    }
    float inv = 1.0f / fmaxf((float)(end - beg), 1.0f);
    float ox = (a0.x + a1.x + a2.x + a3.x + a4.x + a5.x + a6.x + a7.x) * inv;
    float oy = (a0.y + a1.y + a2.y + a3.y + a4.y + a5.y + a6.y + a7.y) * inv;
    *(__half2*)(agg16 + (size_t)node * HID + lane * 2) = __floats2half2_rn(ox, oy);
}

// ---------------- layer 0: fused 11-dim pull-agg + dual matmul + LN + ReLU -> h16 ----------------
__global__ __launch_bounds__(256) void layer0_kernel(
    const float* __restrict__ x, const int* __restrict__ rp, const int* __restrict__ ci,
    const float* __restrict__ w_l, const float* __restrict__ b_l, const float* __restrict__ w_r,
    const float* __restrict__ ln_w, const float* __restrict__ ln_b,
    __half* __restrict__ h16, int n)
{
    int node = (blockIdx.x * 256 + threadIdx.x) >> 6;
    int lane = threadIdx.x & 63;
    if (node >= n) return;
    int beg = rp[node], end = rp[node + 1];
    int g = lane / 11;
    int d = lane - g * 11;
    float acc0 = 0.f, acc1 = 0.f;
    int j = beg + g;
    if (g < 5) {
        for (; j + 5 < end; j += 10) {
            int s0 = ci[j], s1 = ci[j + 5];
            acc0 += x[(size_t)s0 * 11 + d];
            acc1 += x[(size_t)s1 * 11 + d];
        }
        for (; j < end; j += 5) {
            int s0 = ci[j];
            acc0 += x[(size_t)s0 * 11 + d];
        }
    }
    float acc = acc0 + acc1;
    float aggk = 0.f;
    #pragma unroll
    for (int gg = 0; gg < 5; ++gg) {
        aggk += __shfl(acc, (lane < 11) ? (lane + 11 * gg) : lane);
    }
    float inv = 1.0f / fmaxf((float)(end - beg), 1.0f);
    float v0 = b_l[lane], v1 = b_l[lane + 64];
    #pragma unroll
    for (int k = 0; k < 11; ++k) {
        float a  = __shfl(aggk, k) * inv;
        float xi = x[(size_t)node * 11 + k];
        v0 += a * w_l[k * HID + lane]      + xi * w_r[k * HID + lane];
        v1 += a * w_l[k * HID + lane + 64] + xi * w_r[k * HID + lane + 64];
    }
    float s = v0 + v1, s2 = v0 * v0 + v1 * v1;
    #pragma unroll
    for (int m = 1; m < 64; m <<= 1) { s += __shfl_xor(s, m); s2 += __shfl_xor(s2, m); }
    float mu  = s * (1.0f / HID);
    float var = s2 * (1.0f / HID) - mu * mu;
    float rstd = rsqrtf(var + 1e-5f);
    float o0 = fmaxf((v0 - mu) * rstd * ln_w[lane]      + ln_b[lane],      0.0f);
    float o1 = fmaxf((v1 - mu) * rstd * ln_w[lane + 64] + ln_b[lane + 64], 0.0f);
    h16[(size_t)node * HID + lane]      = __float2half_rn(o0);
    h16[(size_t)node * HID + lane + 64] = __float2half_rn(o1);
}

// ---------------- layers 1/2: fp16-LDS GEMM (R4 shape, half tile -> 4 blocks/CU) ----------------
// 256 threads: tx = tid&31 (4 cols), ty = tid>>5 (8 rows) -> 64 nodes/block.
// LDS tile [64][264] halves = 33.8 KB (agg 0..127 | h_in 128..255). fp32 weights + fp32 FMA.
// Alias-safe (h16out == h16in): block stages its own 64 rows fully before any global write.
__global__ __launch_bounds__(256) void layer_kernel(
    const __half* __restrict__ agg16, const __half* __restrict__ h16in,
    const float* __restrict__ w_l, const float* __restrict__ b_l, const float* __restrict__ w_r,
    const float* __restrict__ ln_w, const float* __restrict__ ln_b,
    __half* __restrict__ h16out, int n)
{
    __shared__ __half lds[64][264];
    int base = blockIdx.x * 64;
    int tid = threadIdx.x;
    #pragma unroll
    for (int i = 0; i < 8; ++i) {
        int idx = tid + i * 256;        // 2048 chunks of 4 halves (8B) per source
        int row = idx >> 5;
        int c4  = (idx & 31) * 4;
        int node = base + row;
        float2 a = make_float2(0.f, 0.f);   // raw 4-half payloads
        float2 h = make_float2(0.f, 0.f);
        if (node < n) {
            a = *(const float2*)(agg16 + (size_t)node * HID + c4);
            h = *(const float2*)(h16in + (size_t)node * HID + c4);
        }
        *(float2*)&lds[row][c4]       = a;
        *(float2*)&lds[row][HID + c4] = h;
    }
    __syncthreads();

    int tx = tid & 31, ty = tid >> 5;
    float acc[8][4];
    #pragma unroll
    for (int r = 0; r < 8; ++r) { acc[r][0] = acc[r][1] = acc[r][2] = acc[r][3] = 0.f; }

    const float* W = w_l;
    #pragma unroll
    for (int half = 0; half < 2; ++half) {
        int koff = half * HID;
        for (int k = 0; k < HID; k += 4) {
            float4 w0 = *(const float4*)(W + (size_t)(k + 0) * HID + tx * 4);
            float4 w1 = *(const float4*)(W + (size_t)(k + 1) * HID + tx * 4);
            float4 w2 = *(const float4*)(W + (size_t)(k + 2) * HID + tx * 4);
            float4 w3 = *(const float4*)(W + (size_t)(k + 3) * HID + tx * 4);
            #pragma unroll
            for (int r = 0; r < 8; ++r) {
                float2 raw = *(const float2*)&lds[ty * 8 + r][koff + k];
                const __half2* hp = (const __half2*)&raw;
                float2 lo = __half22float2(hp[0]);
                float2 hi = __half22float2(hp[1]);
                acc[r][0] = fmaf(lo.x, w0.x, fmaf(lo.y, w1.x, fmaf(hi.x, w2.x, fmaf(hi.y, w3.x, acc[r][0]))));
                acc[r][1] = fmaf(lo.x, w0.y, fmaf(lo.y, w1.y, fmaf(hi.x, w2.y, fmaf(hi.y, w3.y, acc[r][1]))));
                acc[r][2] = fmaf(lo.x, w0.z, fmaf(lo.y, w1.z, fmaf(hi.x, w2.z, fmaf(hi.y, w3.z, acc[r][2]))));
                acc[r][3] = fmaf(lo.x, w0.w, fmaf(lo.y, w1.w, fmaf(hi.x, w2.w, fmaf(hi.y, w3.w, acc[r][3]))));
            }
        }
        W = w_r;
    }

    float4 bl = *(const float4*)(b_l  + tx * 4);
    float4 gw = *(const float4*)(ln_w + tx * 4);
    float4 gb = *(const float4*)(ln_b + tx * 4);
    #pragma unroll
    for (int r = 0; r < 8; ++r) {
        float v0 = acc[r][0] + bl.x, v1 = acc[r][1] + bl.y;
        float v2 = acc[r][2] + bl.z, v3 = acc[r][3] + bl.w;
        float s  = v0 + v1 + v2 + v3;
        float s2 = v0*v0 + v1*v1 + v2*v2 + v3*v3;
        #pragma unroll
        for (int m = 16; m >= 1; m >>= 1) { s += __shfl_xor(s, m); s2 += __shfl_xor(s2, m); }
        float mu  = s * (1.0f / HID);
        float var = s2 * (1.0f / HID) - mu * mu;
        float rstd = rsqrtf(var + 1e-5f);
        int row = ty * 8 + r;
        float o0 = fmaxf((v0 - mu) * rstd * gw.x + gb.x, 0.f);
        float o1 = fmaxf((v1 - mu) * rstd * gw.y + gb.y, 0.f);
        float o2 = fmaxf((v2 - mu) * rstd * gw.z + gb.z, 0.f);
        float o3 = fmaxf((v3 - mu) * rstd * gw.w + gb.w, 0.f);
        // residual from fp16 h_in tile
        float2 r01 = __half22float2(*(const __half2*)&lds[row][HID + tx * 4]);
        float2 r23 = __half22float2(*(const __half2*)&lds[row][HID + tx * 4 + 2]);
        o0 += r01.x; o1 += r01.y; o2 += r23.x; o3 += r23.y;
        int node = base + row;
        if (node < n) {
            __half2* d16 = (__half2*)(h16out + (size_t)node * HID + tx * 4);
            d16[0] = __floats2half2_rn(o0, o1);
            d16[1] = __floats2half2_rn(o2, o3);
        }
    }
}

// ---------------- classifier: relu(h@c_w0+b0)@c_w1+b1 from fp16 h ----------------
__global__ __launch_bounds__(256) void cls_kernel(
    const __half* __restrict__ h, const float* __restrict__ w0, const float* __restrict__ b0,
    const float* __restrict__ w1, const float* __restrict__ b1, float* __restrict__ out, int n)
{
    __shared__ float w0s[HID * 64];
    __shared__ float w1s[64];
    int tid = threadIdx.x;
    #pragma unroll
    for (int i = 0; i < 32; ++i) w0s[tid + i * 256] = w0[tid + i * 256];
    if (tid < 64) w1s[tid] = w1[tid];
    __syncthreads();
    int lane = tid & 63, wv = tid >> 6;
    float bb0 = b0[lane], bb1 = b1[0];
    for (int i = 0; i < 16; ++i) {
        int node = blockIdx.x * 64 + wv * 16 + i;
        if (node >= n) break;
        const __half* hr = h + (size_t)node * HID;
        float s = bb0;
        #pragma unroll 4
        for (int k = 0; k < HID; k += 4) {
            float2 lo = __half22float2(*(const __half2*)(hr + k));
            float2 hi = __half22float2(*(const __half2*)(hr + k + 2));
            s = fmaf(lo.x, w0s[(k + 0) * 64 + lane], s);
            s = fmaf(lo.y, w0s[(k + 1) * 64 + lane], s);
            s = fmaf(hi.x, w0s[(k + 2) * 64 + lane], s);
            s = fmaf(hi.y, w0s[(k + 3) * 64 + lane], s);
        }
        s = fmaxf(s, 0.f);
        float t = s * w1s[lane];
        #pragma unroll
        for (int m = 1; m < 64; m <<= 1) t += __shfl_xor(t, m);
        if (lane == 0) out[node] = t + bb1;
    }
}

extern "C" void kernel_launch(void* const* d_in, const int* in_sizes, int n_in,
                              void* d_out, int out_size, void* d_ws, size_t ws_size,
                              hipStream_t stream) {
    const float* x  = (const float*)d_in[0];
    const int*   ei = (const int*)d_in[1];     // integer inputs arrive as int32
    const float* w_l0 = (const float*)d_in[2];
    const float* b_l0 = (const float*)d_in[3];
    const float* w_r0 = (const float*)d_in[4];
    const float* lnw0 = (const float*)d_in[5];
    const float* lnb0 = (const float*)d_in[6];
    const float* w_l1 = (const float*)d_in[7];
    const float* b_l1 = (const float*)d_in[8];
    const float* w_r1 = (const float*)d_in[9];
    const float* lnw1 = (const float*)d_in[10];
    const float* lnb1 = (const float*)d_in[11];
    const float* w_l2 = (const float*)d_in[12];
    const float* b_l2 = (const float*)d_in[13];
    const float* w_r2 = (const float*)d_in[14];
    const float* lnw2 = (const float*)d_in[15];
    const float* lnb2 = (const float*)d_in[16];
    const float* c_w0 = (const float*)d_in[17];
    const float* c_b0 = (const float*)d_in[18];
    const float* c_w1 = (const float*)d_in[19];
    const float* c_b1 = (const float*)d_in[20];
    float* out = (float*)d_out;

    int N = in_sizes[0] / 11;
    int E = in_sizes[1] / 2;
    int nb = (N + 255) / 256;

    // workspace: [deg: N][rp: N+1][cursor: N][csr: E][part: nb] [h16: N*HID halves][agg16: N*HID halves]
    int*    deg    = (int*)d_ws;
    int*    rp     = deg + N;
    int*    cursor = rp + (N + 1);
    int*    csr    = cursor + N;
    int*    part   = csr + E;
    __half* h16    = (__half*)(part + ((nb + 63) & ~63));
    __half* agg16  = h16 + (size_t)N * HID;

    // ---- CSR build ----
    hipMemsetAsync(deg, 0, (size_t)N * sizeof(int), stream);
    deg_kernel<<<(E + 255) / 256, 256, 0, stream>>>(ei, deg, E);
    part_kernel<<<nb, 256, 0, stream>>>(deg, part, N);
    scanpart_kernel<<<1, 1024, 0, stream>>>(part, nb);
    rp_kernel<<<nb, 256, 0, stream>>>(deg, part, rp, cursor, N);
    fill_kernel<<<(E + 255) / 256, 256, 0, stream>>>(ei, cursor, csr, E);

    int nodeBlocks = (N + 3) / 4;

    // ---- layer 0 ----  h0 -> h16
    layer0_kernel<<<nodeBlocks, 256, 0, stream>>>(x, rp, csr, w_l0, b_l0, w_r0, lnw0, lnb0, h16, N);

    // ---- layer 1 ----  gather(h16)->agg16 ; layer(agg16, h16) -> h16 (alias-safe, LDS staged)
    aggp_kernel<<<nodeBlocks, 256, 0, stream>>>(rp, csr, h16, agg16, N);
    layer_kernel<<<(N + 63) / 64, 256, 0, stream>>>(agg16, h16, w_l1, b_l1, w_r1, lnw1, lnb1, h16, N);

    // ---- layer 2 ----
    aggp_kernel<<<nodeBlocks, 256, 0, stream>>>(rp, csr, h16, agg16, N);
    layer_kernel<<<(N + 63) / 64, 256, 0, stream>>>(agg16, h16, w_l2, b_l2, w_r2, lnw2, lnb2, h16, N);

    // ---- classifier ----
    cls_kernel<<<(N + 63) / 64, 256, 0, stream>>>(h16, c_w0, c_b0, c_w1, c_b1, out, N);
}

// Round 13
// 350.476 us; speedup vs baseline: 1.4654x; 1.0812x over previous
//
#include <hip/hip_runtime.h>
#include <hip/hip_fp16.h>

#define HID 128

typedef _Float16 h2_t __attribute__((ext_vector_type(2)));

static __device__ __forceinline__ float fdot2(__half2 a, __half2 b, float c) {
    return __builtin_amdgcn_fdot2(__builtin_bit_cast(h2_t, a), __builtin_bit_cast(h2_t, b), c, false);
}

// ---------------- degree histogram (int) ----------------
__global__ __launch_bounds__(256) void deg_kernel(const int* __restrict__ ei,
                                                  int* __restrict__ deg, int E) {
    int e = blockIdx.x * 256 + threadIdx.x;
    if (e >= E) return;
    atomicAdd(&deg[ei[E + e]], 1);
}

// ---------------- scan stage 1: per-block (256 elems) sums ----------------
__global__ __launch_bounds__(256) void part_kernel(const int* __restrict__ deg,
                                                   int* __restrict__ part, int n) {
    int i = blockIdx.x * 256 + threadIdx.x;
    int v = (i < n) ? deg[i] : 0;
    #pragma unroll
    for (int m = 1; m < 64; m <<= 1) v += __shfl_xor(v, m);
    __shared__ int w[4];
    int lane = threadIdx.x & 63, wv = threadIdx.x >> 6;
    if (lane == 0) w[wv] = v;
    __syncthreads();
    if (threadIdx.x == 0) part[blockIdx.x] = w[0] + w[1] + w[2] + w[3];
}

// ---------------- scan stage 2: exclusive scan of block sums ----------------
__global__ __launch_bounds__(1024) void scanpart_kernel(int* __restrict__ part, int nb) {
    __shared__ int s[1024];
    int t = threadIdx.x;
    int v = (t < nb) ? part[t] : 0;
    int orig = v;
    s[t] = v;
    __syncthreads();
    for (int off = 1; off < 1024; off <<= 1) {
        int u = (t >= off) ? s[t - off] : 0;
        __syncthreads();
        s[t] += u;
        __syncthreads();
    }
    if (t < nb) part[t] = s[t] - orig;   // exclusive
}

// ---------------- scan stage 3: per-block exclusive scan -> rp, cursor ----------------
__global__ __launch_bounds__(256) void rp_kernel(const int* __restrict__ deg,
                                                 const int* __restrict__ part,
                                                 int* __restrict__ rp,
                                                 int* __restrict__ cursor, int n) {
    int tid = threadIdx.x, lane = tid & 63, wv = tid >> 6;
    int i = blockIdx.x * 256 + tid;
    int v = (i < n) ? deg[i] : 0;
    int orig = v;
    #pragma unroll
    for (int off = 1; off < 64; off <<= 1) {
        int t = __shfl_up(v, off);
        if (lane >= off) v += t;
    }
    __shared__ int wsum[4];
    if (lane == 63) wsum[wv] = v;
    __syncthreads();
    int wbase = 0;
    #pragma unroll
    for (int w = 0; w < 4; ++w) if (w < wv) wbase += wsum[w];
    int excl = part[blockIdx.x] + wbase + v - orig;
    if (i < n) { rp[i] = excl; cursor[i] = excl; }
    if (i == n - 1) rp[n] = excl + orig;
}

// ---------------- CSR fill ----------------
__global__ __launch_bounds__(256) void fill_kernel(const int* __restrict__ ei,
                                                   int* __restrict__ cursor,
                                                   int* __restrict__ csr_src, int E) {
    int e = blockIdx.x * 256 + threadIdx.x;
    if (e >= E) return;
    int dst = ei[E + e];
    int pos = atomicAdd(&cursor[dst], 1);
    csr_src[pos] = ei[e];
}

// ---------------- weight pack: fp32 [256][128] (w_l|w_r) -> fp16 k-pair-packed [128 pairs][128] ----------------
// wpk[p*128+c] = (w[2p][c], w[2p+1][c]) as half2, where w = concat(w_l, w_r) over K=256.
__global__ __launch_bounds__(256) void wpack_kernel(const float* __restrict__ wl,
                                                    const float* __restrict__ wr,
                                                    __half2* __restrict__ wpk) {
    int idx = blockIdx.x * 256 + threadIdx.x;   // over 128*128
    if (idx >= 128 * 128) return;
    int p = idx >> 7, c = idx & 127;
    int k = 2 * p;
    const float* W = (k < HID) ? wl : wr;
    int kk = k & (HID - 1);
    wpk[idx] = __floats2half2_rn(W[kk * HID + c], W[(kk + 1) * HID + c]);
}

// ---------------- 128-dim pull aggregation (fp16 in, fp32 sum, fp16 MEAN out) ----------------
__global__ __launch_bounds__(256) void aggp_kernel(const int* __restrict__ rp,
                                                   const int* __restrict__ ci,
                                                   const __half* __restrict__ h16,
                                                   __half* __restrict__ agg16, int n) {
    int node = (blockIdx.x * 256 + threadIdx.x) >> 6;
    if (node >= n) return;
    int lane = threadIdx.x & 63;
    float2 a0 = make_float2(0.f, 0.f), a1 = make_float2(0.f, 0.f);
    float2 a2 = make_float2(0.f, 0.f), a3 = make_float2(0.f, 0.f);
    float2 a4 = make_float2(0.f, 0.f), a5 = make_float2(0.f, 0.f);
    float2 a6 = make_float2(0.f, 0.f), a7 = make_float2(0.f, 0.f);
    int beg = rp[node], end = rp[node + 1];
    int j = beg;
    for (; j + 7 < end; j += 8) {
        int s0 = ci[j],     s1 = ci[j + 1], s2 = ci[j + 2], s3 = ci[j + 3];
        int s4 = ci[j + 4], s5 = ci[j + 5], s6 = ci[j + 6], s7 = ci[j + 7];
        float2 f0 = __half22float2(*(const __half2*)(h16 + (size_t)s0 * HID + lane * 2));
        float2 f1 = __half22float2(*(const __half2*)(h16 + (size_t)s1 * HID + lane * 2));
        float2 f2 = __half22float2(*(const __half2*)(h16 + (size_t)s2 * HID + lane * 2));
        float2 f3 = __half22float2(*(const __half2*)(h16 + (size_t)s3 * HID + lane * 2));
        float2 f4 = __half22float2(*(const __half2*)(h16 + (size_t)s4 * HID + lane * 2));
        float2 f5 = __half22float2(*(const __half2*)(h16 + (size_t)s5 * HID + lane * 2));
        float2 f6 = __half22float2(*(const __half2*)(h16 + (size_t)s6 * HID + lane * 2));
        float2 f7 = __half22float2(*(const __half2*)(h16 + (size_t)s7 * HID + lane * 2));
        a0.x += f0.x; a0.y += f0.y;  a1.x += f1.x; a1.y += f1.y;
        a2.x += f2.x; a2.y += f2.y;  a3.x += f3.x; a3.y += f3.y;
        a4.x += f4.x; a4.y += f4.y;  a5.x += f5.x; a5.y += f5.y;
        a6.x += f6.x; a6.y += f6.y;  a7.x += f7.x; a7.y += f7.y;
    }
    for (; j + 3 < end; j += 4) {
        int s0 = ci[j], s1 = ci[j + 1], s2 = ci[j + 2], s3 = ci[j + 3];
        float2 f0 = __half22float2(*(const __half2*)(h16 + (size_t)s0 * HID + lane * 2));
        float2 f1 = __half22float2(*(const __half2*)(h16 + (size_t)s1 * HID + lane * 2));
        float2 f2 = __half22float2(*(const __half2*)(h16 + (size_t)s2 * HID + lane * 2));
        float2 f3 = __half22float2(*(const __half2*)(h16 + (size_t)s3 * HID + lane * 2));
        a0.x += f0.x; a0.y += f0.y;  a1.x += f1.x; a1.y += f1.y;
        a2.x += f2.x; a2.y += f2.y;  a3.x += f3.x; a3.y += f3.y;
    }
    for (; j < end; ++j) {
        int s0 = ci[j];
        float2 f0 = __half22float2(*(const __half2*)(h16 + (size_t)s0 * HID + lane * 2));
        a0.x += f0.x; a0.y += f0.y;
    }
    float inv = 1.0f / fmaxf((float)(end - beg), 1.0f);
    float ox = (a0.x + a1.x + a2.x + a3.x + a4.x + a5.x + a6.x + a7.x) * inv;
    float oy = (a0.y + a1.y + a2.y + a3.y + a4.y + a5.y + a6.y + a7.y) * inv;
    *(__half2*)(agg16 + (size_t)node * HID + lane * 2) = __floats2half2_rn(ox, oy);
}

// ---------------- layer 0: fused 11-dim pull-agg + dual matmul + LN + ReLU -> h16 ----------------
__global__ __launch_bounds__(256) void layer0_kernel(
    const float* __restrict__ x, const int* __restrict__ rp, const int* __restrict__ ci,
    const float* __restrict__ w_l, const float* __restrict__ b_l, const float* __restrict__ w_r,
    const float* __restrict__ ln_w, const float* __restrict__ ln_b,
    __half* __restrict__ h16, int n)
{
    int node = (blockIdx.x * 256 + threadIdx.x) >> 6;
    int lane = threadIdx.x & 63;
    if (node >= n) return;
    int beg = rp[node], end = rp[node + 1];
    int g = lane / 11;
    int d = lane - g * 11;
    float acc0 = 0.f, acc1 = 0.f;
    int j = beg + g;
    if (g < 5) {
        for (; j + 5 < end; j += 10) {
            int s0 = ci[j], s1 = ci[j + 5];
            acc0 += x[(size_t)s0 * 11 + d];
            acc1 += x[(size_t)s1 * 11 + d];
        }
        for (; j < end; j += 5) {
            int s0 = ci[j];
            acc0 += x[(size_t)s0 * 11 + d];
        }
    }
    float acc = acc0 + acc1;
    float aggk = 0.f;
    #pragma unroll
    for (int gg = 0; gg < 5; ++gg) {
        aggk += __shfl(acc, (lane < 11) ? (lane + 11 * gg) : lane);
    }
    float inv = 1.0f / fmaxf((float)(end - beg), 1.0f);
    float v0 = b_l[lane], v1 = b_l[lane + 64];
    #pragma unroll
    for (int k = 0; k < 11; ++k) {
        float a  = __shfl(aggk, k) * inv;
        float xi = x[(size_t)node * 11 + k];
        v0 += a * w_l[k * HID + lane]      + xi * w_r[k * HID + lane];
        v1 += a * w_l[k * HID + lane + 64] + xi * w_r[k * HID + lane + 64];
    }
    float s = v0 + v1, s2 = v0 * v0 + v1 * v1;
    #pragma unroll
    for (int m = 1; m < 64; m <<= 1) { s += __shfl_xor(s, m); s2 += __shfl_xor(s2, m); }
    float mu  = s * (1.0f / HID);
    float var = s2 * (1.0f / HID) - mu * mu;
    float rstd = rsqrtf(var + 1e-5f);
    float o0 = fmaxf((v0 - mu) * rstd * ln_w[lane]      + ln_b[lane],      0.0f);
    float o1 = fmaxf((v1 - mu) * rstd * ln_w[lane + 64] + ln_b[lane + 64], 0.0f);
    h16[(size_t)node * HID + lane]      = __float2half_rn(o0);
    h16[(size_t)node * HID + lane + 64] = __float2half_rn(o1);
}

// ---------------- layers 1/2: fp16 dot2 GEMM (R4 shape, half LDS tile) ----------------
// 256 threads: tx = tid&31 (4 cols), ty = tid>>5 (8 rows) -> 64 nodes/block.
// LDS tile [64][264] halves (agg 0..127 | h_in 128..255). Weights: k-pair-packed fp16 (wpk).
// Inner loop: v_dot2_f32_f16 (2 MACs/instr, fp32 accumulate) — no cvt in the hot loop.
// Alias-safe (h16out == h16in): block stages its own 64 rows fully before any global write.
__global__ __launch_bounds__(256) void layer_kernel(
    const __half* __restrict__ agg16, const __half* __restrict__ h16in,
    const __half2* __restrict__ wpk, const float* __restrict__ b_l,
    const float* __restrict__ ln_w, const float* __restrict__ ln_b,
    __half* __restrict__ h16out, int n)
{
    __shared__ __half lds[64][264];
    int base = blockIdx.x * 64;
    int tid = threadIdx.x;
    #pragma unroll
    for (int i = 0; i < 8; ++i) {
        int idx = tid + i * 256;        // 2048 chunks of 4 halves (8B) per source
        int row = idx >> 5;
        int c4  = (idx & 31) * 4;
        int node = base + row;
        float2 a = make_float2(0.f, 0.f);   // raw 4-half payloads
        float2 h = make_float2(0.f, 0.f);
        if (node < n) {
            a = *(const float2*)(agg16 + (size_t)node * HID + c4);
            h = *(const float2*)(h16in + (size_t)node * HID + c4);
        }
        *(float2*)&lds[row][c4]       = a;
        *(float2*)&lds[row][HID + c4] = h;
    }
    __syncthreads();

    int tx = tid & 31, ty = tid >> 5;
    float acc[8][4];
    #pragma unroll
    for (int r = 0; r < 8; ++r) { acc[r][0] = acc[r][1] = acc[r][2] = acc[r][3] = 0.f; }

    // K=256 as 128 k-pairs; process 2 pairs (4 halves) per iteration.
    for (int p = 0; p < 128; p += 2) {
        __half2 w00 = wpk[(size_t)(p + 0) * HID + tx * 4 + 0];
        __half2 w01 = wpk[(size_t)(p + 0) * HID + tx * 4 + 1];
        __half2 w02 = wpk[(size_t)(p + 0) * HID + tx * 4 + 2];
        __half2 w03 = wpk[(size_t)(p + 0) * HID + tx * 4 + 3];
        __half2 w10 = wpk[(size_t)(p + 1) * HID + tx * 4 + 0];
        __half2 w11 = wpk[(size_t)(p + 1) * HID + tx * 4 + 1];
        __half2 w12 = wpk[(size_t)(p + 1) * HID + tx * 4 + 2];
        __half2 w13 = wpk[(size_t)(p + 1) * HID + tx * 4 + 3];
        #pragma unroll
        for (int r = 0; r < 8; ++r) {
            float2 raw = *(const float2*)&lds[ty * 8 + r][p * 2];   // halves k=2p..2p+3
            const __half2* ap = (const __half2*)&raw;
            __half2 a0 = ap[0], a1 = ap[1];
            acc[r][0] = fdot2(a0, w00, acc[r][0]);
            acc[r][1] = fdot2(a0, w01, acc[r][1]);
            acc[r][2] = fdot2(a0, w02, acc[r][2]);
            acc[r][3] = fdot2(a0, w03, acc[r][3]);
            acc[r][0] = fdot2(a1, w10, acc[r][0]);
            acc[r][1] = fdot2(a1, w11, acc[r][1]);
            acc[r][2] = fdot2(a1, w12, acc[r][2]);
            acc[r][3] = fdot2(a1, w13, acc[r][3]);
        }
    }

    float4 bl = *(const float4*)(b_l  + tx * 4);
    float4 gw = *(const float4*)(ln_w + tx * 4);
    float4 gb = *(const float4*)(ln_b + tx * 4);
    #pragma unroll
    for (int r = 0; r < 8; ++r) {
        float v0 = acc[r][0] + bl.x, v1 = acc[r][1] + bl.y;
        float v2 = acc[r][2] + bl.z, v3 = acc[r][3] + bl.w;
        float s  = v0 + v1 + v2 + v3;
        float s2 = v0*v0 + v1*v1 + v2*v2 + v3*v3;
        #pragma unroll
        for (int m = 16; m >= 1; m >>= 1) { s += __shfl_xor(s, m); s2 += __shfl_xor(s2, m); }
        float mu  = s * (1.0f / HID);
        float var = s2 * (1.0f / HID) - mu * mu;
        float rstd = rsqrtf(var + 1e-5f);
        int row = ty * 8 + r;
        float o0 = fmaxf((v0 - mu) * rstd * gw.x + gb.x, 0.f);
        float o1 = fmaxf((v1 - mu) * rstd * gw.y + gb.y, 0.f);
        float o2 = fmaxf((v2 - mu) * rstd * gw.z + gb.z, 0.f);
        float o3 = fmaxf((v3 - mu) * rstd * gw.w + gb.w, 0.f);
        float2 r01 = __half22float2(*(const __half2*)&lds[row][HID + tx * 4]);
        float2 r23 = __half22float2(*(const __half2*)&lds[row][HID + tx * 4 + 2]);
        o0 += r01.x; o1 += r01.y; o2 += r23.x; o3 += r23.y;
        int node = base + row;
        if (node < n) {
            __half2* d16 = (__half2*)(h16out + (size_t)node * HID + tx * 4);
            d16[0] = __floats2half2_rn(o0, o1);
            d16[1] = __floats2half2_rn(o2, o3);
        }
    }
}

// ---------------- classifier: relu(h@c_w0+b0)@c_w1+b1 from fp16 h ----------------
__global__ __launch_bounds__(256) void cls_kernel(
    const __half* __restrict__ h, const float* __restrict__ w0, const float* __restrict__ b0,
    const float* __restrict__ w1, const float* __restrict__ b1, float* __restrict__ out, int n)
{
    __shared__ float w0s[HID * 64];
    __shared__ float w1s[64];
    int tid = threadIdx.x;
    #pragma unroll
    for (int i = 0; i < 32; ++i) w0s[tid + i * 256] = w0[tid + i * 256];
    if (tid < 64) w1s[tid] = w1[tid];
    __syncthreads();
    int lane = tid & 63, wv = tid >> 6;
    float bb0 = b0[lane], bb1 = b1[0];
    for (int i = 0; i < 16; ++i) {
        int node = blockIdx.x * 64 + wv * 16 + i;
        if (node >= n) break;
        const __half* hr = h + (size_t)node * HID;
        float s = bb0;
        #pragma unroll 4
        for (int k = 0; k < HID; k += 4) {
            float2 lo = __half22float2(*(const __half2*)(hr + k));
            float2 hi = __half22float2(*(const __half2*)(hr + k + 2));
            s = fmaf(lo.x, w0s[(k + 0) * 64 + lane], s);
            s = fmaf(lo.y, w0s[(k + 1) * 64 + lane], s);
            s = fmaf(hi.x, w0s[(k + 2) * 64 + lane], s);
            s = fmaf(hi.y, w0s[(k + 3) * 64 + lane], s);
        }
        s = fmaxf(s, 0.f);
        float t = s * w1s[lane];
        #pragma unroll
        for (int m = 1; m < 64; m <<= 1) t += __shfl_xor(t, m);
        if (lane == 0) out[node] = t + bb1;
    }
}

extern "C" void kernel_launch(void* const* d_in, const int* in_sizes, int n_in,
                              void* d_out, int out_size, void* d_ws, size_t ws_size,
                              hipStream_t stream) {
    const float* x  = (const float*)d_in[0];
    const int*   ei = (const int*)d_in[1];     // integer inputs arrive as int32
    const float* w_l0 = (const float*)d_in[2];
    const float* b_l0 = (const float*)d_in[3];
    const float* w_r0 = (const float*)d_in[4];
    const float* lnw0 = (const float*)d_in[5];
    const float* lnb0 = (const float*)d_in[6];
    const float* w_l1 = (const float*)d_in[7];
    const float* b_l1 = (const float*)d_in[8];
    const float* w_r1 = (const float*)d_in[9];
    const float* lnw1 = (const float*)d_in[10];
    const float* lnb1 = (const float*)d_in[11];
    const float* w_l2 = (const float*)d_in[12];
    const float* b_l2 = (const float*)d_in[13];
    const float* w_r2 = (const float*)d_in[14];
    const float* lnw2 = (const float*)d_in[15];
    const float* lnb2 = (const float*)d_in[16];
    const float* c_w0 = (const float*)d_in[17];
    const float* c_b0 = (const float*)d_in[18];
    const float* c_w1 = (const float*)d_in[19];
    const float* c_b1 = (const float*)d_in[20];
    float* out = (float*)d_out;

    int N = in_sizes[0] / 11;
    int E = in_sizes[1] / 2;
    int nb = (N + 255) / 256;

    // workspace: [deg: N][rp: N+1][cursor: N][csr: E][part: nb]
    //            [h16: N*HID halves][agg16: N*HID halves][wpk1: 16384 half2][wpk2: 16384 half2]
    int*     deg    = (int*)d_ws;
    int*     rp     = deg + N;
    int*     cursor = rp + (N + 1);
    int*     csr    = cursor + N;
    int*     part   = csr + E;
    __half*  h16    = (__half*)(part + ((nb + 63) & ~63));
    __half*  agg16  = h16 + (size_t)N * HID;
    __half2* wpk1   = (__half2*)(agg16 + (size_t)N * HID);
    __half2* wpk2   = wpk1 + 128 * HID;

    // ---- CSR build + weight pack ----
    hipMemsetAsync(deg, 0, (size_t)N * sizeof(int), stream);
    deg_kernel<<<(E + 255) / 256, 256, 0, stream>>>(ei, deg, E);
    part_kernel<<<nb, 256, 0, stream>>>(deg, part, N);
    scanpart_kernel<<<1, 1024, 0, stream>>>(part, nb);
    rp_kernel<<<nb, 256, 0, stream>>>(deg, part, rp, cursor, N);
    fill_kernel<<<(E + 255) / 256, 256, 0, stream>>>(ei, cursor, csr, E);
    wpack_kernel<<<64, 256, 0, stream>>>(w_l1, w_r1, wpk1);
    wpack_kernel<<<64, 256, 0, stream>>>(w_l2, w_r2, wpk2);

    int nodeBlocks = (N + 3) / 4;

    // ---- layer 0 ----  h0 -> h16
    layer0_kernel<<<nodeBlocks, 256, 0, stream>>>(x, rp, csr, w_l0, b_l0, w_r0, lnw0, lnb0, h16, N);

    // ---- layer 1 ----  gather(h16)->agg16 ; layer(agg16, h16) -> h16
    aggp_kernel<<<nodeBlocks, 256, 0, stream>>>(rp, csr, h16, agg16, N);
    layer_kernel<<<(N + 63) / 64, 256, 0, stream>>>(agg16, h16, wpk1, b_l1, lnw1, lnb1, h16, N);

    // ---- layer 2 ----
    aggp_kernel<<<nodeBlocks, 256, 0, stream>>>(rp, csr, h16, agg16, N);
    layer_kernel<<<(N + 63) / 64, 256, 0, stream>>>(agg16, h16, wpk2, b_l2, lnw2, lnb2, h16, N);

    // ---- classifier ----
    cls_kernel<<<(N + 63) / 64, 256, 0, stream>>>(h16, c_w0, c_b0, c_w1, c_b1, out, N);
}

// Round 14
// 336.054 us; speedup vs baseline: 1.5283x; 1.0429x over previous
//
#include <hip/hip_runtime.h>
#include <hip/hip_fp16.h>

#define HID 128

typedef _Float16 h2_t __attribute__((ext_vector_type(2)));

static __device__ __forceinline__ float fdot2(__half2 a, __half2 b, float c) {
    return __builtin_amdgcn_fdot2(__builtin_bit_cast(h2_t, a), __builtin_bit_cast(h2_t, b), c, false);
}

// ---------------- degree histogram, XCD/dst-range partitioned ----------------
// Group g = blockIdx&7 handles dst in [g*n/8, (g+1)*n/8): every deg[] line has ONE
// writer group -> atomics stay in one XCD's L2 (no cross-XCD line ping-pong).
__global__ __launch_bounds__(256) void deg_kernel(const int* __restrict__ ei,
                                                  int* __restrict__ deg, int E, int n) {
    int grp  = blockIdx.x & 7;
    int blk  = blockIdx.x >> 3;
    int nblk = gridDim.x >> 3;
    int lo = (int)(((long long)n * grp) >> 3);
    int hi = (int)(((long long)n * (grp + 1)) >> 3);
    for (int e = blk * 256 + threadIdx.x; e < E; e += nblk * 256) {
        int dst = ei[E + e];
        if (dst >= lo && dst < hi) atomicAdd(&deg[dst], 1);
    }
}

// ---------------- scan stage 1: per-block (256 elems) sums ----------------
__global__ __launch_bounds__(256) void part_kernel(const int* __restrict__ deg,
                                                   int* __restrict__ part, int n) {
    int i = blockIdx.x * 256 + threadIdx.x;
    int v = (i < n) ? deg[i] : 0;
    #pragma unroll
    for (int m = 1; m < 64; m <<= 1) v += __shfl_xor(v, m);
    __shared__ int w[4];
    int lane = threadIdx.x & 63, wv = threadIdx.x >> 6;
    if (lane == 0) w[wv] = v;
    __syncthreads();
    if (threadIdx.x == 0) part[blockIdx.x] = w[0] + w[1] + w[2] + w[3];
}

// ---------------- scan stage 2: exclusive scan of block sums ----------------
__global__ __launch_bounds__(1024) void scanpart_kernel(int* __restrict__ part, int nb) {
    __shared__ int s[1024];
    int t = threadIdx.x;
    int v = (t < nb) ? part[t] : 0;
    int orig = v;
    s[t] = v;
    __syncthreads();
    for (int off = 1; off < 1024; off <<= 1) {
        int u = (t >= off) ? s[t - off] : 0;
        __syncthreads();
        s[t] += u;
        __syncthreads();
    }
    if (t < nb) part[t] = s[t] - orig;   // exclusive
}

// ---------------- scan stage 3: per-block exclusive scan -> rp, cursor ----------------
__global__ __launch_bounds__(256) void rp_kernel(const int* __restrict__ deg,
                                                 const int* __restrict__ part,
                                                 int* __restrict__ rp,
                                                 int* __restrict__ cursor, int n) {
    int tid = threadIdx.x, lane = tid & 63, wv = tid >> 6;
    int i = blockIdx.x * 256 + tid;
    int v = (i < n) ? deg[i] : 0;
    int orig = v;
    #pragma unroll
    for (int off = 1; off < 64; off <<= 1) {
        int t = __shfl_up(v, off);
        if (lane >= off) v += t;
    }
    __shared__ int wsum[4];
    if (lane == 63) wsum[wv] = v;
    __syncthreads();
    int wbase = 0;
    #pragma unroll
    for (int w = 0; w < 4; ++w) if (w < wv) wbase += wsum[w];
    int excl = part[blockIdx.x] + wbase + v - orig;
    if (i < n) { rp[i] = excl; cursor[i] = excl; }
    if (i == n - 1) rp[n] = excl + orig;
}

// ---------------- CSR fill, XCD/dst-range partitioned (same grouping as deg) ----------------
// Each csr[] line (one dst's slots) is written by one group -> writes coalesce in one
// XCD's L2. Fixes R13's E*64B phantom HBM write traffic (52.8 MB -> ~buffer size).
__global__ __launch_bounds__(256) void fill_kernel(const int* __restrict__ ei,
                                                   int* __restrict__ cursor,
                                                   int* __restrict__ csr_src, int E, int n) {
    int grp  = blockIdx.x & 7;
    int blk  = blockIdx.x >> 3;
    int nblk = gridDim.x >> 3;
    int lo = (int)(((long long)n * grp) >> 3);
    int hi = (int)(((long long)n * (grp + 1)) >> 3);
    for (int e = blk * 256 + threadIdx.x; e < E; e += nblk * 256) {
        int dst = ei[E + e];
        if (dst >= lo && dst < hi) {
            int pos = atomicAdd(&cursor[dst], 1);
            csr_src[pos] = ei[e];
        }
    }
}

// ---------------- 128-dim pull aggregation (fp16 in, fp32 sum, fp16 MEAN out) ----------------
__global__ __launch_bounds__(256) void aggp_kernel(const int* __restrict__ rp,
                                                   const int* __restrict__ ci,
                                                   const __half* __restrict__ h16,
                                                   __half* __restrict__ agg16, int n) {
    int node = (blockIdx.x * 256 + threadIdx.x) >> 6;
    if (node >= n) return;
    int lane = threadIdx.x & 63;
    float2 a0 = make_float2(0.f, 0.f), a1 = make_float2(0.f, 0.f);
    float2 a2 = make_float2(0.f, 0.f), a3 = make_float2(0.f, 0.f);
    float2 a4 = make_float2(0.f, 0.f), a5 = make_float2(0.f, 0.f);
    float2 a6 = make_float2(0.f, 0.f), a7 = make_float2(0.f, 0.f);
    int beg = rp[node], end = rp[node + 1];
    int j = beg;
    for (; j + 7 < end; j += 8) {
        int s0 = ci[j],     s1 = ci[j + 1], s2 = ci[j + 2], s3 = ci[j + 3];
        int s4 = ci[j + 4], s5 = ci[j + 5], s6 = ci[j + 6], s7 = ci[j + 7];
        float2 f0 = __half22float2(*(const __half2*)(h16 + (size_t)s0 * HID + lane * 2));
        float2 f1 = __half22float2(*(const __half2*)(h16 + (size_t)s1 * HID + lane * 2));
        float2 f2 = __half22float2(*(const __half2*)(h16 + (size_t)s2 * HID + lane * 2));
        float2 f3 = __half22float2(*(const __half2*)(h16 + (size_t)s3 * HID + lane * 2));
        float2 f4 = __half22float2(*(const __half2*)(h16 + (size_t)s4 * HID + lane * 2));
        float2 f5 = __half22float2(*(const __half2*)(h16 + (size_t)s5 * HID + lane * 2));
        float2 f6 = __half22float2(*(const __half2*)(h16 + (size_t)s6 * HID + lane * 2));
        float2 f7 = __half22float2(*(const __half2*)(h16 + (size_t)s7 * HID + lane * 2));
        a0.x += f0.x; a0.y += f0.y;  a1.x += f1.x; a1.y += f1.y;
        a2.x += f2.x; a2.y += f2.y;  a3.x += f3.x; a3.y += f3.y;
        a4.x += f4.x; a4.y += f4.y;  a5.x += f5.x; a5.y += f5.y;
        a6.x += f6.x; a6.y += f6.y;  a7.x += f7.x; a7.y += f7.y;
    }
    for (; j + 3 < end; j += 4) {
        int s0 = ci[j], s1 = ci[j + 1], s2 = ci[j + 2], s3 = ci[j + 3];
        float2 f0 = __half22float2(*(const __half2*)(h16 + (size_t)s0 * HID + lane * 2));
        float2 f1 = __half22float2(*(const __half2*)(h16 + (size_t)s1 * HID + lane * 2));
        float2 f2 = __half22float2(*(const __half2*)(h16 + (size_t)s2 * HID + lane * 2));
        float2 f3 = __half22float2(*(const __half2*)(h16 + (size_t)s3 * HID + lane * 2));
        a0.x += f0.x; a0.y += f0.y;  a1.x += f1.x; a1.y += f1.y;
        a2.x += f2.x; a2.y += f2.y;  a3.x += f3.x; a3.y += f3.y;
    }
    for (; j < end; ++j) {
        int s0 = ci[j];
        float2 f0 = __half22float2(*(const __half2*)(h16 + (size_t)s0 * HID + lane * 2));
        a0.x += f0.x; a0.y += f0.y;
    }
    float inv = 1.0f / fmaxf((float)(end - beg), 1.0f);
    float ox = (a0.x + a1.x + a2.x + a3.x + a4.x + a5.x + a6.x + a7.x) * inv;
    float oy = (a0.y + a1.y + a2.y + a3.y + a4.y + a5.y + a6.y + a7.y) * inv;
    *(__half2*)(agg16 + (size_t)node * HID + lane * 2) = __floats2half2_rn(ox, oy);
}

// ---------------- layer 0: fused 11-dim pull-agg + dual matmul + LN + ReLU -> h16 ----------------
__global__ __launch_bounds__(256) void layer0_kernel(
    const float* __restrict__ x, const int* __restrict__ rp, const int* __restrict__ ci,
    const float* __restrict__ w_l, const float* __restrict__ b_l, const float* __restrict__ w_r,
    const float* __restrict__ ln_w, const float* __restrict__ ln_b,
    __half* __restrict__ h16, int n)
{
    int node = (blockIdx.x * 256 + threadIdx.x) >> 6;
    int lane = threadIdx.x & 63;
    if (node >= n) return;
    int beg = rp[node], end = rp[node + 1];
    int g = lane / 11;
    int d = lane - g * 11;
    float acc0 = 0.f, acc1 = 0.f;
    int j = beg + g;
    if (g < 5) {
        for (; j + 5 < end; j += 10) {
            int s0 = ci[j], s1 = ci[j + 5];
            acc0 += x[(size_t)s0 * 11 + d];
            acc1 += x[(size_t)s1 * 11 + d];
        }
        for (; j < end; j += 5) {
            int s0 = ci[j];
            acc0 += x[(size_t)s0 * 11 + d];
        }
    }
    float acc = acc0 + acc1;
    float aggk = 0.f;
    #pragma unroll
    for (int gg = 0; gg < 5; ++gg) {
        aggk += __shfl(acc, (lane < 11) ? (lane + 11 * gg) : lane);
    }
    float inv = 1.0f / fmaxf((float)(end - beg), 1.0f);
    float v0 = b_l[lane], v1 = b_l[lane + 64];
    #pragma unroll
    for (int k = 0; k < 11; ++k) {
        float a  = __shfl(aggk, k) * inv;
        float xi = x[(size_t)node * 11 + k];
        v0 += a * w_l[k * HID + lane]      + xi * w_r[k * HID + lane];
        v1 += a * w_l[k * HID + lane + 64] + xi * w_r[k * HID + lane + 64];
    }
    float s = v0 + v1, s2 = v0 * v0 + v1 * v1;
    #pragma unroll
    for (int m = 1; m < 64; m <<= 1) { s += __shfl_xor(s, m); s2 += __shfl_xor(s2, m); }
    float mu  = s * (1.0f / HID);
    float var = s2 * (1.0f / HID) - mu * mu;
    float rstd = rsqrtf(var + 1e-5f);
    float o0 = fmaxf((v0 - mu) * rstd * ln_w[lane]      + ln_b[lane],      0.0f);
    float o1 = fmaxf((v1 - mu) * rstd * ln_w[lane + 64] + ln_b[lane + 64], 0.0f);
    h16[(size_t)node * HID + lane]      = __float2half_rn(o0);
    h16[(size_t)node * HID + lane + 64] = __float2half_rn(o1);
}

// ---------------- weight pack: fp32 [256][128] (w_l|w_r) -> fp16 k-pair-packed ----------------
__global__ __launch_bounds__(256) void wpack_kernel(const float* __restrict__ wl,
                                                    const float* __restrict__ wr,
                                                    __half2* __restrict__ wpk) {
    int idx = blockIdx.x * 256 + threadIdx.x;   // over 128*128
    if (idx >= 128 * 128) return;
    int p = idx >> 7, c = idx & 127;
    int k = 2 * p;
    const float* W = (k < HID) ? wl : wr;
    int kk = k & (HID - 1);
    wpk[idx] = __floats2half2_rn(W[kk * HID + c], W[(kk + 1) * HID + c]);
}

// ---------------- layers 1/2: fp16 dot2 GEMM (R4 shape, half LDS tile) ----------------
__global__ __launch_bounds__(256) void layer_kernel(
    const __half* __restrict__ agg16, const __half* __restrict__ h16in,
    const __half2* __restrict__ wpk, const float* __restrict__ b_l,
    const float* __restrict__ ln_w, const float* __restrict__ ln_b,
    __half* __restrict__ h16out, int n)
{
    __shared__ __half lds[64][264];
    int base = blockIdx.x * 64;
    int tid = threadIdx.x;
    #pragma unroll
    for (int i = 0; i < 8; ++i) {
        int idx = tid + i * 256;
        int row = idx >> 5;
        int c4  = (idx & 31) * 4;
        int node = base + row;
        float2 a = make_float2(0.f, 0.f);
        float2 h = make_float2(0.f, 0.f);
        if (node < n) {
            a = *(const float2*)(agg16 + (size_t)node * HID + c4);
            h = *(const float2*)(h16in + (size_t)node * HID + c4);
        }
        *(float2*)&lds[row][c4]       = a;
        *(float2*)&lds[row][HID + c4] = h;
    }
    __syncthreads();

    int tx = tid & 31, ty = tid >> 5;
    float acc[8][4];
    #pragma unroll
    for (int r = 0; r < 8; ++r) { acc[r][0] = acc[r][1] = acc[r][2] = acc[r][3] = 0.f; }

    for (int p = 0; p < 128; p += 2) {
        __half2 w00 = wpk[(size_t)(p + 0) * HID + tx * 4 + 0];
        __half2 w01 = wpk[(size_t)(p + 0) * HID + tx * 4 + 1];
        __half2 w02 = wpk[(size_t)(p + 0) * HID + tx * 4 + 2];
        __half2 w03 = wpk[(size_t)(p + 0) * HID + tx * 4 + 3];
        __half2 w10 = wpk[(size_t)(p + 1) * HID + tx * 4 + 0];
        __half2 w11 = wpk[(size_t)(p + 1) * HID + tx * 4 + 1];
        __half2 w12 = wpk[(size_t)(p + 1) * HID + tx * 4 + 2];
        __half2 w13 = wpk[(size_t)(p + 1) * HID + tx * 4 + 3];
        #pragma unroll
        for (int r = 0; r < 8; ++r) {
            float2 raw = *(const float2*)&lds[ty * 8 + r][p * 2];
            const __half2* ap = (const __half2*)&raw;
            __half2 a0 = ap[0], a1 = ap[1];
            acc[r][0] = fdot2(a0, w00, acc[r][0]);
            acc[r][1] = fdot2(a0, w01, acc[r][1]);
            acc[r][2] = fdot2(a0, w02, acc[r][2]);
            acc[r][3] = fdot2(a0, w03, acc[r][3]);
            acc[r][0] = fdot2(a1, w10, acc[r][0]);
            acc[r][1] = fdot2(a1, w11, acc[r][1]);
            acc[r][2] = fdot2(a1, w12, acc[r][2]);
            acc[r][3] = fdot2(a1, w13, acc[r][3]);
        }
    }

    float4 bl = *(const float4*)(b_l  + tx * 4);
    float4 gw = *(const float4*)(ln_w + tx * 4);
    float4 gb = *(const float4*)(ln_b + tx * 4);
    #pragma unroll
    for (int r = 0; r < 8; ++r) {
        float v0 = acc[r][0] + bl.x, v1 = acc[r][1] + bl.y;
        float v2 = acc[r][2] + bl.z, v3 = acc[r][3] + bl.w;
        float s  = v0 + v1 + v2 + v3;
        float s2 = v0*v0 + v1*v1 + v2*v2 + v3*v3;
        #pragma unroll
        for (int m = 16; m >= 1; m >>= 1) { s += __shfl_xor(s, m); s2 += __shfl_xor(s2, m); }
        float mu  = s * (1.0f / HID);
        float var = s2 * (1.0f / HID) - mu * mu;
        float rstd = rsqrtf(var + 1e-5f);
        int row = ty * 8 + r;
        float o0 = fmaxf((v0 - mu) * rstd * gw.x + gb.x, 0.f);
        float o1 = fmaxf((v1 - mu) * rstd * gw.y + gb.y, 0.f);
        float o2 = fmaxf((v2 - mu) * rstd * gw.z + gb.z, 0.f);
        float o3 = fmaxf((v3 - mu) * rstd * gw.w + gb.w, 0.f);
        float2 r01 = __half22float2(*(const __half2*)&lds[row][HID + tx * 4]);
        float2 r23 = __half22float2(*(const __half2*)&lds[row][HID + tx * 4 + 2]);
        o0 += r01.x; o1 += r01.y; o2 += r23.x; o3 += r23.y;
        int node = base + row;
        if (node < n) {
            __half2* d16 = (__half2*)(h16out + (size_t)node * HID + tx * 4);
            d16[0] = __floats2half2_rn(o0, o1);
            d16[1] = __floats2half2_rn(o2, o3);
        }
    }
}

// ---------------- classifier: relu(h@c_w0+b0)@c_w1+b1 from fp16 h ----------------
__global__ __launch_bounds__(256) void cls_kernel(
    const __half* __restrict__ h, const float* __restrict__ w0, const float* __restrict__ b0,
    const float* __restrict__ w1, const float* __restrict__ b1, float* __restrict__ out, int n)
{
    __shared__ float w0s[HID * 64];
    __shared__ float w1s[64];
    int tid = threadIdx.x;
    #pragma unroll
    for (int i = 0; i < 32; ++i) w0s[tid + i * 256] = w0[tid + i * 256];
    if (tid < 64) w1s[tid] = w1[tid];
    __syncthreads();
    int lane = tid & 63, wv = tid >> 6;
    float bb0 = b0[lane], bb1 = b1[0];
    for (int i = 0; i < 16; ++i) {
        int node = blockIdx.x * 64 + wv * 16 + i;
        if (node >= n) break;
        const __half* hr = h + (size_t)node * HID;
        float s = bb0;
        #pragma unroll 4
        for (int k = 0; k < HID; k += 4) {
            float2 lo = __half22float2(*(const __half2*)(hr + k));
            float2 hi = __half22float2(*(const __half2*)(hr + k + 2));
            s = fmaf(lo.x, w0s[(k + 0) * 64 + lane], s);
            s = fmaf(lo.y, w0s[(k + 1) * 64 + lane], s);
            s = fmaf(hi.x, w0s[(k + 2) * 64 + lane], s);
            s = fmaf(hi.y, w0s[(k + 3) * 64 + lane], s);
        }
        s = fmaxf(s, 0.f);
        float t = s * w1s[lane];
        #pragma unroll
        for (int m = 1; m < 64; m <<= 1) t += __shfl_xor(t, m);
        if (lane == 0) out[node] = t + bb1;
    }
}

extern "C" void kernel_launch(void* const* d_in, const int* in_sizes, int n_in,
                              void* d_out, int out_size, void* d_ws, size_t ws_size,
                              hipStream_t stream) {
    const float* x  = (const float*)d_in[0];
    const int*   ei = (const int*)d_in[1];     // integer inputs arrive as int32
    const float* w_l0 = (const float*)d_in[2];
    const float* b_l0 = (const float*)d_in[3];
    const float* w_r0 = (const float*)d_in[4];
    const float* lnw0 = (const float*)d_in[5];
    const float* lnb0 = (const float*)d_in[6];
    const float* w_l1 = (const float*)d_in[7];
    const float* b_l1 = (const float*)d_in[8];
    const float* w_r1 = (const float*)d_in[9];
    const float* lnw1 = (const float*)d_in[10];
    const float* lnb1 = (const float*)d_in[11];
    const float* w_l2 = (const float*)d_in[12];
    const float* b_l2 = (const float*)d_in[13];
    const float* w_r2 = (const float*)d_in[14];
    const float* lnw2 = (const float*)d_in[15];
    const float* lnb2 = (const float*)d_in[16];
    const float* c_w0 = (const float*)d_in[17];
    const float* c_b0 = (const float*)d_in[18];
    const float* c_w1 = (const float*)d_in[19];
    const float* c_b1 = (const float*)d_in[20];
    float* out = (float*)d_out;

    int N = in_sizes[0] / 11;
    int E = in_sizes[1] / 2;
    int nb = (N + 255) / 256;

    // workspace: [deg: N][rp: N+1][cursor: N][csr: E][part: nb]
    //            [h16: N*HID halves][agg16: N*HID halves][wpk1][wpk2]
    int*     deg    = (int*)d_ws;
    int*     rp     = deg + N;
    int*     cursor = rp + (N + 1);
    int*     csr    = cursor + N;
    int*     part   = csr + E;
    __half*  h16    = (__half*)(part + ((nb + 63) & ~63));
    __half*  agg16  = h16 + (size_t)N * HID;
    __half2* wpk1   = (__half2*)(agg16 + (size_t)N * HID);
    __half2* wpk2   = wpk1 + 128 * HID;

    // ---- CSR build (dst-range partitioned across XCDs) + weight pack ----
    hipMemsetAsync(deg, 0, (size_t)N * sizeof(int), stream);
    deg_kernel<<<8 * 512, 256, 0, stream>>>(ei, deg, E, N);
    part_kernel<<<nb, 256, 0, stream>>>(deg, part, N);
    scanpart_kernel<<<1, 1024, 0, stream>>>(part, nb);
    rp_kernel<<<nb, 256, 0, stream>>>(deg, part, rp, cursor, N);
    fill_kernel<<<8 * 512, 256, 0, stream>>>(ei, cursor, csr, E, N);
    wpack_kernel<<<64, 256, 0, stream>>>(w_l1, w_r1, wpk1);
    wpack_kernel<<<64, 256, 0, stream>>>(w_l2, w_r2, wpk2);

    int nodeBlocks = (N + 3) / 4;

    // ---- layer 0 ----  h0 -> h16
    layer0_kernel<<<nodeBlocks, 256, 0, stream>>>(x, rp, csr, w_l0, b_l0, w_r0, lnw0, lnb0, h16, N);

    // ---- layer 1 ----  gather(h16)->agg16 ; layer(agg16, h16) -> h16
    aggp_kernel<<<nodeBlocks, 256, 0, stream>>>(rp, csr, h16, agg16, N);
    layer_kernel<<<(N + 63) / 64, 256, 0, stream>>>(agg16, h16, wpk1, b_l1, lnw1, lnb1, h16, N);

    // ---- layer 2 ----
    aggp_kernel<<<nodeBlocks, 256, 0, stream>>>(rp, csr, h16, agg16, N);
    layer_kernel<<<(N + 63) / 64, 256, 0, stream>>>(agg16, h16, wpk2, b_l2, lnw2, lnb2, h16, N);

    // ---- classifier ----
    cls_kernel<<<(N + 63) / 64, 256, 0, stream>>>(h16, c_w0, c_b0, c_w1, c_b1, out, N);
}

// Round 15
// 324.640 us; speedup vs baseline: 1.5820x; 1.0352x over previous
//
#include <hip/hip_runtime.h>
#include <hip/hip_fp16.h>

#define HID 128

typedef _Float16 h2_t __attribute__((ext_vector_type(2)));

static __device__ __forceinline__ float fdot2(__half2 a, __half2 b, float c) {
    return __builtin_amdgcn_fdot2(__builtin_bit_cast(h2_t, a), __builtin_bit_cast(h2_t, b), c, false);
}

// ---------------- degree histogram, XCD/dst-range partitioned ----------------
__global__ __launch_bounds__(256) void deg_kernel(const int* __restrict__ ei,
                                                  int* __restrict__ deg, int E, int n) {
    int grp  = blockIdx.x & 7;
    int blk  = blockIdx.x >> 3;
    int nblk = gridDim.x >> 3;
    int lo = (int)(((long long)n * grp) >> 3);
    int hi = (int)(((long long)n * (grp + 1)) >> 3);
    for (int e = blk * 256 + threadIdx.x; e < E; e += nblk * 256) {
        int dst = ei[E + e];
        if (dst >= lo && dst < hi) atomicAdd(&deg[dst], 1);
    }
}

// ---------------- scan stage 1: per-block (256 elems) sums ----------------
__global__ __launch_bounds__(256) void part_kernel(const int* __restrict__ deg,
                                                   int* __restrict__ part, int n) {
    int i = blockIdx.x * 256 + threadIdx.x;
    int v = (i < n) ? deg[i] : 0;
    #pragma unroll
    for (int m = 1; m < 64; m <<= 1) v += __shfl_xor(v, m);
    __shared__ int w[4];
    int lane = threadIdx.x & 63, wv = threadIdx.x >> 6;
    if (lane == 0) w[wv] = v;
    __syncthreads();
    if (threadIdx.x == 0) part[blockIdx.x] = w[0] + w[1] + w[2] + w[3];
}

// ---------------- scan stage 2: exclusive scan of block sums ----------------
__global__ __launch_bounds__(1024) void scanpart_kernel(int* __restrict__ part, int nb) {
    __shared__ int s[1024];
    int t = threadIdx.x;
    int v = (t < nb) ? part[t] : 0;
    int orig = v;
    s[t] = v;
    __syncthreads();
    for (int off = 1; off < 1024; off <<= 1) {
        int u = (t >= off) ? s[t - off] : 0;
        __syncthreads();
        s[t] += u;
        __syncthreads();
    }
    if (t < nb) part[t] = s[t] - orig;   // exclusive
}

// ---------------- scan stage 3: per-block exclusive scan -> rp, cursor ----------------
__global__ __launch_bounds__(256) void rp_kernel(const int* __restrict__ deg,
                                                 const int* __restrict__ part,
                                                 int* __restrict__ rp,
                                                 int* __restrict__ cursor, int n) {
    int tid = threadIdx.x, lane = tid & 63, wv = tid >> 6;
    int i = blockIdx.x * 256 + tid;
    int v = (i < n) ? deg[i] : 0;
    int orig = v;
    #pragma unroll
    for (int off = 1; off < 64; off <<= 1) {
        int t = __shfl_up(v, off);
        if (lane >= off) v += t;
    }
    __shared__ int wsum[4];
    if (lane == 63) wsum[wv] = v;
    __syncthreads();
    int wbase = 0;
    #pragma unroll
    for (int w = 0; w < 4; ++w) if (w < wv) wbase += wsum[w];
    int excl = part[blockIdx.x] + wbase + v - orig;
    if (i < n) { rp[i] = excl; cursor[i] = excl; }
    if (i == n - 1) rp[n] = excl + orig;
}

// ---------------- CSR fill, XCD/dst-range partitioned ----------------
__global__ __launch_bounds__(256) void fill_kernel(const int* __restrict__ ei,
                                                   int* __restrict__ cursor,
                                                   int* __restrict__ csr_src, int E, int n) {
    int grp  = blockIdx.x & 7;
    int blk  = blockIdx.x >> 3;
    int nblk = gridDim.x >> 3;
    int lo = (int)(((long long)n * grp) >> 3);
    int hi = (int)(((long long)n * (grp + 1)) >> 3);
    for (int e = blk * 256 + threadIdx.x; e < E; e += nblk * 256) {
        int dst = ei[E + e];
        if (dst >= lo && dst < hi) {
            int pos = atomicAdd(&cursor[dst], 1);
            csr_src[pos] = ei[e];
        }
    }
}

// ---------------- 128-dim pull aggregation (fp16 in, fp32 sum, fp16 MEAN out) ----------------
__global__ __launch_bounds__(256) void aggp_kernel(const int* __restrict__ rp,
                                                   const int* __restrict__ ci,
                                                   const __half* __restrict__ h16,
                                                   __half* __restrict__ agg16, int n) {
    int node = (blockIdx.x * 256 + threadIdx.x) >> 6;
    if (node >= n) return;
    int lane = threadIdx.x & 63;
    float2 a0 = make_float2(0.f, 0.f), a1 = make_float2(0.f, 0.f);
    float2 a2 = make_float2(0.f, 0.f), a3 = make_float2(0.f, 0.f);
    float2 a4 = make_float2(0.f, 0.f), a5 = make_float2(0.f, 0.f);
    float2 a6 = make_float2(0.f, 0.f), a7 = make_float2(0.f, 0.f);
    int beg = rp[node], end = rp[node + 1];
    int j = beg;
    for (; j + 7 < end; j += 8) {
        int s0 = ci[j],     s1 = ci[j + 1], s2 = ci[j + 2], s3 = ci[j + 3];
        int s4 = ci[j + 4], s5 = ci[j + 5], s6 = ci[j + 6], s7 = ci[j + 7];
        float2 f0 = __half22float2(*(const __half2*)(h16 + (size_t)s0 * HID + lane * 2));
        float2 f1 = __half22float2(*(const __half2*)(h16 + (size_t)s1 * HID + lane * 2));
        float2 f2 = __half22float2(*(const __half2*)(h16 + (size_t)s2 * HID + lane * 2));
        float2 f3 = __half22float2(*(const __half2*)(h16 + (size_t)s3 * HID + lane * 2));
        float2 f4 = __half22float2(*(const __half2*)(h16 + (size_t)s4 * HID + lane * 2));
        float2 f5 = __half22float2(*(const __half2*)(h16 + (size_t)s5 * HID + lane * 2));
        float2 f6 = __half22float2(*(const __half2*)(h16 + (size_t)s6 * HID + lane * 2));
        float2 f7 = __half22float2(*(const __half2*)(h16 + (size_t)s7 * HID + lane * 2));
        a0.x += f0.x; a0.y += f0.y;  a1.x += f1.x; a1.y += f1.y;
        a2.x += f2.x; a2.y += f2.y;  a3.x += f3.x; a3.y += f3.y;
        a4.x += f4.x; a4.y += f4.y;  a5.x += f5.x; a5.y += f5.y;
        a6.x += f6.x; a6.y += f6.y;  a7.x += f7.x; a7.y += f7.y;
    }
    for (; j + 3 < end; j += 4) {
        int s0 = ci[j], s1 = ci[j + 1], s2 = ci[j + 2], s3 = ci[j + 3];
        float2 f0 = __half22float2(*(const __half2*)(h16 + (size_t)s0 * HID + lane * 2));
        float2 f1 = __half22float2(*(const __half2*)(h16 + (size_t)s1 * HID + lane * 2));
        float2 f2 = __half22float2(*(const __half2*)(h16 + (size_t)s2 * HID + lane * 2));
        float2 f3 = __half22float2(*(const __half2*)(h16 + (size_t)s3 * HID + lane * 2));
        a0.x += f0.x; a0.y += f0.y;  a1.x += f1.x; a1.y += f1.y;
        a2.x += f2.x; a2.y += f2.y;  a3.x += f3.x; a3.y += f3.y;
    }
    for (; j < end; ++j) {
        int s0 = ci[j];
        float2 f0 = __half22float2(*(const __half2*)(h16 + (size_t)s0 * HID + lane * 2));
        a0.x += f0.x; a0.y += f0.y;
    }
    float inv = 1.0f / fmaxf((float)(end - beg), 1.0f);
    float ox = (a0.x + a1.x + a2.x + a3.x + a4.x + a5.x + a6.x + a7.x) * inv;
    float oy = (a0.y + a1.y + a2.y + a3.y + a4.y + a5.y + a6.y + a7.y) * inv;
    *(__half2*)(agg16 + (size_t)node * HID + lane * 2) = __floats2half2_rn(ox, oy);
}

// ---------------- layer 0: fused 11-dim pull-agg + dual matmul + LN + ReLU -> h16 ----------------
__global__ __launch_bounds__(256) void layer0_kernel(
    const float* __restrict__ x, const int* __restrict__ rp, const int* __restrict__ ci,
    const float* __restrict__ w_l, const float* __restrict__ b_l, const float* __restrict__ w_r,
    const float* __restrict__ ln_w, const float* __restrict__ ln_b,
    __half* __restrict__ h16, int n)
{
    int node = (blockIdx.x * 256 + threadIdx.x) >> 6;
    int lane = threadIdx.x & 63;
    if (node >= n) return;
    int beg = rp[node], end = rp[node + 1];
    int g = lane / 11;
    int d = lane - g * 11;
    float acc0 = 0.f, acc1 = 0.f;
    int j = beg + g;
    if (g < 5) {
        for (; j + 5 < end; j += 10) {
            int s0 = ci[j], s1 = ci[j + 5];
            acc0 += x[(size_t)s0 * 11 + d];
            acc1 += x[(size_t)s1 * 11 + d];
        }
        for (; j < end; j += 5) {
            int s0 = ci[j];
            acc0 += x[(size_t)s0 * 11 + d];
        }
    }
    float acc = acc0 + acc1;
    float aggk = 0.f;
    #pragma unroll
    for (int gg = 0; gg < 5; ++gg) {
        aggk += __shfl(acc, (lane < 11) ? (lane + 11 * gg) : lane);
    }
    float inv = 1.0f / fmaxf((float)(end - beg), 1.0f);
    float v0 = b_l[lane], v1 = b_l[lane + 64];
    #pragma unroll
    for (int k = 0; k < 11; ++k) {
        float a  = __shfl(aggk, k) * inv;
        float xi = x[(size_t)node * 11 + k];
        v0 += a * w_l[k * HID + lane]      + xi * w_r[k * HID + lane];
        v1 += a * w_l[k * HID + lane + 64] + xi * w_r[k * HID + lane + 64];
    }
    float s = v0 + v1, s2 = v0 * v0 + v1 * v1;
    #pragma unroll
    for (int m = 1; m < 64; m <<= 1) { s += __shfl_xor(s, m); s2 += __shfl_xor(s2, m); }
    float mu  = s * (1.0f / HID);
    float var = s2 * (1.0f / HID) - mu * mu;
    float rstd = rsqrtf(var + 1e-5f);
    float o0 = fmaxf((v0 - mu) * rstd * ln_w[lane]      + ln_b[lane],      0.0f);
    float o1 = fmaxf((v1 - mu) * rstd * ln_w[lane + 64] + ln_b[lane + 64], 0.0f);
    h16[(size_t)node * HID + lane]      = __float2half_rn(o0);
    h16[(size_t)node * HID + lane + 64] = __float2half_rn(o1);
}

// ---------------- weight pack: fp32 [256][128] (w_l|w_r) -> fp16 k-pair-packed ----------------
__global__ __launch_bounds__(256) void wpack_kernel(const float* __restrict__ wl,
                                                    const float* __restrict__ wr,
                                                    __half2* __restrict__ wpk) {
    int idx = blockIdx.x * 256 + threadIdx.x;   // over 128*128
    if (idx >= 128 * 128) return;
    int p = idx >> 7, c = idx & 127;
    int k = 2 * p;
    const float* W = (k < HID) ? wl : wr;
    int kk = k & (HID - 1);
    wpk[idx] = __floats2half2_rn(W[kk * HID + c], W[(kk + 1) * HID + c]);
}

// ---------------- cls weight pack: fp32 [128][64] -> fp16 k-pair-packed [64][64] ----------------
__global__ __launch_bounds__(256) void wpack_cls_kernel(const float* __restrict__ w0,
                                                        __half2* __restrict__ w0p) {
    int idx = blockIdx.x * 256 + threadIdx.x;   // over 64*64
    if (idx >= 64 * 64) return;
    int p = idx >> 6, c = idx & 63;
    w0p[idx] = __floats2half2_rn(w0[(2 * p) * 64 + c], w0[(2 * p + 1) * 64 + c]);
}

// ---------------- layers 1/2: fp16 dot2 GEMM (R4 shape, half LDS tile) ----------------
__global__ __launch_bounds__(256) void layer_kernel(
    const __half* __restrict__ agg16, const __half* __restrict__ h16in,
    const __half2* __restrict__ wpk, const float* __restrict__ b_l,
    const float* __restrict__ ln_w, const float* __restrict__ ln_b,
    __half* __restrict__ h16out, int n)
{
    __shared__ __half lds[64][264];
    int base = blockIdx.x * 64;
    int tid = threadIdx.x;
    #pragma unroll
    for (int i = 0; i < 8; ++i) {
        int idx = tid + i * 256;
        int row = idx >> 5;
        int c4  = (idx & 31) * 4;
        int node = base + row;
        float2 a = make_float2(0.f, 0.f);
        float2 h = make_float2(0.f, 0.f);
        if (node < n) {
            a = *(const float2*)(agg16 + (size_t)node * HID + c4);
            h = *(const float2*)(h16in + (size_t)node * HID + c4);
        }
        *(float2*)&lds[row][c4]       = a;
        *(float2*)&lds[row][HID + c4] = h;
    }
    __syncthreads();

    int tx = tid & 31, ty = tid >> 5;
    float acc[8][4];
    #pragma unroll
    for (int r = 0; r < 8; ++r) { acc[r][0] = acc[r][1] = acc[r][2] = acc[r][3] = 0.f; }

    for (int p = 0; p < 128; p += 2) {
        __half2 w00 = wpk[(size_t)(p + 0) * HID + tx * 4 + 0];
        __half2 w01 = wpk[(size_t)(p + 0) * HID + tx * 4 + 1];
        __half2 w02 = wpk[(size_t)(p + 0) * HID + tx * 4 + 2];
        __half2 w03 = wpk[(size_t)(p + 0) * HID + tx * 4 + 3];
        __half2 w10 = wpk[(size_t)(p + 1) * HID + tx * 4 + 0];
        __half2 w11 = wpk[(size_t)(p + 1) * HID + tx * 4 + 1];
        __half2 w12 = wpk[(size_t)(p + 1) * HID + tx * 4 + 2];
        __half2 w13 = wpk[(size_t)(p + 1) * HID + tx * 4 + 3];
        #pragma unroll
        for (int r = 0; r < 8; ++r) {
            float2 raw = *(const float2*)&lds[ty * 8 + r][p * 2];
            const __half2* ap = (const __half2*)&raw;
            __half2 a0 = ap[0], a1 = ap[1];
            acc[r][0] = fdot2(a0, w00, acc[r][0]);
            acc[r][1] = fdot2(a0, w01, acc[r][1]);
            acc[r][2] = fdot2(a0, w02, acc[r][2]);
            acc[r][3] = fdot2(a0, w03, acc[r][3]);
            acc[r][0] = fdot2(a1, w10, acc[r][0]);
            acc[r][1] = fdot2(a1, w11, acc[r][1]);
            acc[r][2] = fdot2(a1, w12, acc[r][2]);
            acc[r][3] = fdot2(a1, w13, acc[r][3]);
        }
    }

    float4 bl = *(const float4*)(b_l  + tx * 4);
    float4 gw = *(const float4*)(ln_w + tx * 4);
    float4 gb = *(const float4*)(ln_b + tx * 4);
    #pragma unroll
    for (int r = 0; r < 8; ++r) {
        float v0 = acc[r][0] + bl.x, v1 = acc[r][1] + bl.y;
        float v2 = acc[r][2] + bl.z, v3 = acc[r][3] + bl.w;
        float s  = v0 + v1 + v2 + v3;
        float s2 = v0*v0 + v1*v1 + v2*v2 + v3*v3;
        #pragma unroll
        for (int m = 16; m >= 1; m >>= 1) { s += __shfl_xor(s, m); s2 += __shfl_xor(s2, m); }
        float mu  = s * (1.0f / HID);
        float var = s2 * (1.0f / HID) - mu * mu;
        float rstd = rsqrtf(var + 1e-5f);
        int row = ty * 8 + r;
        float o0 = fmaxf((v0 - mu) * rstd * gw.x + gb.x, 0.f);
        float o1 = fmaxf((v1 - mu) * rstd * gw.y + gb.y, 0.f);
        float o2 = fmaxf((v2 - mu) * rstd * gw.z + gb.z, 0.f);
        float o3 = fmaxf((v3 - mu) * rstd * gw.w + gb.w, 0.f);
        float2 r01 = __half22float2(*(const __half2*)&lds[row][HID + tx * 4]);
        float2 r23 = __half22float2(*(const __half2*)&lds[row][HID + tx * 4 + 2]);
        o0 += r01.x; o1 += r01.y; o2 += r23.x; o3 += r23.y;
        int node = base + row;
        if (node < n) {
            __half2* d16 = (__half2*)(h16out + (size_t)node * HID + tx * 4);
            d16[0] = __floats2half2_rn(o0, o1);
            d16[1] = __floats2half2_rn(o2, o3);
        }
    }
}

// ---------------- classifier: dot2, 16 nodes/block (4/wave), 2 accumulators ----------------
__global__ __launch_bounds__(256) void cls_kernel(
    const __half* __restrict__ h, const __half2* __restrict__ w0p, const float* __restrict__ b0,
    const float* __restrict__ w1, const float* __restrict__ b1, float* __restrict__ out, int n)
{
    __shared__ __half2 w0s[64 * 64];   // 16 KB, k-pair-packed
    int tid = threadIdx.x;
    #pragma unroll
    for (int i = 0; i < 16; ++i) w0s[tid + i * 256] = w0p[tid + i * 256];
    __syncthreads();
    int lane = tid & 63, wv = tid >> 6;
    float bb0 = b0[lane], ww1 = w1[lane], bb1 = b1[0];
    #pragma unroll 1
    for (int q = 0; q < 4; ++q) {
        int node = blockIdx.x * 16 + wv * 4 + q;
        if (node >= n) break;
        const __half2* hr = (const __half2*)(h + (size_t)node * HID);
        float s0 = 0.f, s1 = 0.f;
        #pragma unroll
        for (int p = 0; p < 64; p += 2) {
            s0 = fdot2(hr[p],     w0s[(p + 0) * 64 + lane], s0);
            s1 = fdot2(hr[p + 1], w0s[(p + 1) * 64 + lane], s1);
        }
        float s = fmaxf(s0 + s1 + bb0, 0.f);
        float t = s * ww1;
        #pragma unroll
        for (int m = 1; m < 64; m <<= 1) t += __shfl_xor(t, m);
        if (lane == 0) out[node] = t + bb1;
    }
}

extern "C" void kernel_launch(void* const* d_in, const int* in_sizes, int n_in,
                              void* d_out, int out_size, void* d_ws, size_t ws_size,
                              hipStream_t stream) {
    const float* x  = (const float*)d_in[0];
    const int*   ei = (const int*)d_in[1];     // integer inputs arrive as int32
    const float* w_l0 = (const float*)d_in[2];
    const float* b_l0 = (const float*)d_in[3];
    const float* w_r0 = (const float*)d_in[4];
    const float* lnw0 = (const float*)d_in[5];
    const float* lnb0 = (const float*)d_in[6];
    const float* w_l1 = (const float*)d_in[7];
    const float* b_l1 = (const float*)d_in[8];
    const float* w_r1 = (const float*)d_in[9];
    const float* lnw1 = (const float*)d_in[10];
    const float* lnb1 = (const float*)d_in[11];
    const float* w_l2 = (const float*)d_in[12];
    const float* b_l2 = (const float*)d_in[13];
    const float* w_r2 = (const float*)d_in[14];
    const float* lnw2 = (const float*)d_in[15];
    const float* lnb2 = (const float*)d_in[16];
    const float* c_w0 = (const float*)d_in[17];
    const float* c_b0 = (const float*)d_in[18];
    const float* c_w1 = (const float*)d_in[19];
    const float* c_b1 = (const float*)d_in[20];
    float* out = (float*)d_out;

    int N = in_sizes[0] / 11;
    int E = in_sizes[1] / 2;
    int nb = (N + 255) / 256;

    // workspace: [deg: N][rp: N+1][cursor: N][csr: E][part: nb]
    //            [h16][agg16][wpk1][wpk2][w0p]
    int*     deg    = (int*)d_ws;
    int*     rp     = deg + N;
    int*     cursor = rp + (N + 1);
    int*     csr    = cursor + N;
    int*     part   = csr + E;
    __half*  h16    = (__half*)(part + ((nb + 63) & ~63));
    __half*  agg16  = h16 + (size_t)N * HID;
    __half2* wpk1   = (__half2*)(agg16 + (size_t)N * HID);
    __half2* wpk2   = wpk1 + 128 * HID;
    __half2* w0p    = wpk2 + 128 * HID;

    // ---- CSR build (dst-range partitioned across XCDs) + weight packs ----
    hipMemsetAsync(deg, 0, (size_t)N * sizeof(int), stream);
    deg_kernel<<<8 * 512, 256, 0, stream>>>(ei, deg, E, N);
    part_kernel<<<nb, 256, 0, stream>>>(deg, part, N);
    scanpart_kernel<<<1, 1024, 0, stream>>>(part, nb);
    rp_kernel<<<nb, 256, 0, stream>>>(deg, part, rp, cursor, N);
    fill_kernel<<<8 * 512, 256, 0, stream>>>(ei, cursor, csr, E, N);
    wpack_kernel<<<64, 256, 0, stream>>>(w_l1, w_r1, wpk1);
    wpack_kernel<<<64, 256, 0, stream>>>(w_l2, w_r2, wpk2);
    wpack_cls_kernel<<<16, 256, 0, stream>>>(c_w0, w0p);

    int nodeBlocks = (N + 3) / 4;

    // ---- layer 0 ----  h0 -> h16
    layer0_kernel<<<nodeBlocks, 256, 0, stream>>>(x, rp, csr, w_l0, b_l0, w_r0, lnw0, lnb0, h16, N);

    // ---- layer 1 ----  gather(h16)->agg16 ; layer(agg16, h16) -> h16
    aggp_kernel<<<nodeBlocks, 256, 0, stream>>>(rp, csr, h16, agg16, N);
    layer_kernel<<<(N + 63) / 64, 256, 0, stream>>>(agg16, h16, wpk1, b_l1, lnw1, lnb1, h16, N);

    // ---- layer 2 ----
    aggp_kernel<<<nodeBlocks, 256, 0, stream>>>(rp, csr, h16, agg16, N);
    layer_kernel<<<(N + 63) / 64, 256, 0, stream>>>(agg16, h16, wpk2, b_l2, lnw2, lnb2, h16, N);

    // ---- classifier ----
    cls_kernel<<<(N + 15) / 16, 256, 0, stream>>>(h16, w0p, c_b0, c_w1, c_b1, out, N);
}

// Round 16
// 269.317 us; speedup vs baseline: 1.9070x; 1.2054x over previous
//
#include <hip/hip_runtime.h>
#include <hip/hip_fp16.h>

#define HID 128

typedef _Float16 h2_t __attribute__((ext_vector_type(2)));
typedef _Float16 half8 __attribute__((ext_vector_type(8)));
typedef float f32x4 __attribute__((ext_vector_type(4)));

static __device__ __forceinline__ float fdot2(__half2 a, __half2 b, float c) {
    return __builtin_amdgcn_fdot2(__builtin_bit_cast(h2_t, a), __builtin_bit_cast(h2_t, b), c, false);
}

// ---------------- degree histogram, XCD/dst-range partitioned ----------------
__global__ __launch_bounds__(256) void deg_kernel(const int* __restrict__ ei,
                                                  int* __restrict__ deg, int E, int n) {
    int grp  = blockIdx.x & 7;
    int blk  = blockIdx.x >> 3;
    int nblk = gridDim.x >> 3;
    int lo = (int)(((long long)n * grp) >> 3);
    int hi = (int)(((long long)n * (grp + 1)) >> 3);
    for (int e = blk * 256 + threadIdx.x; e < E; e += nblk * 256) {
        int dst = ei[E + e];
        if (dst >= lo && dst < hi) atomicAdd(&deg[dst], 1);
    }
}

// ---------------- scan stage 1 ----------------
__global__ __launch_bounds__(256) void part_kernel(const int* __restrict__ deg,
                                                   int* __restrict__ part, int n) {
    int i = blockIdx.x * 256 + threadIdx.x;
    int v = (i < n) ? deg[i] : 0;
    #pragma unroll
    for (int m = 1; m < 64; m <<= 1) v += __shfl_xor(v, m);
    __shared__ int w[4];
    int lane = threadIdx.x & 63, wv = threadIdx.x >> 6;
    if (lane == 0) w[wv] = v;
    __syncthreads();
    if (threadIdx.x == 0) part[blockIdx.x] = w[0] + w[1] + w[2] + w[3];
}

// ---------------- scan stage 2 ----------------
__global__ __launch_bounds__(1024) void scanpart_kernel(int* __restrict__ part, int nb) {
    __shared__ int s[1024];
    int t = threadIdx.x;
    int v = (t < nb) ? part[t] : 0;
    int orig = v;
    s[t] = v;
    __syncthreads();
    for (int off = 1; off < 1024; off <<= 1) {
        int u = (t >= off) ? s[t - off] : 0;
        __syncthreads();
        s[t] += u;
        __syncthreads();
    }
    if (t < nb) part[t] = s[t] - orig;   // exclusive
}

// ---------------- scan stage 3 ----------------
__global__ __launch_bounds__(256) void rp_kernel(const int* __restrict__ deg,
                                                 const int* __restrict__ part,
                                                 int* __restrict__ rp,
                                                 int* __restrict__ cursor, int n) {
    int tid = threadIdx.x, lane = tid & 63, wv = tid >> 6;
    int i = blockIdx.x * 256 + tid;
    int v = (i < n) ? deg[i] : 0;
    int orig = v;
    #pragma unroll
    for (int off = 1; off < 64; off <<= 1) {
        int t = __shfl_up(v, off);
        if (lane >= off) v += t;
    }
    __shared__ int wsum[4];
    if (lane == 63) wsum[wv] = v;
    __syncthreads();
    int wbase = 0;
    #pragma unroll
    for (int w = 0; w < 4; ++w) if (w < wv) wbase += wsum[w];
    int excl = part[blockIdx.x] + wbase + v - orig;
    if (i < n) { rp[i] = excl; cursor[i] = excl; }
    if (i == n - 1) rp[n] = excl + orig;
}

// ---------------- CSR fill, XCD/dst-range partitioned ----------------
__global__ __launch_bounds__(256) void fill_kernel(const int* __restrict__ ei,
                                                   int* __restrict__ cursor,
                                                   int* __restrict__ csr_src, int E, int n) {
    int grp  = blockIdx.x & 7;
    int blk  = blockIdx.x >> 3;
    int nblk = gridDim.x >> 3;
    int lo = (int)(((long long)n * grp) >> 3);
    int hi = (int)(((long long)n * (grp + 1)) >> 3);
    for (int e = blk * 256 + threadIdx.x; e < E; e += nblk * 256) {
        int dst = ei[E + e];
        if (dst >= lo && dst < hi) {
            int pos = atomicAdd(&cursor[dst], 1);
            csr_src[pos] = ei[e];
        }
    }
}

// ---------------- 128-dim pull aggregation (fp16 in, fp32 sum, fp16 MEAN out) ----------------
__global__ __launch_bounds__(256) void aggp_kernel(const int* __restrict__ rp,
                                                   const int* __restrict__ ci,
                                                   const __half* __restrict__ h16,
                                                   __half* __restrict__ agg16, int n) {
    int node = (blockIdx.x * 256 + threadIdx.x) >> 6;
    if (node >= n) return;
    int lane = threadIdx.x & 63;
    float2 a0 = make_float2(0.f, 0.f), a1 = make_float2(0.f, 0.f);
    float2 a2 = make_float2(0.f, 0.f), a3 = make_float2(0.f, 0.f);
    float2 a4 = make_float2(0.f, 0.f), a5 = make_float2(0.f, 0.f);
    float2 a6 = make_float2(0.f, 0.f), a7 = make_float2(0.f, 0.f);
    int beg = rp[node], end = rp[node + 1];
    int j = beg;
    for (; j + 7 < end; j += 8) {
        int s0 = ci[j],     s1 = ci[j + 1], s2 = ci[j + 2], s3 = ci[j + 3];
        int s4 = ci[j + 4], s5 = ci[j + 5], s6 = ci[j + 6], s7 = ci[j + 7];
        float2 f0 = __half22float2(*(const __half2*)(h16 + (size_t)s0 * HID + lane * 2));
        float2 f1 = __half22float2(*(const __half2*)(h16 + (size_t)s1 * HID + lane * 2));
        float2 f2 = __half22float2(*(const __half2*)(h16 + (size_t)s2 * HID + lane * 2));
        float2 f3 = __half22float2(*(const __half2*)(h16 + (size_t)s3 * HID + lane * 2));
        float2 f4 = __half22float2(*(const __half2*)(h16 + (size_t)s4 * HID + lane * 2));
        float2 f5 = __half22float2(*(const __half2*)(h16 + (size_t)s5 * HID + lane * 2));
        float2 f6 = __half22float2(*(const __half2*)(h16 + (size_t)s6 * HID + lane * 2));
        float2 f7 = __half22float2(*(const __half2*)(h16 + (size_t)s7 * HID + lane * 2));
        a0.x += f0.x; a0.y += f0.y;  a1.x += f1.x; a1.y += f1.y;
        a2.x += f2.x; a2.y += f2.y;  a3.x += f3.x; a3.y += f3.y;
        a4.x += f4.x; a4.y += f4.y;  a5.x += f5.x; a5.y += f5.y;
        a6.x += f6.x; a6.y += f6.y;  a7.x += f7.x; a7.y += f7.y;
    }
    for (; j + 3 < end; j += 4) {
        int s0 = ci[j], s1 = ci[j + 1], s2 = ci[j + 2], s3 = ci[j + 3];
        float2 f0 = __half22float2(*(const __half2*)(h16 + (size_t)s0 * HID + lane * 2));
        float2 f1 = __half22float2(*(const __half2*)(h16 + (size_t)s1 * HID + lane * 2));
        float2 f2 = __half22float2(*(const __half2*)(h16 + (size_t)s2 * HID + lane * 2));
        float2 f3 = __half22float2(*(const __half2*)(h16 + (size_t)s3 * HID + lane * 2));
        a0.x += f0.x; a0.y += f0.y;  a1.x += f1.x; a1.y += f1.y;
        a2.x += f2.x; a2.y += f2.y;  a3.x += f3.x; a3.y += f3.y;
    }
    for (; j < end; ++j) {
        int s0 = ci[j];
        float2 f0 = __half22float2(*(const __half2*)(h16 + (size_t)s0 * HID + lane * 2));
        a0.x += f0.x; a0.y += f0.y;
    }
    float inv = 1.0f / fmaxf((float)(end - beg), 1.0f);
    float ox = (a0.x + a1.x + a2.x + a3.x + a4.x + a5.x + a6.x + a7.x) * inv;
    float oy = (a0.y + a1.y + a2.y + a3.y + a4.y + a5.y + a6.y + a7.y) * inv;
    *(__half2*)(agg16 + (size_t)node * HID + lane * 2) = __floats2half2_rn(ox, oy);
}

// ---------------- layer 0: fused 11-dim pull-agg + dual matmul + LN + ReLU -> h16 ----------------
__global__ __launch_bounds__(256) void layer0_kernel(
    const float* __restrict__ x, const int* __restrict__ rp, const int* __restrict__ ci,
    const float* __restrict__ w_l, const float* __restrict__ b_l, const float* __restrict__ w_r,
    const float* __restrict__ ln_w, const float* __restrict__ ln_b,
    __half* __restrict__ h16, int n)
{
    int node = (blockIdx.x * 256 + threadIdx.x) >> 6;
    int lane = threadIdx.x & 63;
    if (node >= n) return;
    int beg = rp[node], end = rp[node + 1];
    int g = lane / 11;
    int d = lane - g * 11;
    float acc0 = 0.f, acc1 = 0.f;
    int j = beg + g;
    if (g < 5) {
        for (; j + 5 < end; j += 10) {
            int s0 = ci[j], s1 = ci[j + 5];
            acc0 += x[(size_t)s0 * 11 + d];
            acc1 += x[(size_t)s1 * 11 + d];
        }
        for (; j < end; j += 5) {
            int s0 = ci[j];
            acc0 += x[(size_t)s0 * 11 + d];
        }
    }
    float acc = acc0 + acc1;
    float aggk = 0.f;
    #pragma unroll
    for (int gg = 0; gg < 5; ++gg) {
        aggk += __shfl(acc, (lane < 11) ? (lane + 11 * gg) : lane);
    }
    float inv = 1.0f / fmaxf((float)(end - beg), 1.0f);
    float v0 = b_l[lane], v1 = b_l[lane + 64];
    #pragma unroll
    for (int k = 0; k < 11; ++k) {
        float a  = __shfl(aggk, k) * inv;
        float xi = x[(size_t)node * 11 + k];
        v0 += a * w_l[k * HID + lane]      + xi * w_r[k * HID + lane];
        v1 += a * w_l[k * HID + lane + 64] + xi * w_r[k * HID + lane + 64];
    }
    float s = v0 + v1, s2 = v0 * v0 + v1 * v1;
    #pragma unroll
    for (int m = 1; m < 64; m <<= 1) { s += __shfl_xor(s, m); s2 += __shfl_xor(s2, m); }
    float mu  = s * (1.0f / HID);
    float var = s2 * (1.0f / HID) - mu * mu;
    float rstd = rsqrtf(var + 1e-5f);
    float o0 = fmaxf((v0 - mu) * rstd * ln_w[lane]      + ln_b[lane],      0.0f);
    float o1 = fmaxf((v1 - mu) * rstd * ln_w[lane + 64] + ln_b[lane + 64], 0.0f);
    h16[(size_t)node * HID + lane]      = __float2half_rn(o0);
    h16[(size_t)node * HID + lane + 64] = __float2half_rn(o1);
}

// ---------------- MFMA B-fragment weight pack ----------------
// wf[((kt*8+ct)*64 + lane)*8 + j] = W[kt*32 + (lane>>4)*8 + j][ct*16 + (lane&15)] as fp16,
// where W = concat(w_l, w_r) over K=256. One fragment = one wave's contiguous 1KB B read.
__global__ __launch_bounds__(256) void wfrag_kernel(const float* __restrict__ wl,
                                                    const float* __restrict__ wr,
                                                    __half* __restrict__ wf) {
    int idx = blockIdx.x * 256 + threadIdx.x;   // over 8*8*64 = 4096
    if (idx >= 4096) return;
    int kt = idx >> 9;
    int ct = (idx >> 6) & 7;
    int l  = idx & 63;
    int col = ct * 16 + (l & 15);
    int kbase = kt * 32 + (l >> 4) * 8;
    #pragma unroll
    for (int j = 0; j < 8; ++j) {
        int k = kbase + j;
        const float* W = (k < HID) ? wl : wr;
        int kk = k & (HID - 1);
        wf[(size_t)idx * 8 + j] = __float2half_rn(W[kk * HID + col]);
    }
}

// ---------------- cls weight pack: fp32 [128][64] -> fp16 k-pair-packed [64][64] ----------------
__global__ __launch_bounds__(256) void wpack_cls_kernel(const float* __restrict__ w0,
                                                        __half2* __restrict__ w0p) {
    int idx = blockIdx.x * 256 + threadIdx.x;   // over 64*64
    if (idx >= 64 * 64) return;
    int p = idx >> 6, c = idx & 63;
    w0p[idx] = __floats2half2_rn(w0[(2 * p) * 64 + c], w0[(2 * p + 1) * 64 + c]);
}

// ---------------- layers 1/2: MFMA GEMM (64 nodes/block, 4 waves x 16-row tiles) ----------------
// A-fragment (16x16x32): lane l holds A[l&15][(l>>4)*8 + j] -> ds_read_b128 from LDS tile.
// B-fragment: pre-packed wf (1KB contiguous per fragment). C/D: col=lane&15, row=(lane>>4)*4+reg.
// Epilogue: bias + LN (16-lane shfl row-reduce) + ReLU + residual (from LDS h half) -> h16out.
// Alias-safe (h16out == h16in): block stages its own 64 rows fully before any global write.
__global__ __launch_bounds__(256) void layer_kernel(
    const __half* __restrict__ agg16, const __half* __restrict__ h16in,
    const __half* __restrict__ wf, const float* __restrict__ b_l,
    const float* __restrict__ ln_w, const float* __restrict__ ln_b,
    __half* __restrict__ h16out, int n)
{
    __shared__ __half lds[64][264];   // [node][agg(0..127) | h_in(128..255)]
    int base = blockIdx.x * 64;
    int tid = threadIdx.x;
    #pragma unroll
    for (int i = 0; i < 8; ++i) {
        int idx = tid + i * 256;
        int row = idx >> 5;
        int c4  = (idx & 31) * 4;
        int node = base + row;
        float2 a = make_float2(0.f, 0.f);
        float2 h = make_float2(0.f, 0.f);
        if (node < n) {
            a = *(const float2*)(agg16 + (size_t)node * HID + c4);
            h = *(const float2*)(h16in + (size_t)node * HID + c4);
        }
        *(float2*)&lds[row][c4]       = a;
        *(float2*)&lds[row][HID + c4] = h;
    }
    __syncthreads();

    int w = tid >> 6;              // wave -> 16-row tile
    int l = tid & 63;
    int g = l >> 4, cl = l & 15;

    f32x4 acc[8];
    #pragma unroll
    for (int ct = 0; ct < 8; ++ct) acc[ct] = (f32x4){0.f, 0.f, 0.f, 0.f};

    #pragma unroll
    for (int kt = 0; kt < 8; ++kt) {
        half8 a = *(const half8*)&lds[w * 16 + cl][kt * 32 + g * 8];
        #pragma unroll
        for (int ct = 0; ct < 8; ++ct) {
            half8 b = *(const half8*)(wf + ((size_t)(kt * 8 + ct) * 64 + l) * 8);
            acc[ct] = __builtin_amdgcn_mfma_f32_16x16x32_f16(a, b, acc[ct], 0, 0, 0);
        }
    }

    // per-lane column params for cols ct*16 + cl
    float bl8[8], gw8[8], gb8[8];
    #pragma unroll
    for (int ct = 0; ct < 8; ++ct) {
        bl8[ct] = b_l[ct * 16 + cl];
        gw8[ct] = ln_w[ct * 16 + cl];
        gb8[ct] = ln_b[ct * 16 + cl];
    }

    #pragma unroll
    for (int r = 0; r < 4; ++r) {
        int row = w * 16 + g * 4 + r;      // D row mapping
        float v[8];
        float s = 0.f, s2 = 0.f;
        #pragma unroll
        for (int ct = 0; ct < 8; ++ct) {
            v[ct] = acc[ct][r] + bl8[ct];
            s += v[ct]; s2 += v[ct] * v[ct];
        }
        #pragma unroll
        for (int m = 1; m < 16; m <<= 1) { s += __shfl_xor(s, m); s2 += __shfl_xor(s2, m); }
        float mu  = s * (1.0f / HID);
        float var = s2 * (1.0f / HID) - mu * mu;
        float rstd = rsqrtf(var + 1e-5f);
        int node = base + row;
        if (node < n) {
            #pragma unroll
            for (int ct = 0; ct < 8; ++ct) {
                float o = fmaxf((v[ct] - mu) * rstd * gw8[ct] + gb8[ct], 0.f)
                          + __half2float(lds[row][HID + ct * 16 + cl]);
                h16out[(size_t)node * HID + ct * 16 + cl] = __float2half_rn(o);
            }
        }
    }
}

// ---------------- classifier: dot2, 16 nodes/block (4/wave), 2 accumulators ----------------
__global__ __launch_bounds__(256) void cls_kernel(
    const __half* __restrict__ h, const __half2* __restrict__ w0p, const float* __restrict__ b0,
    const float* __restrict__ w1, const float* __restrict__ b1, float* __restrict__ out, int n)
{
    __shared__ __half2 w0s[64 * 64];   // 16 KB, k-pair-packed
    int tid = threadIdx.x;
    #pragma unroll
    for (int i = 0; i < 16; ++i) w0s[tid + i * 256] = w0p[tid + i * 256];
    __syncthreads();
    int lane = tid & 63, wv = tid >> 6;
    float bb0 = b0[lane], ww1 = w1[lane], bb1 = b1[0];
    #pragma unroll 1
    for (int q = 0; q < 4; ++q) {
        int node = blockIdx.x * 16 + wv * 4 + q;
        if (node >= n) break;
        const __half2* hr = (const __half2*)(h + (size_t)node * HID);
        float s0 = 0.f, s1 = 0.f;
        #pragma unroll
        for (int p = 0; p < 64; p += 2) {
            s0 = fdot2(hr[p],     w0s[(p + 0) * 64 + lane], s0);
            s1 = fdot2(hr[p + 1], w0s[(p + 1) * 64 + lane], s1);
        }
        float s = fmaxf(s0 + s1 + bb0, 0.f);
        float t = s * ww1;
        #pragma unroll
        for (int m = 1; m < 64; m <<= 1) t += __shfl_xor(t, m);
        if (lane == 0) out[node] = t + bb1;
    }
}

extern "C" void kernel_launch(void* const* d_in, const int* in_sizes, int n_in,
                              void* d_out, int out_size, void* d_ws, size_t ws_size,
                              hipStream_t stream) {
    const float* x  = (const float*)d_in[0];
    const int*   ei = (const int*)d_in[1];     // integer inputs arrive as int32
    const float* w_l0 = (const float*)d_in[2];
    const float* b_l0 = (const float*)d_in[3];
    const float* w_r0 = (const float*)d_in[4];
    const float* lnw0 = (const float*)d_in[5];
    const float* lnb0 = (const float*)d_in[6];
    const float* w_l1 = (const float*)d_in[7];
    const float* b_l1 = (const float*)d_in[8];
    const float* w_r1 = (const float*)d_in[9];
    const float* lnw1 = (const float*)d_in[10];
    const float* lnb1 = (const float*)d_in[11];
    const float* w_l2 = (const float*)d_in[12];
    const float* b_l2 = (const float*)d_in[13];
    const float* w_r2 = (const float*)d_in[14];
    const float* lnw2 = (const float*)d_in[15];
    const float* lnb2 = (const float*)d_in[16];
    const float* c_w0 = (const float*)d_in[17];
    const float* c_b0 = (const float*)d_in[18];
    const float* c_w1 = (const float*)d_in[19];
    const float* c_b1 = (const float*)d_in[20];
    float* out = (float*)d_out;

    int N = in_sizes[0] / 11;
    int E = in_sizes[1] / 2;
    int nb = (N + 255) / 256;

    // workspace: [deg: N][rp: N+1][cursor: N][csr: E][part: nb]
    //            [h16][agg16][wf1: 32768 halves][wf2: 32768 halves][w0p: 4096 half2]
    int*     deg    = (int*)d_ws;
    int*     rp     = deg + N;
    int*     cursor = rp + (N + 1);
    int*     csr    = cursor + N;
    int*     part   = csr + E;
    __half*  h16    = (__half*)(part + ((nb + 63) & ~63));
    __half*  agg16  = h16 + (size_t)N * HID;
    __half*  wf1    = agg16 + (size_t)N * HID;
    __half*  wf2    = wf1 + 4096 * 8;
    __half2* w0p    = (__half2*)(wf2 + 4096 * 8);

    // ---- CSR build (dst-range partitioned across XCDs) + weight packs ----
    hipMemsetAsync(deg, 0, (size_t)N * sizeof(int), stream);
    deg_kernel<<<8 * 512, 256, 0, stream>>>(ei, deg, E, N);
    part_kernel<<<nb, 256, 0, stream>>>(deg, part, N);
    scanpart_kernel<<<1, 1024, 0, stream>>>(part, nb);
    rp_kernel<<<nb, 256, 0, stream>>>(deg, part, rp, cursor, N);
    fill_kernel<<<8 * 512, 256, 0, stream>>>(ei, cursor, csr, E, N);
    wfrag_kernel<<<16, 256, 0, stream>>>(w_l1, w_r1, wf1);
    wfrag_kernel<<<16, 256, 0, stream>>>(w_l2, w_r2, wf2);
    wpack_cls_kernel<<<16, 256, 0, stream>>>(c_w0, w0p);

    int nodeBlocks = (N + 3) / 4;

    // ---- layer 0 ----  h0 -> h16
    layer0_kernel<<<nodeBlocks, 256, 0, stream>>>(x, rp, csr, w_l0, b_l0, w_r0, lnw0, lnb0, h16, N);

    // ---- layer 1 ----  gather(h16)->agg16 ; layer(agg16, h16) -> h16
    aggp_kernel<<<nodeBlocks, 256, 0, stream>>>(rp, csr, h16, agg16, N);
    layer_kernel<<<(N + 63) / 64, 256, 0, stream>>>(agg16, h16, wf1, b_l1, lnw1, lnb1, h16, N);

    // ---- layer 2 ----
    aggp_kernel<<<nodeBlocks, 256, 0, stream>>>(rp, csr, h16, agg16, N);
    layer_kernel<<<(N + 63) / 64, 256, 0, stream>>>(agg16, h16, wf2, b_l2, lnw2, lnb2, h16, N);

    // ---- classifier ----
    cls_kernel<<<(N + 15) / 16, 256, 0, stream>>>(h16, w0p, c_b0, c_w1, c_b1, out, N);
}

// Round 17
// 268.716 us; speedup vs baseline: 1.9112x; 1.0022x over previous
//
#include <hip/hip_runtime.h>
#include <hip/hip_fp16.h>

#define HID 128

typedef _Float16 h2_t __attribute__((ext_vector_type(2)));
typedef _Float16 half8 __attribute__((ext_vector_type(8)));
typedef float f32x4 __attribute__((ext_vector_type(4)));

static __device__ __forceinline__ float fdot2(__half2 a, __half2 b, float c) {
    return __builtin_amdgcn_fdot2(__builtin_bit_cast(h2_t, a), __builtin_bit_cast(h2_t, b), c, false);
}

// ---------------- fast zero (replaces runtime fillBuffer: 40us -> ~2us) ----------------
__global__ __launch_bounds__(256) void zero_kernel(int4* __restrict__ p, int n4) {
    int i = blockIdx.x * 256 + threadIdx.x;
    if (i < n4) p[i] = make_int4(0, 0, 0, 0);
}

// ---------------- degree histogram, XCD/dst-range partitioned ----------------
__global__ __launch_bounds__(256) void deg_kernel(const int* __restrict__ ei,
                                                  int* __restrict__ deg, int E, int n) {
    int grp  = blockIdx.x & 7;
    int blk  = blockIdx.x >> 3;
    int nblk = gridDim.x >> 3;
    int lo = (int)(((long long)n * grp) >> 3);
    int hi = (int)(((long long)n * (grp + 1)) >> 3);
    for (int e = blk * 256 + threadIdx.x; e < E; e += nblk * 256) {
        int dst = ei[E + e];
        if (dst >= lo && dst < hi) atomicAdd(&deg[dst], 1);
    }
}

// ---------------- scan stage 1 ----------------
__global__ __launch_bounds__(256) void part_kernel(const int* __restrict__ deg,
                                                   int* __restrict__ part, int n) {
    int i = blockIdx.x * 256 + threadIdx.x;
    int v = (i < n) ? deg[i] : 0;
    #pragma unroll
    for (int m = 1; m < 64; m <<= 1) v += __shfl_xor(v, m);
    __shared__ int w[4];
    int lane = threadIdx.x & 63, wv = threadIdx.x >> 6;
    if (lane == 0) w[wv] = v;
    __syncthreads();
    if (threadIdx.x == 0) part[blockIdx.x] = w[0] + w[1] + w[2] + w[3];
}

// ---------------- scan stage 2 ----------------
__global__ __launch_bounds__(1024) void scanpart_kernel(int* __restrict__ part, int nb) {
    __shared__ int s[1024];
    int t = threadIdx.x;
    int v = (t < nb) ? part[t] : 0;
    int orig = v;
    s[t] = v;
    __syncthreads();
    for (int off = 1; off < 1024; off <<= 1) {
        int u = (t >= off) ? s[t - off] : 0;
        __syncthreads();
        s[t] += u;
        __syncthreads();
    }
    if (t < nb) part[t] = s[t] - orig;   // exclusive
}

// ---------------- scan stage 3 ----------------
__global__ __launch_bounds__(256) void rp_kernel(const int* __restrict__ deg,
                                                 const int* __restrict__ part,
                                                 int* __restrict__ rp,
                                                 int* __restrict__ cursor, int n) {
    int tid = threadIdx.x, lane = tid & 63, wv = tid >> 6;
    int i = blockIdx.x * 256 + tid;
    int v = (i < n) ? deg[i] : 0;
    int orig = v;
    #pragma unroll
    for (int off = 1; off < 64; off <<= 1) {
        int t = __shfl_up(v, off);
        if (lane >= off) v += t;
    }
    __shared__ int wsum[4];
    if (lane == 63) wsum[wv] = v;
    __syncthreads();
    int wbase = 0;
    #pragma unroll
    for (int w = 0; w < 4; ++w) if (w < wv) wbase += wsum[w];
    int excl = part[blockIdx.x] + wbase + v - orig;
    if (i < n) { rp[i] = excl; cursor[i] = excl; }
    if (i == n - 1) rp[n] = excl + orig;
}

// ---------------- CSR fill, XCD/dst-range partitioned ----------------
__global__ __launch_bounds__(256) void fill_kernel(const int* __restrict__ ei,
                                                   int* __restrict__ cursor,
                                                   int* __restrict__ csr_src, int E, int n) {
    int grp  = blockIdx.x & 7;
    int blk  = blockIdx.x >> 3;
    int nblk = gridDim.x >> 3;
    int lo = (int)(((long long)n * grp) >> 3);
    int hi = (int)(((long long)n * (grp + 1)) >> 3);
    for (int e = blk * 256 + threadIdx.x; e < E; e += nblk * 256) {
        int dst = ei[E + e];
        if (dst >= lo && dst < hi) {
            int pos = atomicAdd(&cursor[dst], 1);
            csr_src[pos] = ei[e];
        }
    }
}

// ---------------- 128-dim pull aggregation (fp16 in, fp32 sum, fp16 MEAN out) ----------------
__global__ __launch_bounds__(256) void aggp_kernel(const int* __restrict__ rp,
                                                   const int* __restrict__ ci,
                                                   const __half* __restrict__ h16,
                                                   __half* __restrict__ agg16, int n) {
    int node = (blockIdx.x * 256 + threadIdx.x) >> 6;
    if (node >= n) return;
    int lane = threadIdx.x & 63;
    float2 a0 = make_float2(0.f, 0.f), a1 = make_float2(0.f, 0.f);
    float2 a2 = make_float2(0.f, 0.f), a3 = make_float2(0.f, 0.f);
    float2 a4 = make_float2(0.f, 0.f), a5 = make_float2(0.f, 0.f);
    float2 a6 = make_float2(0.f, 0.f), a7 = make_float2(0.f, 0.f);
    int beg = rp[node], end = rp[node + 1];
    int j = beg;
    for (; j + 7 < end; j += 8) {
        int s0 = ci[j],     s1 = ci[j + 1], s2 = ci[j + 2], s3 = ci[j + 3];
        int s4 = ci[j + 4], s5 = ci[j + 5], s6 = ci[j + 6], s7 = ci[j + 7];
        float2 f0 = __half22float2(*(const __half2*)(h16 + (size_t)s0 * HID + lane * 2));
        float2 f1 = __half22float2(*(const __half2*)(h16 + (size_t)s1 * HID + lane * 2));
        float2 f2 = __half22float2(*(const __half2*)(h16 + (size_t)s2 * HID + lane * 2));
        float2 f3 = __half22float2(*(const __half2*)(h16 + (size_t)s3 * HID + lane * 2));
        float2 f4 = __half22float2(*(const __half2*)(h16 + (size_t)s4 * HID + lane * 2));
        float2 f5 = __half22float2(*(const __half2*)(h16 + (size_t)s5 * HID + lane * 2));
        float2 f6 = __half22float2(*(const __half2*)(h16 + (size_t)s6 * HID + lane * 2));
        float2 f7 = __half22float2(*(const __half2*)(h16 + (size_t)s7 * HID + lane * 2));
        a0.x += f0.x; a0.y += f0.y;  a1.x += f1.x; a1.y += f1.y;
        a2.x += f2.x; a2.y += f2.y;  a3.x += f3.x; a3.y += f3.y;
        a4.x += f4.x; a4.y += f4.y;  a5.x += f5.x; a5.y += f5.y;
        a6.x += f6.x; a6.y += f6.y;  a7.x += f7.x; a7.y += f7.y;
    }
    for (; j + 3 < end; j += 4) {
        int s0 = ci[j], s1 = ci[j + 1], s2 = ci[j + 2], s3 = ci[j + 3];
        float2 f0 = __half22float2(*(const __half2*)(h16 + (size_t)s0 * HID + lane * 2));
        float2 f1 = __half22float2(*(const __half2*)(h16 + (size_t)s1 * HID + lane * 2));
        float2 f2 = __half22float2(*(const __half2*)(h16 + (size_t)s2 * HID + lane * 2));
        float2 f3 = __half22float2(*(const __half2*)(h16 + (size_t)s3 * HID + lane * 2));
        a0.x += f0.x; a0.y += f0.y;  a1.x += f1.x; a1.y += f1.y;
        a2.x += f2.x; a2.y += f2.y;  a3.x += f3.x; a3.y += f3.y;
    }
    for (; j < end; ++j) {
        int s0 = ci[j];
        float2 f0 = __half22float2(*(const __half2*)(h16 + (size_t)s0 * HID + lane * 2));
        a0.x += f0.x; a0.y += f0.y;
    }
    float inv = 1.0f / fmaxf((float)(end - beg), 1.0f);
    float ox = (a0.x + a1.x + a2.x + a3.x + a4.x + a5.x + a6.x + a7.x) * inv;
    float oy = (a0.y + a1.y + a2.y + a3.y + a4.y + a5.y + a6.y + a7.y) * inv;
    *(__half2*)(agg16 + (size_t)node * HID + lane * 2) = __floats2half2_rn(ox, oy);
}

// ---------------- layer 0: fused 11-dim pull-agg + dual matmul + LN + ReLU -> h16 ----------------
__global__ __launch_bounds__(256) void layer0_kernel(
    const float* __restrict__ x, const int* __restrict__ rp, const int* __restrict__ ci,
    const float* __restrict__ w_l, const float* __restrict__ b_l, const float* __restrict__ w_r,
    const float* __restrict__ ln_w, const float* __restrict__ ln_b,
    __half* __restrict__ h16, int n)
{
    int node = (blockIdx.x * 256 + threadIdx.x) >> 6;
    int lane = threadIdx.x & 63;
    if (node >= n) return;
    int beg = rp[node], end = rp[node + 1];
    int g = lane / 11;
    int d = lane - g * 11;
    float acc0 = 0.f, acc1 = 0.f;
    int j = beg + g;
    if (g < 5) {
        for (; j + 5 < end; j += 10) {
            int s0 = ci[j], s1 = ci[j + 5];
            acc0 += x[(size_t)s0 * 11 + d];
            acc1 += x[(size_t)s1 * 11 + d];
        }
        for (; j < end; j += 5) {
            int s0 = ci[j];
            acc0 += x[(size_t)s0 * 11 + d];
        }
    }
    float acc = acc0 + acc1;
    float aggk = 0.f;
    #pragma unroll
    for (int gg = 0; gg < 5; ++gg) {
        aggk += __shfl(acc, (lane < 11) ? (lane + 11 * gg) : lane);
    }
    float inv = 1.0f / fmaxf((float)(end - beg), 1.0f);
    float v0 = b_l[lane], v1 = b_l[lane + 64];
    #pragma unroll
    for (int k = 0; k < 11; ++k) {
        float a  = __shfl(aggk, k) * inv;
        float xi = x[(size_t)node * 11 + k];
        v0 += a * w_l[k * HID + lane]      + xi * w_r[k * HID + lane];
        v1 += a * w_l[k * HID + lane + 64] + xi * w_r[k * HID + lane + 64];
    }
    float s = v0 + v1, s2 = v0 * v0 + v1 * v1;
    #pragma unroll
    for (int m = 1; m < 64; m <<= 1) { s += __shfl_xor(s, m); s2 += __shfl_xor(s2, m); }
    float mu  = s * (1.0f / HID);
    float var = s2 * (1.0f / HID) - mu * mu;
    float rstd = rsqrtf(var + 1e-5f);
    float o0 = fmaxf((v0 - mu) * rstd * ln_w[lane]      + ln_b[lane],      0.0f);
    float o1 = fmaxf((v1 - mu) * rstd * ln_w[lane + 64] + ln_b[lane + 64], 0.0f);
    h16[(size_t)node * HID + lane]      = __float2half_rn(o0);
    h16[(size_t)node * HID + lane + 64] = __float2half_rn(o1);
}

// ---------------- MFMA B-fragment weight pack ----------------
__global__ __launch_bounds__(256) void wfrag_kernel(const float* __restrict__ wl,
                                                    const float* __restrict__ wr,
                                                    __half* __restrict__ wf) {
    int idx = blockIdx.x * 256 + threadIdx.x;   // over 8*8*64 = 4096
    if (idx >= 4096) return;
    int kt = idx >> 9;
    int ct = (idx >> 6) & 7;
    int l  = idx & 63;
    int col = ct * 16 + (l & 15);
    int kbase = kt * 32 + (l >> 4) * 8;
    #pragma unroll
    for (int j = 0; j < 8; ++j) {
        int k = kbase + j;
        const float* W = (k < HID) ? wl : wr;
        int kk = k & (HID - 1);
        wf[(size_t)idx * 8 + j] = __float2half_rn(W[kk * HID + col]);
    }
}

// ---------------- cls weight pack: fp32 [128][64] -> fp16 k-pair-packed [64][64] ----------------
__global__ __launch_bounds__(256) void wpack_cls_kernel(const float* __restrict__ w0,
                                                        __half2* __restrict__ w0p) {
    int idx = blockIdx.x * 256 + threadIdx.x;   // over 64*64
    if (idx >= 64 * 64) return;
    int p = idx >> 6, c = idx & 63;
    w0p[idx] = __floats2half2_rn(w0[(2 * p) * 64 + c], w0[(2 * p + 1) * 64 + c]);
}

// ---------------- layers 1/2: MFMA GEMM (64 nodes/block, 4 waves x 16-row tiles) ----------------
__global__ __launch_bounds__(256) void layer_kernel(
    const __half* __restrict__ agg16, const __half* __restrict__ h16in,
    const __half* __restrict__ wf, const float* __restrict__ b_l,
    const float* __restrict__ ln_w, const float* __restrict__ ln_b,
    __half* __restrict__ h16out, int n)
{
    __shared__ __half lds[64][264];   // [node][agg(0..127) | h_in(128..255)]
    int base = blockIdx.x * 64;
    int tid = threadIdx.x;
    #pragma unroll
    for (int i = 0; i < 8; ++i) {
        int idx = tid + i * 256;
        int row = idx >> 5;
        int c4  = (idx & 31) * 4;
        int node = base + row;
        float2 a = make_float2(0.f, 0.f);
        float2 h = make_float2(0.f, 0.f);
        if (node < n) {
            a = *(const float2*)(agg16 + (size_t)node * HID + c4);
            h = *(const float2*)(h16in + (size_t)node * HID + c4);
        }
        *(float2*)&lds[row][c4]       = a;
        *(float2*)&lds[row][HID + c4] = h;
    }
    __syncthreads();

    int w = tid >> 6;              // wave -> 16-row tile
    int l = tid & 63;
    int g = l >> 4, cl = l & 15;

    f32x4 acc[8];
    #pragma unroll
    for (int ct = 0; ct < 8; ++ct) acc[ct] = (f32x4){0.f, 0.f, 0.f, 0.f};

    #pragma unroll
    for (int kt = 0; kt < 8; ++kt) {
        half8 a = *(const half8*)&lds[w * 16 + cl][kt * 32 + g * 8];
        #pragma unroll
        for (int ct = 0; ct < 8; ++ct) {
            half8 b = *(const half8*)(wf + ((size_t)(kt * 8 + ct) * 64 + l) * 8);
            acc[ct] = __builtin_amdgcn_mfma_f32_16x16x32_f16(a, b, acc[ct], 0, 0, 0);
        }
    }

    float bl8[8], gw8[8], gb8[8];
    #pragma unroll
    for (int ct = 0; ct < 8; ++ct) {
        bl8[ct] = b_l[ct * 16 + cl];
        gw8[ct] = ln_w[ct * 16 + cl];
        gb8[ct] = ln_b[ct * 16 + cl];
    }

    #pragma unroll
    for (int r = 0; r < 4; ++r) {
        int row = w * 16 + g * 4 + r;      // D row mapping
        float v[8];
        float s = 0.f, s2 = 0.f;
        #pragma unroll
        for (int ct = 0; ct < 8; ++ct) {
            v[ct] = acc[ct][r] + bl8[ct];
            s += v[ct]; s2 += v[ct] * v[ct];
        }
        #pragma unroll
        for (int m = 1; m < 16; m <<= 1) { s += __shfl_xor(s, m); s2 += __shfl_xor(s2, m); }
        float mu  = s * (1.0f / HID);
        float var = s2 * (1.0f / HID) - mu * mu;
        float rstd = rsqrtf(var + 1e-5f);
        int node = base + row;
        if (node < n) {
            #pragma unroll
            for (int ct = 0; ct < 8; ++ct) {
                float o = fmaxf((v[ct] - mu) * rstd * gw8[ct] + gb8[ct], 0.f)
                          + __half2float(lds[row][HID + ct * 16 + cl]);
                h16out[(size_t)node * HID + ct * 16 + cl] = __float2half_rn(o);
            }
        }
    }
}

// ---------------- classifier: dot2, 16 nodes/block (4/wave), 2 accumulators ----------------
__global__ __launch_bounds__(256) void cls_kernel(
    const __half* __restrict__ h, const __half2* __restrict__ w0p, const float* __restrict__ b0,
    const float* __restrict__ w1, const float* __restrict__ b1, float* __restrict__ out, int n)
{
    __shared__ __half2 w0s[64 * 64];   // 16 KB, k-pair-packed
    int tid = threadIdx.x;
    #pragma unroll
    for (int i = 0; i < 16; ++i) w0s[tid + i * 256] = w0p[tid + i * 256];
    __syncthreads();
    int lane = tid & 63, wv = tid >> 6;
    float bb0 = b0[lane], ww1 = w1[lane], bb1 = b1[0];
    #pragma unroll 1
    for (int q = 0; q < 4; ++q) {
        int node = blockIdx.x * 16 + wv * 4 + q;
        if (node >= n) break;
        const __half2* hr = (const __half2*)(h + (size_t)node * HID);
        float s0 = 0.f, s1 = 0.f;
        #pragma unroll
        for (int p = 0; p < 64; p += 2) {
            s0 = fdot2(hr[p],     w0s[(p + 0) * 64 + lane], s0);
            s1 = fdot2(hr[p + 1], w0s[(p + 1) * 64 + lane], s1);
        }
        float s = fmaxf(s0 + s1 + bb0, 0.f);
        float t = s * ww1;
        #pragma unroll
        for (int m = 1; m < 64; m <<= 1) t += __shfl_xor(t, m);
        if (lane == 0) out[node] = t + bb1;
    }
}

extern "C" void kernel_launch(void* const* d_in, const int* in_sizes, int n_in,
                              void* d_out, int out_size, void* d_ws, size_t ws_size,
                              hipStream_t stream) {
    const float* x  = (const float*)d_in[0];
    const int*   ei = (const int*)d_in[1];     // integer inputs arrive as int32
    const float* w_l0 = (const float*)d_in[2];
    const float* b_l0 = (const float*)d_in[3];
    const float* w_r0 = (const float*)d_in[4];
    const float* lnw0 = (const float*)d_in[5];
    const float* lnb0 = (const float*)d_in[6];
    const float* w_l1 = (const float*)d_in[7];
    const float* b_l1 = (const float*)d_in[8];
    const float* w_r1 = (const float*)d_in[9];
    const float* lnw1 = (const float*)d_in[10];
    const float* lnb1 = (const float*)d_in[11];
    const float* w_l2 = (const float*)d_in[12];
    const float* b_l2 = (const float*)d_in[13];
    const float* w_r2 = (const float*)d_in[14];
    const float* lnw2 = (const float*)d_in[15];
    const float* lnb2 = (const float*)d_in[16];
    const float* c_w0 = (const float*)d_in[17];
    const float* c_b0 = (const float*)d_in[18];
    const float* c_w1 = (const float*)d_in[19];
    const float* c_b1 = (const float*)d_in[20];
    float* out = (float*)d_out;

    int N = in_sizes[0] / 11;
    int E = in_sizes[1] / 2;
    int nb = (N + 255) / 256;

    // workspace: [deg: N][rp: N+1][cursor: N][csr: E][part: nb]
    //            [h16][agg16][wf1: 32768 halves][wf2: 32768 halves][w0p: 4096 half2]
    int*     deg    = (int*)d_ws;
    int*     rp     = deg + N;
    int*     cursor = rp + (N + 1);
    int*     csr    = cursor + N;
    int*     part   = csr + E;
    __half*  h16    = (__half*)(part + ((nb + 63) & ~63));
    __half*  agg16  = h16 + (size_t)N * HID;
    __half*  wf1    = agg16 + (size_t)N * HID;
    __half*  wf2    = wf1 + 4096 * 8;
    __half2* w0p    = (__half2*)(wf2 + 4096 * 8);

    // ---- CSR build (dst-range partitioned across XCDs) + weight packs ----
    int n4 = (N + 3) / 4;   // int4 count; over-zeroing <=3 ints into rp is harmless (rp rewritten)
    zero_kernel<<<(n4 + 255) / 256, 256, 0, stream>>>((int4*)deg, n4);
    deg_kernel<<<8 * 512, 256, 0, stream>>>(ei, deg, E, N);
    part_kernel<<<nb, 256, 0, stream>>>(deg, part, N);
    scanpart_kernel<<<1, 1024, 0, stream>>>(part, nb);
    rp_kernel<<<nb, 256, 0, stream>>>(deg, part, rp, cursor, N);
    fill_kernel<<<8 * 512, 256, 0, stream>>>(ei, cursor, csr, E, N);
    wfrag_kernel<<<16, 256, 0, stream>>>(w_l1, w_r1, wf1);
    wfrag_kernel<<<16, 256, 0, stream>>>(w_l2, w_r2, wf2);
    wpack_cls_kernel<<<16, 256, 0, stream>>>(c_w0, w0p);

    int nodeBlocks = (N + 3) / 4;

    // ---- layer 0 ----  h0 -> h16
    layer0_kernel<<<nodeBlocks, 256, 0, stream>>>(x, rp, csr, w_l0, b_l0, w_r0, lnw0, lnb0, h16, N);

    // ---- layer 1 ----  gather(h16)->agg16 ; layer(agg16, h16) -> h16
    aggp_kernel<<<nodeBlocks, 256, 0, stream>>>(rp, csr, h16, agg16, N);
    layer_kernel<<<(N + 63) / 64, 256, 0, stream>>>(agg16, h16, wf1, b_l1, lnw1, lnb1, h16, N);

    // ---- layer 2 ----
    aggp_kernel<<<nodeBlocks, 256, 0, stream>>>(rp, csr, h16, agg16, N);
    layer_kernel<<<(N + 63) / 64, 256, 0, stream>>>(agg16, h16, wf2, b_l2, lnw2, lnb2, h16, N);

    // ---- classifier ----
    cls_kernel<<<(N + 15) / 16, 256, 0, stream>>>(h16, w0p, c_b0, c_w1, c_b1, out, N);
}